// Round 2
// baseline (11341.160 us; speedup 1.0000x reference)
//
#include <hip/hip_runtime.h>
#include <hip/hip_bf16.h>

static const int S    = 16640;  // padded sequence (65*256)
static const int PADR = 255;    // zero rows prepended inside attention
static const int NT   = 16385;  // tokens incl cls
static const int CH   = 512;    // hidden dim

__device__ __forceinline__ float warpSum(float v) {
#pragma unroll
  for (int off = 32; off; off >>= 1) v += __shfl_xor(v, off);
  return v;
}
__device__ __forceinline__ float warpMax(float v) {
#pragma unroll
  for (int off = 32; off; off >>= 1) v = fmaxf(v, __shfl_xor(v, off));
  return v;
}
__device__ __forceinline__ float blockSum(float v) {
  __shared__ float sm[8];
  int lane = threadIdx.x & 63, wv = threadIdx.x >> 6;
  v = warpSum(v);
  __syncthreads();
  if (lane == 0) sm[wv] = v;
  __syncthreads();
  float t = 0.f;
  int nw = blockDim.x >> 6;
  for (int i = 0; i < nw; i++) t += sm[i];
  return t;
}
__device__ __forceinline__ float blockMax(float v) {
  __shared__ float sm[8];
  int lane = threadIdx.x & 63, wv = threadIdx.x >> 6;
  v = warpMax(v);
  __syncthreads();
  if (lane == 0) sm[wv] = v;
  __syncthreads();
  float t = -1e30f;
  int nw = blockDim.x >> 6;
  for (int i = 0; i < nw; i++) t = fmaxf(t, sm[i]);
  return t;
}

// ---------------------------------------------------------------------------
// Generic tiled matmul: C = alpha * A (M,K) * op(B) + bias [+ beta*C]
//   BT=true : B is (N,K) row-major, compute A*B^T
//   BT=false: B is (K,N) row-major, compute A*B
// MODE 0: C[row*ldc+col] = v + beta*C ; MODE 1: relu(v) ; MODE 2: head-major
//   split store C[(col>>6)*s64 + row*64 + (col&63)] (for per-head q/k/v)
// ---------------------------------------------------------------------------
template <bool BT, int MODE>
__global__ __launch_bounds__(256) void mm_kernel(
    const float* __restrict__ A, const float* __restrict__ Bm, float* __restrict__ C,
    const float* __restrict__ bias,
    int M, int N, int K, int lda, int ldb, int ldc,
    long sA, long sB, long sC, float alpha, float beta, long s64)
{
  __shared__ float As[16][64];
  __shared__ float Bs[16][64];
  const int bz = blockIdx.z;
  A  += (long)bz * sA;
  Bm += (long)bz * sB;
  C  += (long)bz * sC;
  const int m0 = blockIdx.y * 64, n0 = blockIdx.x * 64;
  const int tid = threadIdx.x;
  const int tm = tid >> 4, tn = tid & 15;
  const int ar = tid >> 2;          // 0..63
  const int ac = (tid & 3) << 2;    // 0,4,8,12
  float acc[4][4] = {};
  for (int k0 = 0; k0 < K; k0 += 16) {
#pragma unroll
    for (int i = 0; i < 4; i++) {
      int gm = m0 + ar, gk = k0 + ac + i;
      As[ac + i][ar] = (gm < M && gk < K) ? A[(long)gm * lda + gk] : 0.f;
    }
    if constexpr (BT) {
#pragma unroll
      for (int i = 0; i < 4; i++) {
        int gn = n0 + ar, gk = k0 + ac + i;
        Bs[ac + i][ar] = (gn < N && gk < K) ? Bm[(long)gn * ldb + gk] : 0.f;
      }
    } else {
      int bk = tid >> 4;           // 0..15
      int bn = (tid & 15) << 2;    // 0..60
#pragma unroll
      for (int i = 0; i < 4; i++) {
        int gk = k0 + bk, gn = n0 + bn + i;
        Bs[bk][bn + i] = (gk < K && gn < N) ? Bm[(long)gk * ldb + gn] : 0.f;
      }
    }
    __syncthreads();
#pragma unroll
    for (int kk = 0; kk < 16; kk++) {
      float a[4], b[4];
#pragma unroll
      for (int i = 0; i < 4; i++) { a[i] = As[kk][tm * 4 + i]; b[i] = Bs[kk][tn * 4 + i]; }
#pragma unroll
      for (int i = 0; i < 4; i++)
#pragma unroll
        for (int j = 0; j < 4; j++)
          acc[i][j] = fmaf(a[i], b[j], acc[i][j]);
    }
    __syncthreads();
  }
#pragma unroll
  for (int i = 0; i < 4; i++) {
    int row = m0 + tm * 4 + i;
    if (row >= M) continue;
#pragma unroll
    for (int j = 0; j < 4; j++) {
      int col = n0 + tn * 4 + j;
      if (col >= N) continue;
      float v = alpha * acc[i][j];
      if (bias) v += bias[col];
      if constexpr (MODE == 1) v = fmaxf(v, 0.f);
      if constexpr (MODE == 2) {
        C[(long)(col >> 6) * s64 + (long)row * 64 + (col & 63)] = v;
      } else {
        long idx = (long)row * ldc + col;
        C[idx] = (beta != 0.f) ? v + beta * C[idx] : v;
      }
    }
  }
}

// ---------------------------------------------------------------------------
__global__ void cls_copy(const float* __restrict__ c, float* __restrict__ h) {
  h[threadIdx.x] = c[threadIdx.x];
}

// LayerNorm of h (NT rows) into padded buffer: rows [0,PADR) zero, row s>=PADR
// = LN(h[s-PADR]) * g + b.  One block (256 thr) per output row, C=512.
__global__ __launch_bounds__(256) void ln_pad(const float* __restrict__ h,
    const float* __restrict__ g, const float* __restrict__ b,
    float* __restrict__ out, int pad)
{
  int s = blockIdx.x, t = threadIdx.x;
  float* o = out + (long)s * CH;
  if (s < pad) { o[t] = 0.f; o[t + 256] = 0.f; return; }
  const float* x = h + (long)(s - pad) * CH;
  float x0 = x[t], x1 = x[t + 256];
  float mu = blockSum(x0 + x1) * (1.f / 512.f);
  float d0 = x0 - mu, d1 = x1 - mu;
  float var = blockSum(d0 * d0 + d1 * d1) * (1.f / 512.f);
  float rs = rsqrtf(var + 1e-5f);
  o[t]       = d0 * rs * g[t]       + b[t];
  o[t + 256] = d1 * rs * g[t + 256] + b[t + 256];
}

// landmark means: (8,S,64) -> (8,256,64), landmark j = mean of rows j*65..j*65+64
__global__ __launch_bounds__(64) void landmark(const float* __restrict__ q, float* __restrict__ ql) {
  int hb = blockIdx.x;            // h*256 + j
  int d = threadIdx.x;
  int hh = hb >> 8, j = hb & 255;
  const float* src = q + ((long)hh * S + (long)j * 65) * 64 + d;
  float s = 0.f;
  for (int g2 = 0; g2 < 65; g2++) s += src[(long)g2 * 64];
  ql[(long)hb * 64 + d] = s * (1.f / 65.f);
}

// in-place row softmax over 256 columns; one block per row
__global__ __launch_bounds__(256) void rowsoftmax(float* __restrict__ X) {
  float* row = X + (long)blockIdx.x * 256;
  int t = threadIdx.x;
  float x = row[t];
  float m = blockMax(x);
  float e = __expf(x - m);
  float s = blockSum(e);
  row[t] = e / s;
}

__global__ __launch_bounds__(256) void rowabs(const float* __restrict__ a2, float* __restrict__ rs) {
  int r = blockIdx.x;
  float s = blockSum(fabsf(a2[(long)r * 256 + threadIdx.x]));
  if (threadIdx.x == 0) rs[r] = s;
}
__global__ __launch_bounds__(256) void colabs(const float* __restrict__ a2, float* __restrict__ cs) {
  int hb = blockIdx.x; int hh = hb >> 8, j = hb & 255;
  float s = blockSum(fabsf(a2[((long)hh * 256 + threadIdx.x) * 256 + j]));
  if (threadIdx.x == 0) cs[hb] = s;
}
__global__ __launch_bounds__(256) void scaleinv(const float* __restrict__ rs,
                                                const float* __restrict__ cs, float* __restrict__ inv) {
  float m1 = -1e30f, m2 = -1e30f;
  for (int i = threadIdx.x; i < 2048; i += 256) { m1 = fmaxf(m1, rs[i]); m2 = fmaxf(m2, cs[i]); }
  m1 = blockMax(m1);
  m2 = blockMax(m2);
  if (threadIdx.x == 0) inv[0] = 1.f / (m1 * m2);
}
// z0[h][i][j] = a2[h][j][i] * inv
__global__ __launch_bounds__(256) void z0k(const float* __restrict__ a2,
                                           const float* __restrict__ inv, float* __restrict__ z) {
  int hb = blockIdx.x; int hh = hb >> 8, i = hb & 255; int j = threadIdx.x;
  z[(long)hb * 256 + j] = a2[((long)hh * 256 + j) * 256 + i] * inv[0];
}
// Y = c*I - X  (batched 8 heads of 256x256, grid 2048 rows)
__global__ __launch_bounds__(256) void aIminus(const float* __restrict__ X, float* __restrict__ Y, float c) {
  long r = blockIdx.x; int i = (int)(r & 255); int j = threadIdx.x;
  Y[r * 256 + j] = ((j == i) ? c : 0.f) - X[r * 256 + j];
}

// a3@v with online softmax, stage 1: partials over key splits.
// grid: 8 heads * 16 landmark-groups * 16 key-splits; 256 thr (4 waves x 4 rows)
__global__ __launch_bounds__(256) void a3v_partial(const float* __restrict__ ql,
    const float* __restrict__ k, const float* __restrict__ v,
    float* __restrict__ pm, float* __restrict__ pz, float* __restrict__ pacc)
{
  int bx = blockIdx.x;
  int hh = bx >> 8, grp = (bx >> 4) & 15, split = bx & 15;
  int wv = threadIdx.x >> 6, lane = threadIdx.x & 63;
  int i0 = grp * 16 + wv * 4;
  const int chunk = S >> 4;       // 1040
  long j0 = (long)split * chunk;
  const float* kh = k + (long)hh * S * 64 + lane;
  const float* vh = v + (long)hh * S * 64 + lane;
  float qd[4], m[4], Z[4], acc[4];
#pragma unroll
  for (int r = 0; r < 4; r++) {
    qd[r] = ql[((long)hh * 256 + i0 + r) * 64 + lane];
    m[r] = -1e30f; Z[r] = 0.f; acc[r] = 0.f;
  }
  for (long j = j0; j < j0 + chunk; j++) {
    float kd = kh[j * 64];
    float vd = vh[j * 64];
#pragma unroll
    for (int r = 0; r < 4; r++) {
      float p = warpSum(qd[r] * kd);
      if (p > m[r]) {
        float sc = __expf(m[r] - p);
        Z[r] *= sc; acc[r] *= sc; m[r] = p;
      }
      float e = __expf(p - m[r]);
      Z[r] += e; acc[r] += e * vd;
    }
  }
#pragma unroll
  for (int r = 0; r < 4; r++) {
    long idx = ((long)hh * 256 + i0 + r) * 16 + split;
    pacc[idx * 64 + lane] = acc[r];
    if (lane == 0) { pm[idx] = m[r]; pz[idx] = Z[r]; }
  }
}
__global__ __launch_bounds__(64) void a3v_merge(const float* __restrict__ pm,
    const float* __restrict__ pz, const float* __restrict__ pacc, float* __restrict__ w3v)
{
  int hb = blockIdx.x; int lane = threadIdx.x;
  long base = (long)hb * 16;
  float M = -1e30f;
  for (int s2 = 0; s2 < 16; s2++) M = fmaxf(M, pm[base + s2]);
  float Z = 0.f, acc = 0.f;
  for (int s2 = 0; s2 < 16; s2++) {
    float sc = __expf(pm[base + s2] - M);
    Z += pz[base + s2] * sc;
    acc += pacc[(base + s2) * 64 + lane] * sc;
  }
  w3v[(long)hb * 64 + lane] = acc / Z;
}

// depthwise residual conv along sequence (kernel 33, pad 16), F += conv(v)
__global__ __launch_bounds__(64) void resconv(const float* __restrict__ v,
    const float* __restrict__ w, float* __restrict__ F)
{
  int s = blockIdx.x, hh = blockIdx.y, d = threadIdx.x;
  const float* vh = v + (long)hh * S * 64;
  float a = 0.f;
  for (int t = 0; t < 33; t++) {
    int j = s + t - 16;
    if (0 <= j && j < S) a += w[hh * 33 + t] * vh[(long)j * 64 + d];
  }
  F[(long)s * CH + hh * 64 + d] += a;
}

// h feat rows (1..16384, 512 cols) -> f (512, 16384) CHW
__global__ __launch_bounds__(256) void transpose_feat(const float* __restrict__ h, float* __restrict__ f) {
  __shared__ float tile[32][33];
  int p0 = blockIdx.x * 32;   // position
  int c0 = blockIdx.y * 32;   // channel
  int tx = threadIdx.x & 31, ty = threadIdx.x >> 5;   // 32x8
  for (int i = 0; i < 32; i += 8)
    tile[ty + i][tx] = h[(long)(1 + p0 + ty + i) * CH + c0 + tx];
  __syncthreads();
  for (int i = 0; i < 32; i += 8)
    f[(long)(c0 + ty + i) * 16384 + p0 + tx] = tile[tx][ty + i];
}

// h[1+p][c] = f + dw7 + dw5 + dw3 (+biases), per (c,y) block, 128 thr (x)
__global__ __launch_bounds__(128) void ppeg_conv(const float* __restrict__ f,
    const float* __restrict__ w7, const float* __restrict__ b7,
    const float* __restrict__ w5, const float* __restrict__ b5,
    const float* __restrict__ w3, const float* __restrict__ b3,
    float* __restrict__ h)
{
  int y = blockIdx.x, c = blockIdx.y, x = threadIdx.x;
  __shared__ float W7s[49], W5s[25], W3s[9];
  if (x < 49) W7s[x] = w7[c * 49 + x];
  if (x < 25) W5s[x] = w5[c * 25 + x];
  if (x < 9)  W3s[x] = w3[c * 9 + x];
  __syncthreads();
  const float* fc = f + (long)c * 16384;
  float acc = fc[y * 128 + x] + b7[c] + b5[c] + b3[c];
#pragma unroll
  for (int dy = 0; dy < 7; dy++) {
    int yy = y + dy - 3; if (yy < 0 || yy >= 128) continue;
    const float* row = fc + yy * 128;
#pragma unroll
    for (int dx = 0; dx < 7; dx++) {
      int xx = x + dx - 3; if (xx < 0 || xx >= 128) continue;
      acc += W7s[dy * 7 + dx] * row[xx];
    }
  }
#pragma unroll
  for (int dy = 0; dy < 5; dy++) {
    int yy = y + dy - 2; if (yy < 0 || yy >= 128) continue;
    const float* row = fc + yy * 128;
#pragma unroll
    for (int dx = 0; dx < 5; dx++) {
      int xx = x + dx - 2; if (xx < 0 || xx >= 128) continue;
      acc += W5s[dy * 5 + dx] * row[xx];
    }
  }
#pragma unroll
  for (int dy = 0; dy < 3; dy++) {
    int yy = y + dy - 1; if (yy < 0 || yy >= 128) continue;
    const float* row = fc + yy * 128;
#pragma unroll
    for (int dx = 0; dx < 3; dx++) {
      int xx = x + dx - 1; if (xx < 0 || xx >= 128) continue;
      acc += W3s[dy * 3 + dx] * row[xx];
    }
  }
  h[(long)(1 + y * 128 + x) * CH + c] = acc;
}

// final: LN(h row 0) then 2-class head, f32 out
__global__ __launch_bounds__(256) void final_k(const float* __restrict__ h,
    const float* __restrict__ g, const float* __restrict__ b,
    const float* __restrict__ w, const float* __restrict__ fb, float* __restrict__ out)
{
  int t = threadIdx.x;
  float x0 = h[t], x1 = h[t + 256];
  float mu = blockSum(x0 + x1) * (1.f / 512.f);
  float d0 = x0 - mu, d1 = x1 - mu;
  float var = blockSum(d0 * d0 + d1 * d1) * (1.f / 512.f);
  float rs = rsqrtf(var + 1e-5f);
  float y0 = d0 * rs * g[t]       + b[t];
  float y1 = d1 * rs * g[t + 256] + b[t + 256];
  float s0 = blockSum(y0 * w[t]       + y1 * w[t + 256]);
  float s1 = blockSum(y0 * w[512 + t] + y1 * w[512 + t + 256]);
  if (t == 0) {
    out[0] = s0 + fb[0];
    out[1] = s1 + fb[1];
  }
}

// ---------------------------------------------------------------------------
struct AttnW {
  const float *lng, *lnb, *qkvw, *outw, *outb, *resw;
};

static void run_attn(const AttnW& Wt, float* h, float* hn, float* q, float* k, float* v,
                     float* S1, float* ql, float* kl, float* w3v, float* Wm,
                     float* a2, float* xz, float* t1, float* t2, float* zA, float* zB,
                     float* rs, float* cs, float* inv, float* pm, float* pz, float* pacc,
                     hipStream_t stream)
{
  const long s64 = (long)S * 64;
  ln_pad<<<S, 256, 0, stream>>>(h, Wt.lng, Wt.lnb, hn, PADR);
  // q,k,v head-major (8,S,64); q scaled by 1/sqrt(64)
  mm_kernel<true, 2><<<dim3(8, 260, 1), 256, 0, stream>>>(
      hn, Wt.qkvw,               q, nullptr, S, 512, 512, 512, 512, 0, 0, 0, 0, 0.125f, 0.f, s64);
  mm_kernel<true, 2><<<dim3(8, 260, 1), 256, 0, stream>>>(
      hn, Wt.qkvw + 512 * 512,   k, nullptr, S, 512, 512, 512, 512, 0, 0, 0, 0, 1.f, 0.f, s64);
  mm_kernel<true, 2><<<dim3(8, 260, 1), 256, 0, stream>>>(
      hn, Wt.qkvw + 2 * 512 * 512, v, nullptr, S, 512, 512, 512, 512, 0, 0, 0, 0, 1.f, 0.f, s64);
  landmark<<<2048, 64, 0, stream>>>(q, ql);
  landmark<<<2048, 64, 0, stream>>>(k, kl);
  // a2 = softmax(ql @ kl^T), batched over heads
  mm_kernel<true, 0><<<dim3(4, 4, 8), 256, 0, stream>>>(
      ql, kl, a2, nullptr, 256, 256, 64, 64, 64, 256, 16384, 16384, 65536, 1.f, 0.f, 0);
  rowsoftmax<<<2048, 256, 0, stream>>>(a2);
  // pinv scale 1/(max rowsum * max colsum)
  rowabs<<<2048, 256, 0, stream>>>(a2, rs);
  colabs<<<2048, 256, 0, stream>>>(a2, cs);
  scaleinv<<<1, 256, 0, stream>>>(rs, cs, inv);
  z0k<<<2048, 256, 0, stream>>>(a2, inv, zA);
  float* zc = zA; float* zo = zB;
  for (int it = 0; it < 6; it++) {
    mm_kernel<false, 0><<<dim3(4, 4, 8), 256, 0, stream>>>(
        a2, zc, xz, nullptr, 256, 256, 256, 256, 256, 256, 65536, 65536, 65536, 1.f, 0.f, 0);
    aIminus<<<2048, 256, 0, stream>>>(xz, t1, 7.f);
    mm_kernel<false, 0><<<dim3(4, 4, 8), 256, 0, stream>>>(
        xz, t1, t2, nullptr, 256, 256, 256, 256, 256, 256, 65536, 65536, 65536, 1.f, 0.f, 0);
    aIminus<<<2048, 256, 0, stream>>>(t2, t1, 15.f);
    mm_kernel<false, 0><<<dim3(4, 4, 8), 256, 0, stream>>>(
        xz, t1, t2, nullptr, 256, 256, 256, 256, 256, 256, 65536, 65536, 65536, 1.f, 0.f, 0);
    aIminus<<<2048, 256, 0, stream>>>(t2, t1, 13.f);
    mm_kernel<false, 0><<<dim3(4, 4, 8), 256, 0, stream>>>(
        zc, t1, zo, nullptr, 256, 256, 256, 256, 256, 256, 65536, 65536, 65536, 0.25f, 0.f, 0);
    float* tmp = zc; zc = zo; zo = tmp;
  }
  // w3v = softmax(ql @ k^T) @ v  (online, two-stage)
  a3v_partial<<<2048, 256, 0, stream>>>(ql, k, v, pm, pz, pacc);
  a3v_merge<<<2048, 64, 0, stream>>>(pm, pz, pacc, w3v);
  // Wm = pinv(a2) @ w3v   (8, 256, 64)
  mm_kernel<false, 0><<<dim3(1, 4, 8), 256, 0, stream>>>(
      zc, w3v, Wm, nullptr, 256, 64, 256, 256, 64, 64, 65536, 16384, 16384, 1.f, 0.f, 0);
  // F(=hn)[s, h*64+d] = softmax(q_h @ kl_h^T) @ Wm_h   per head
  for (int hh = 0; hh < 8; hh++) {
    mm_kernel<true, 0><<<dim3(4, 260, 1), 256, 0, stream>>>(
        q + (long)hh * s64, kl + hh * 16384, S1, nullptr, S, 256, 64, 64, 64, 256, 0, 0, 0, 1.f, 0.f, 0);
    rowsoftmax<<<S, 256, 0, stream>>>(S1);
    mm_kernel<false, 0><<<dim3(1, 260, 1), 256, 0, stream>>>(
        S1, Wm + hh * 16384, hn + hh * 64, nullptr, S, 64, 256, 256, 64, 512, 0, 0, 0, 1.f, 0.f, 0);
  }
  resconv<<<dim3(S, 8, 1), 64, 0, stream>>>(v, Wt.resw, hn);
  // h += F[PADR:, :] @ outw^T + outb
  mm_kernel<true, 0><<<dim3(8, 257, 1), 256, 0, stream>>>(
      hn + (long)PADR * CH, Wt.outw, h, Wt.outb, NT, 512, 512, 512, 512, 512, 0, 0, 0, 1.f, 1.f, 0);
}

extern "C" void kernel_launch(void* const* d_in, const int* in_sizes, int n_in,
                              void* d_out, int out_size, void* d_ws, size_t ws_size,
                              hipStream_t stream)
{
  const float* X      = (const float*)d_in[0];
  const float* fc1w   = (const float*)d_in[1];
  const float* fc1b   = (const float*)d_in[2];
  const float* clstok = (const float*)d_in[3];
  AttnW w1{ (const float*)d_in[4], (const float*)d_in[5], (const float*)d_in[6],
            (const float*)d_in[7], (const float*)d_in[8], (const float*)d_in[9] };
  const float* w7 = (const float*)d_in[10]; const float* b7 = (const float*)d_in[11];
  const float* w5 = (const float*)d_in[12]; const float* b5 = (const float*)d_in[13];
  const float* w3 = (const float*)d_in[14]; const float* b3 = (const float*)d_in[15];
  AttnW w2{ (const float*)d_in[16], (const float*)d_in[17], (const float*)d_in[18],
            (const float*)d_in[19], (const float*)d_in[20], (const float*)d_in[21] };
  const float* lnfg = (const float*)d_in[22];
  const float* lnfb = (const float*)d_in[23];
  const float* fc2w = (const float*)d_in[24];
  const float* fc2b = (const float*)d_in[25];
  float* out = (float*)d_out;

  char* wsb = (char*)d_ws;
  size_t off = 0;
  auto alloc = [&](size_t nfloats) {
    float* p = (float*)(wsb + off);
    off = (off + nfloats * 4 + 255) & ~(size_t)255;
    return p;
  };
  float* h    = alloc((size_t)NT * CH);          // 33.6 MB
  float* hn   = alloc((size_t)S * CH);           // LN-out, later attention F
  float* q    = alloc((size_t)S * CH);           // also ppeg CHW buffer
  float* k    = alloc((size_t)S * CH);
  float* v    = alloc((size_t)S * CH);
  float* S1   = alloc((size_t)S * 256);          // per-head a1 scores
  float* ql   = alloc(8 * 256 * 64);
  float* kl   = alloc(8 * 256 * 64);
  float* w3v  = alloc(8 * 256 * 64);
  float* Wm   = alloc(8 * 256 * 64);
  float* a2   = alloc(8 * 256 * 256);
  float* xz   = alloc(8 * 256 * 256);
  float* t1   = alloc(8 * 256 * 256);
  float* t2   = alloc(8 * 256 * 256);
  float* zA   = alloc(8 * 256 * 256);
  float* zB   = alloc(8 * 256 * 256);
  float* rs   = alloc(2048);
  float* cs   = alloc(2048);
  float* inv  = alloc(64);
  float* pm   = alloc(8 * 256 * 16);
  float* pz   = alloc(8 * 256 * 16);
  float* pacc = alloc((size_t)8 * 256 * 16 * 64);
  (void)in_sizes; (void)n_in; (void)out_size; (void)ws_size;

  // h[0] = cls ; h[1..16384] = relu(X @ fc1^T + b)
  cls_copy<<<1, 512, 0, stream>>>(clstok, h);
  mm_kernel<true, 1><<<dim3(8, 256, 1), 256, 0, stream>>>(
      X, fc1w, h + CH, fc1b, 16384, 512, 1024, 1024, 1024, 512, 0, 0, 0, 1.f, 0.f, 0);

  run_attn(w1, h, hn, q, k, v, S1, ql, kl, w3v, Wm, a2, xz, t1, t2, zA, zB,
           rs, cs, inv, pm, pz, pacc, stream);

  // PPEG: f = CHW(feat); h[1+p][c] = f + dw7 + dw5 + dw3
  transpose_feat<<<dim3(512, 16, 1), 256, 0, stream>>>(h, q);
  ppeg_conv<<<dim3(128, 512, 1), 128, 0, stream>>>(q, w7, b7, w5, b5, w3, b3, h);

  run_attn(w2, h, hn, q, k, v, S1, ql, kl, w3v, Wm, a2, xz, t1, t2, zA, zB,
           rs, cs, inv, pm, pz, pacc, stream);

  final_k<<<1, 256, 0, stream>>>(h, lnfg, lnfb, fc2w, fc2b, out);
}

// Round 3
// 7403.841 us; speedup vs baseline: 1.5318x; 1.5318x over previous
//
#include <hip/hip_runtime.h>
#include <hip/hip_bf16.h>

static const int S    = 16640;  // padded sequence (65*256)
static const int PADR = 255;    // zero rows prepended inside attention
static const int NT   = 16385;  // tokens incl cls
static const int CH   = 512;    // hidden dim

__device__ __forceinline__ float warpSum(float v) {
#pragma unroll
  for (int off = 32; off; off >>= 1) v += __shfl_xor(v, off);
  return v;
}
__device__ __forceinline__ float warpMax(float v) {
#pragma unroll
  for (int off = 32; off; off >>= 1) v = fmaxf(v, __shfl_xor(v, off));
  return v;
}
__device__ __forceinline__ float blockSum(float v) {
  __shared__ float sm[8];
  int lane = threadIdx.x & 63, wv = threadIdx.x >> 6;
  v = warpSum(v);
  __syncthreads();
  if (lane == 0) sm[wv] = v;
  __syncthreads();
  float t = 0.f;
  int nw = blockDim.x >> 6;
  for (int i = 0; i < nw; i++) t += sm[i];
  return t;
}
__device__ __forceinline__ float blockMax(float v) {
  __shared__ float sm[8];
  int lane = threadIdx.x & 63, wv = threadIdx.x >> 6;
  v = warpMax(v);
  __syncthreads();
  if (lane == 0) sm[wv] = v;
  __syncthreads();
  float t = -1e30f;
  int nw = blockDim.x >> 6;
  for (int i = 0; i < nw; i++) t = fmaxf(t, sm[i]);
  return t;
}

// ---------------------------------------------------------------------------
// Generic tiled matmul: C = alpha * A (M,K) * op(B) + bias [+ beta*C]
//   BT=true : B is (N,K) row-major, compute A*B^T
//   BT=false: B is (K,N) row-major, compute A*B
// MODE 0: C[row*ldc+col] = v + beta*C ; MODE 1: relu(v) ; MODE 2: head-major
//   split store C[(col>>6)*s64 + row*64 + (col&63)] (for per-head q/k/v)
// ---------------------------------------------------------------------------
template <bool BT, int MODE>
__global__ __launch_bounds__(256) void mm_kernel(
    const float* __restrict__ A, const float* __restrict__ Bm, float* __restrict__ C,
    const float* __restrict__ bias,
    int M, int N, int K, int lda, int ldb, int ldc,
    long sA, long sB, long sC, float alpha, float beta, long s64)
{
  __shared__ float As[16][64];
  __shared__ float Bs[16][64];
  const int bz = blockIdx.z;
  A  += (long)bz * sA;
  Bm += (long)bz * sB;
  C  += (long)bz * sC;
  const int m0 = blockIdx.y * 64, n0 = blockIdx.x * 64;
  const int tid = threadIdx.x;
  const int tm = tid >> 4, tn = tid & 15;
  const int ar = tid >> 2;          // 0..63
  const int ac = (tid & 3) << 2;    // 0,4,8,12
  float acc[4][4] = {};
  for (int k0 = 0; k0 < K; k0 += 16) {
#pragma unroll
    for (int i = 0; i < 4; i++) {
      int gm = m0 + ar, gk = k0 + ac + i;
      As[ac + i][ar] = (gm < M && gk < K) ? A[(long)gm * lda + gk] : 0.f;
    }
    if constexpr (BT) {
#pragma unroll
      for (int i = 0; i < 4; i++) {
        int gn = n0 + ar, gk = k0 + ac + i;
        Bs[ac + i][ar] = (gn < N && gk < K) ? Bm[(long)gn * ldb + gk] : 0.f;
      }
    } else {
      int bk = tid >> 4;           // 0..15
      int bn = (tid & 15) << 2;    // 0..60
#pragma unroll
      for (int i = 0; i < 4; i++) {
        int gk = k0 + bk, gn = n0 + bn + i;
        Bs[bk][bn + i] = (gk < K && gn < N) ? Bm[(long)gk * ldb + gn] : 0.f;
      }
    }
    __syncthreads();
#pragma unroll
    for (int kk = 0; kk < 16; kk++) {
      float a[4], b[4];
#pragma unroll
      for (int i = 0; i < 4; i++) { a[i] = As[kk][tm * 4 + i]; b[i] = Bs[kk][tn * 4 + i]; }
#pragma unroll
      for (int i = 0; i < 4; i++)
#pragma unroll
        for (int j = 0; j < 4; j++)
          acc[i][j] = fmaf(a[i], b[j], acc[i][j]);
    }
    __syncthreads();
  }
#pragma unroll
  for (int i = 0; i < 4; i++) {
    int row = m0 + tm * 4 + i;
    if (row >= M) continue;
#pragma unroll
    for (int j = 0; j < 4; j++) {
      int col = n0 + tn * 4 + j;
      if (col >= N) continue;
      float v = alpha * acc[i][j];
      if (bias) v += bias[col];
      if constexpr (MODE == 1) v = fmaxf(v, 0.f);
      if constexpr (MODE == 2) {
        C[(long)(col >> 6) * s64 + (long)row * 64 + (col & 63)] = v;
      } else {
        long idx = (long)row * ldc + col;
        C[idx] = (beta != 0.f) ? v + beta * C[idx] : v;
      }
    }
  }
}

// ---------------------------------------------------------------------------
__global__ void cls_copy(const float* __restrict__ c, float* __restrict__ h) {
  h[threadIdx.x] = c[threadIdx.x];
}

// LayerNorm of h (NT rows) into padded buffer: rows [0,PADR) zero, row s>=PADR
// = LN(h[s-PADR]) * g + b.  One block (256 thr) per output row, C=512.
__global__ __launch_bounds__(256) void ln_pad(const float* __restrict__ h,
    const float* __restrict__ g, const float* __restrict__ b,
    float* __restrict__ out, int pad)
{
  int s = blockIdx.x, t = threadIdx.x;
  float* o = out + (long)s * CH;
  if (s < pad) { o[t] = 0.f; o[t + 256] = 0.f; return; }
  const float* x = h + (long)(s - pad) * CH;
  float x0 = x[t], x1 = x[t + 256];
  float mu = blockSum(x0 + x1) * (1.f / 512.f);
  float d0 = x0 - mu, d1 = x1 - mu;
  float var = blockSum(d0 * d0 + d1 * d1) * (1.f / 512.f);
  float rs = rsqrtf(var + 1e-5f);
  o[t]       = d0 * rs * g[t]       + b[t];
  o[t + 256] = d1 * rs * g[t + 256] + b[t + 256];
}

// landmark means: (8,S,64) -> (8,256,64), landmark j = mean of rows j*65..j*65+64
__global__ __launch_bounds__(64) void landmark(const float* __restrict__ q, float* __restrict__ ql) {
  int hb = blockIdx.x;            // h*256 + j
  int d = threadIdx.x;
  int hh = hb >> 8, j = hb & 255;
  const float* src = q + ((long)hh * S + (long)j * 65) * 64 + d;
  float s = 0.f;
  for (int g2 = 0; g2 < 65; g2++) s += src[(long)g2 * 64];
  ql[(long)hb * 64 + d] = s * (1.f / 65.f);
}

// in-place row softmax over 256 columns; one block per row
__global__ __launch_bounds__(256) void rowsoftmax(float* __restrict__ X) {
  float* row = X + (long)blockIdx.x * 256;
  int t = threadIdx.x;
  float x = row[t];
  float m = blockMax(x);
  float e = __expf(x - m);
  float s = blockSum(e);
  row[t] = e / s;
}

// in-place row softmax over 16640 columns; one block per row, 65 elems/thread
__global__ __launch_bounds__(256) void softmax_wide(float* __restrict__ X) {
  float* row = X + (long)blockIdx.x * 16640;
  int t = threadIdx.x;
  float r[65];
  float m = -1e30f;
#pragma unroll
  for (int i = 0; i < 65; i++) { r[i] = row[i * 256 + t]; m = fmaxf(m, r[i]); }
  m = blockMax(m);
  float s = 0.f;
#pragma unroll
  for (int i = 0; i < 65; i++) { r[i] = __expf(r[i] - m); s += r[i]; }
  s = blockSum(s);
  float inv = 1.f / s;
#pragma unroll
  for (int i = 0; i < 65; i++) row[i * 256 + t] = r[i] * inv;
}

// split-K GEMM: partial[split][m][n] = sum_{k in chunk} A[m][k] * B[k][n]
// A: [256][16640] row-major (softmaxed scores), B: [16640][64] row-major (v_h)
// grid (65 splits, 4 m-tiles), 256 threads; K-chunk = 256 (16 k-tiles of 16)
__global__ __launch_bounds__(256) void gemm_a3v_splitk(
    const float* __restrict__ A, const float* __restrict__ B,
    float* __restrict__ partial)
{
  __shared__ float As[16][64];
  __shared__ float Bs[16][64];
  const int split = blockIdx.x;
  const int m0 = blockIdx.y * 64;
  const int tid = threadIdx.x;
  const int tm = tid >> 4, tn = tid & 15;
  const int ar = tid >> 2, ac = (tid & 3) << 2;
  float acc[4][4] = {};
  const int k0base = split * 256;
  for (int kt = 0; kt < 16; kt++) {
    int k0 = k0base + kt * 16;
#pragma unroll
    for (int i = 0; i < 4; i++)
      As[ac + i][ar] = A[(long)(m0 + ar) * 16640 + k0 + ac + i];
    {
      int bk = tid >> 4, bn = (tid & 15) << 2;
#pragma unroll
      for (int i = 0; i < 4; i++)
        Bs[bk][bn + i] = B[(long)(k0 + bk) * 64 + bn + i];
    }
    __syncthreads();
#pragma unroll
    for (int kk = 0; kk < 16; kk++) {
      float a[4], b[4];
#pragma unroll
      for (int i = 0; i < 4; i++) { a[i] = As[kk][tm * 4 + i]; b[i] = Bs[kk][tn * 4 + i]; }
#pragma unroll
      for (int i = 0; i < 4; i++)
#pragma unroll
        for (int j = 0; j < 4; j++)
          acc[i][j] = fmaf(a[i], b[j], acc[i][j]);
    }
    __syncthreads();
  }
#pragma unroll
  for (int i = 0; i < 4; i++)
#pragma unroll
    for (int j = 0; j < 4; j++)
      partial[((long)split * 256 + m0 + tm * 4 + i) * 64 + tn * 4 + j] = acc[i][j];
}

// w3v_h[i] = sum over 65 splits of partial[split][i]  (i over 256*64)
__global__ __launch_bounds__(256) void a3v_reduce(const float* __restrict__ partial,
                                                  float* __restrict__ w3v) {
  int i = blockIdx.x * 256 + threadIdx.x;
  float s = 0.f;
  for (int sp = 0; sp < 65; sp++) s += partial[(long)sp * 16384 + i];
  w3v[i] = s;
}

__global__ __launch_bounds__(256) void rowabs(const float* __restrict__ a2, float* __restrict__ rs) {
  int r = blockIdx.x;
  float s = blockSum(fabsf(a2[(long)r * 256 + threadIdx.x]));
  if (threadIdx.x == 0) rs[r] = s;
}
__global__ __launch_bounds__(256) void colabs(const float* __restrict__ a2, float* __restrict__ cs) {
  int hb = blockIdx.x; int hh = hb >> 8, j = hb & 255;
  float s = blockSum(fabsf(a2[((long)hh * 256 + threadIdx.x) * 256 + j]));
  if (threadIdx.x == 0) cs[hb] = s;
}
__global__ __launch_bounds__(256) void scaleinv(const float* __restrict__ rs,
                                                const float* __restrict__ cs, float* __restrict__ inv) {
  float m1 = -1e30f, m2 = -1e30f;
  for (int i = threadIdx.x; i < 2048; i += 256) { m1 = fmaxf(m1, rs[i]); m2 = fmaxf(m2, cs[i]); }
  m1 = blockMax(m1);
  m2 = blockMax(m2);
  if (threadIdx.x == 0) inv[0] = 1.f / (m1 * m2);
}
// z0[h][i][j] = a2[h][j][i] * inv
__global__ __launch_bounds__(256) void z0k(const float* __restrict__ a2,
                                           const float* __restrict__ inv, float* __restrict__ z) {
  int hb = blockIdx.x; int hh = hb >> 8, i = hb & 255; int j = threadIdx.x;
  z[(long)hb * 256 + j] = a2[((long)hh * 256 + j) * 256 + i] * inv[0];
}
// Y = c*I - X  (batched 8 heads of 256x256, grid 2048 rows)
__global__ __launch_bounds__(256) void aIminus(const float* __restrict__ X, float* __restrict__ Y, float c) {
  long r = blockIdx.x; int i = (int)(r & 255); int j = threadIdx.x;
  Y[r * 256 + j] = ((j == i) ? c : 0.f) - X[r * 256 + j];
}

// depthwise residual conv along sequence (kernel 33, pad 16), F += conv(v)
__global__ __launch_bounds__(64) void resconv(const float* __restrict__ v,
    const float* __restrict__ w, float* __restrict__ F)
{
  int s = blockIdx.x, hh = blockIdx.y, d = threadIdx.x;
  const float* vh = v + (long)hh * S * 64;
  float a = 0.f;
  for (int t = 0; t < 33; t++) {
    int j = s + t - 16;
    if (0 <= j && j < S) a += w[hh * 33 + t] * vh[(long)j * 64 + d];
  }
  F[(long)s * CH + hh * 64 + d] += a;
}

// h feat rows (1..16384, 512 cols) -> f (512, 16384) CHW
__global__ __launch_bounds__(256) void transpose_feat(const float* __restrict__ h, float* __restrict__ f) {
  __shared__ float tile[32][33];
  int p0 = blockIdx.x * 32;   // position
  int c0 = blockIdx.y * 32;   // channel
  int tx = threadIdx.x & 31, ty = threadIdx.x >> 5;   // 32x8
  for (int i = 0; i < 32; i += 8)
    tile[ty + i][tx] = h[(long)(1 + p0 + ty + i) * CH + c0 + tx];
  __syncthreads();
  for (int i = 0; i < 32; i += 8)
    f[(long)(c0 + ty + i) * 16384 + p0 + tx] = tile[tx][ty + i];
}

// h[1+p][c] = f + dw7 + dw5 + dw3 (+biases), per (c,y) block, 128 thr (x)
__global__ __launch_bounds__(128) void ppeg_conv(const float* __restrict__ f,
    const float* __restrict__ w7, const float* __restrict__ b7,
    const float* __restrict__ w5, const float* __restrict__ b5,
    const float* __restrict__ w3, const float* __restrict__ b3,
    float* __restrict__ h)
{
  int y = blockIdx.x, c = blockIdx.y, x = threadIdx.x;
  __shared__ float W7s[49], W5s[25], W3s[9];
  if (x < 49) W7s[x] = w7[c * 49 + x];
  if (x < 25) W5s[x] = w5[c * 25 + x];
  if (x < 9)  W3s[x] = w3[c * 9 + x];
  __syncthreads();
  const float* fc = f + (long)c * 16384;
  float acc = fc[y * 128 + x] + b7[c] + b5[c] + b3[c];
#pragma unroll
  for (int dy = 0; dy < 7; dy++) {
    int yy = y + dy - 3; if (yy < 0 || yy >= 128) continue;
    const float* row = fc + yy * 128;
#pragma unroll
    for (int dx = 0; dx < 7; dx++) {
      int xx = x + dx - 3; if (xx < 0 || xx >= 128) continue;
      acc += W7s[dy * 7 + dx] * row[xx];
    }
  }
#pragma unroll
  for (int dy = 0; dy < 5; dy++) {
    int yy = y + dy - 2; if (yy < 0 || yy >= 128) continue;
    const float* row = fc + yy * 128;
#pragma unroll
    for (int dx = 0; dx < 5; dx++) {
      int xx = x + dx - 2; if (xx < 0 || xx >= 128) continue;
      acc += W5s[dy * 5 + dx] * row[xx];
    }
  }
#pragma unroll
  for (int dy = 0; dy < 3; dy++) {
    int yy = y + dy - 1; if (yy < 0 || yy >= 128) continue;
    const float* row = fc + yy * 128;
#pragma unroll
    for (int dx = 0; dx < 3; dx++) {
      int xx = x + dx - 1; if (xx < 0 || xx >= 128) continue;
      acc += W3s[dy * 3 + dx] * row[xx];
    }
  }
  h[(long)(1 + y * 128 + x) * CH + c] = acc;
}

// final: LN(h row 0) then 2-class head, f32 out
__global__ __launch_bounds__(256) void final_k(const float* __restrict__ h,
    const float* __restrict__ g, const float* __restrict__ b,
    const float* __restrict__ w, const float* __restrict__ fb, float* __restrict__ out)
{
  int t = threadIdx.x;
  float x0 = h[t], x1 = h[t + 256];
  float mu = blockSum(x0 + x1) * (1.f / 512.f);
  float d0 = x0 - mu, d1 = x1 - mu;
  float var = blockSum(d0 * d0 + d1 * d1) * (1.f / 512.f);
  float rs = rsqrtf(var + 1e-5f);
  float y0 = d0 * rs * g[t]       + b[t];
  float y1 = d1 * rs * g[t + 256] + b[t + 256];
  float s0 = blockSum(y0 * w[t]       + y1 * w[t + 256]);
  float s1 = blockSum(y0 * w[512 + t] + y1 * w[512 + t + 256]);
  if (t == 0) {
    out[0] = s0 + fb[0];
    out[1] = s1 + fb[1];
  }
}

// ---------------------------------------------------------------------------
struct AttnW {
  const float *lng, *lnb, *qkvw, *outw, *outb, *resw;
};

static void run_attn(const AttnW& Wt, float* h, float* hn, float* q, float* k, float* v,
                     float* S1, float* ql, float* kl, float* w3v, float* Wm,
                     float* a2, float* xz, float* t1, float* t2, float* zA, float* zB,
                     float* rs, float* cs, float* inv, float* partial,
                     hipStream_t stream)
{
  const long s64 = (long)S * 64;
  ln_pad<<<S, 256, 0, stream>>>(h, Wt.lng, Wt.lnb, hn, PADR);
  // q,k,v head-major (8,S,64); q scaled by 1/sqrt(64)
  mm_kernel<true, 2><<<dim3(8, 260, 1), 256, 0, stream>>>(
      hn, Wt.qkvw,               q, nullptr, S, 512, 512, 512, 512, 0, 0, 0, 0, 0.125f, 0.f, s64);
  mm_kernel<true, 2><<<dim3(8, 260, 1), 256, 0, stream>>>(
      hn, Wt.qkvw + 512 * 512,   k, nullptr, S, 512, 512, 512, 512, 0, 0, 0, 0, 1.f, 0.f, s64);
  mm_kernel<true, 2><<<dim3(8, 260, 1), 256, 0, stream>>>(
      hn, Wt.qkvw + 2 * 512 * 512, v, nullptr, S, 512, 512, 512, 512, 0, 0, 0, 0, 1.f, 0.f, s64);
  landmark<<<2048, 64, 0, stream>>>(q, ql);
  landmark<<<2048, 64, 0, stream>>>(k, kl);
  // a2 = softmax(ql @ kl^T), batched over heads
  mm_kernel<true, 0><<<dim3(4, 4, 8), 256, 0, stream>>>(
      ql, kl, a2, nullptr, 256, 256, 64, 64, 64, 256, 16384, 16384, 65536, 1.f, 0.f, 0);
  rowsoftmax<<<2048, 256, 0, stream>>>(a2);
  // pinv scale 1/(max rowsum * max colsum)
  rowabs<<<2048, 256, 0, stream>>>(a2, rs);
  colabs<<<2048, 256, 0, stream>>>(a2, cs);
  scaleinv<<<1, 256, 0, stream>>>(rs, cs, inv);
  z0k<<<2048, 256, 0, stream>>>(a2, inv, zA);
  float* zc = zA; float* zo = zB;
  for (int it = 0; it < 6; it++) {
    mm_kernel<false, 0><<<dim3(4, 4, 8), 256, 0, stream>>>(
        a2, zc, xz, nullptr, 256, 256, 256, 256, 256, 256, 65536, 65536, 65536, 1.f, 0.f, 0);
    aIminus<<<2048, 256, 0, stream>>>(xz, t1, 7.f);
    mm_kernel<false, 0><<<dim3(4, 4, 8), 256, 0, stream>>>(
        xz, t1, t2, nullptr, 256, 256, 256, 256, 256, 256, 65536, 65536, 65536, 1.f, 0.f, 0);
    aIminus<<<2048, 256, 0, stream>>>(t2, t1, 15.f);
    mm_kernel<false, 0><<<dim3(4, 4, 8), 256, 0, stream>>>(
        xz, t1, t2, nullptr, 256, 256, 256, 256, 256, 256, 65536, 65536, 65536, 1.f, 0.f, 0);
    aIminus<<<2048, 256, 0, stream>>>(t2, t1, 13.f);
    mm_kernel<false, 0><<<dim3(4, 4, 8), 256, 0, stream>>>(
        zc, t1, zo, nullptr, 256, 256, 256, 256, 256, 256, 65536, 65536, 65536, 0.25f, 0.f, 0);
    float* tmp = zc; zc = zo; zo = tmp;
  }
  // w3v_h = softmax(ql_h @ k_h^T) @ v_h  — materialized per head in S1
  for (int hh = 0; hh < 8; hh++) {
    mm_kernel<true, 0><<<dim3(260, 4, 1), 256, 0, stream>>>(
        ql + hh * 16384, k + (long)hh * s64, S1, nullptr,
        256, S, 64, 64, 64, S, 0, 0, 0, 1.f, 0.f, 0);
    softmax_wide<<<256, 256, 0, stream>>>(S1);
    gemm_a3v_splitk<<<dim3(65, 4, 1), 256, 0, stream>>>(S1, v + (long)hh * s64, partial);
    a3v_reduce<<<64, 256, 0, stream>>>(partial, w3v + hh * 16384);
  }
  // Wm = pinv(a2) @ w3v   (8, 256, 64)
  mm_kernel<false, 0><<<dim3(1, 4, 8), 256, 0, stream>>>(
      zc, w3v, Wm, nullptr, 256, 64, 256, 256, 64, 64, 65536, 16384, 16384, 1.f, 0.f, 0);
  // F(=hn)[s, h*64+d] = softmax(q_h @ kl_h^T) @ Wm_h   per head
  for (int hh = 0; hh < 8; hh++) {
    mm_kernel<true, 0><<<dim3(4, 260, 1), 256, 0, stream>>>(
        q + (long)hh * s64, kl + hh * 16384, S1, nullptr, S, 256, 64, 64, 64, 256, 0, 0, 0, 1.f, 0.f, 0);
    rowsoftmax<<<S, 256, 0, stream>>>(S1);
    mm_kernel<false, 0><<<dim3(1, 260, 1), 256, 0, stream>>>(
        S1, Wm + hh * 16384, hn + hh * 64, nullptr, S, 64, 256, 256, 64, 512, 0, 0, 0, 1.f, 0.f, 0);
  }
  resconv<<<dim3(S, 8, 1), 64, 0, stream>>>(v, Wt.resw, hn);
  // h += F[PADR:, :] @ outw^T + outb
  mm_kernel<true, 0><<<dim3(8, 257, 1), 256, 0, stream>>>(
      hn + (long)PADR * CH, Wt.outw, h, Wt.outb, NT, 512, 512, 512, 512, 512, 0, 0, 0, 1.f, 1.f, 0);
}

extern "C" void kernel_launch(void* const* d_in, const int* in_sizes, int n_in,
                              void* d_out, int out_size, void* d_ws, size_t ws_size,
                              hipStream_t stream)
{
  const float* X      = (const float*)d_in[0];
  const float* fc1w   = (const float*)d_in[1];
  const float* fc1b   = (const float*)d_in[2];
  const float* clstok = (const float*)d_in[3];
  AttnW w1{ (const float*)d_in[4], (const float*)d_in[5], (const float*)d_in[6],
            (const float*)d_in[7], (const float*)d_in[8], (const float*)d_in[9] };
  const float* w7 = (const float*)d_in[10]; const float* b7 = (const float*)d_in[11];
  const float* w5 = (const float*)d_in[12]; const float* b5 = (const float*)d_in[13];
  const float* w3 = (const float*)d_in[14]; const float* b3 = (const float*)d_in[15];
  AttnW w2{ (const float*)d_in[16], (const float*)d_in[17], (const float*)d_in[18],
            (const float*)d_in[19], (const float*)d_in[20], (const float*)d_in[21] };
  const float* lnfg = (const float*)d_in[22];
  const float* lnfb = (const float*)d_in[23];
  const float* fc2w = (const float*)d_in[24];
  const float* fc2b = (const float*)d_in[25];
  float* out = (float*)d_out;

  char* wsb = (char*)d_ws;
  size_t off = 0;
  auto alloc = [&](size_t nfloats) {
    float* p = (float*)(wsb + off);
    off = (off + nfloats * 4 + 255) & ~(size_t)255;
    return p;
  };
  float* h    = alloc((size_t)NT * CH);          // 33.6 MB
  float* hn   = alloc((size_t)S * CH);           // LN-out, later attention F
  float* q    = alloc((size_t)S * CH);           // also ppeg CHW buffer
  float* k    = alloc((size_t)S * CH);
  float* v    = alloc((size_t)S * CH);
  float* S1   = alloc((size_t)S * 256);          // per-head score buffer
  float* ql   = alloc(8 * 256 * 64);
  float* kl   = alloc(8 * 256 * 64);
  float* w3v  = alloc(8 * 256 * 64);
  float* Wm   = alloc(8 * 256 * 64);
  float* a2   = alloc(8 * 256 * 256);
  float* xz   = alloc(8 * 256 * 256);
  float* t1   = alloc(8 * 256 * 256);
  float* t2   = alloc(8 * 256 * 256);
  float* zA   = alloc(8 * 256 * 256);
  float* zB   = alloc(8 * 256 * 256);
  float* rs   = alloc(2048);
  float* cs   = alloc(2048);
  float* inv  = alloc(64);
  float* partial = alloc((size_t)65 * 256 * 64); // split-K partials (4.3 MB)
  (void)in_sizes; (void)n_in; (void)out_size; (void)ws_size;

  // h[0] = cls ; h[1..16384] = relu(X @ fc1^T + b)
  cls_copy<<<1, 512, 0, stream>>>(clstok, h);
  mm_kernel<true, 1><<<dim3(8, 256, 1), 256, 0, stream>>>(
      X, fc1w, h + CH, fc1b, 16384, 512, 1024, 1024, 1024, 512, 0, 0, 0, 1.f, 0.f, 0);

  run_attn(w1, h, hn, q, k, v, S1, ql, kl, w3v, Wm, a2, xz, t1, t2, zA, zB,
           rs, cs, inv, partial, stream);

  // PPEG: f = CHW(feat); h[1+p][c] = f + dw7 + dw5 + dw3
  transpose_feat<<<dim3(512, 16, 1), 256, 0, stream>>>(h, q);
  ppeg_conv<<<dim3(128, 512, 1), 128, 0, stream>>>(q, w7, b7, w5, b5, w3, b3, h);

  run_attn(w2, h, hn, q, k, v, S1, ql, kl, w3v, Wm, a2, xz, t1, t2, zA, zB,
           rs, cs, inv, partial, stream);

  final_k<<<1, 256, 0, stream>>>(h, lnfg, lnfb, fc2w, fc2b, out);
}

// Round 4
// 4152.572 us; speedup vs baseline: 2.7311x; 1.7830x over previous
//
#include <hip/hip_runtime.h>
#include <hip/hip_bf16.h>

static const int S    = 16640;  // padded sequence (65*256)
static const int PADR = 255;    // zero rows prepended inside attention
static const int NT   = 16385;  // tokens incl cls
static const int CH   = 512;    // hidden dim

typedef unsigned short u16;
typedef __attribute__((ext_vector_type(8))) short short8_t;
typedef __attribute__((ext_vector_type(4))) float float4_t;

__device__ __forceinline__ float b2f(u16 x) {
  union { unsigned u; float f; } t; t.u = (unsigned)x << 16; return t.f;
}
__device__ __forceinline__ u16 f2b(float x) {
  union { float f; unsigned u; } t; t.f = x;
  unsigned r = t.u + 0x7fff + ((t.u >> 16) & 1);
  return (u16)(r >> 16);
}

__device__ __forceinline__ float warpSum(float v) {
#pragma unroll
  for (int off = 32; off; off >>= 1) v += __shfl_xor(v, off);
  return v;
}
__device__ __forceinline__ float warpMax(float v) {
#pragma unroll
  for (int off = 32; off; off >>= 1) v = fmaxf(v, __shfl_xor(v, off));
  return v;
}
__device__ __forceinline__ float blockSum(float v) {
  __shared__ float sm[8];
  int lane = threadIdx.x & 63, wv = threadIdx.x >> 6;
  v = warpSum(v);
  __syncthreads();
  if (lane == 0) sm[wv] = v;
  __syncthreads();
  float t = 0.f;
  int nw = blockDim.x >> 6;
  for (int i = 0; i < nw; i++) t += sm[i];
  return t;
}
__device__ __forceinline__ float blockMax(float v) {
  __shared__ float sm[8];
  int lane = threadIdx.x & 63, wv = threadIdx.x >> 6;
  v = warpMax(v);
  __syncthreads();
  if (lane == 0) sm[wv] = v;
  __syncthreads();
  float t = -1e30f;
  int nw = blockDim.x >> 6;
  for (int i = 0; i < nw; i++) t = fmaxf(t, sm[i]);
  return t;
}

// ---------------------------------------------------------------------------
// f32 -> bf16 conversion (vectorized by 4)
__global__ __launch_bounds__(256) void cvt_f2b(const float* __restrict__ in,
                                               u16* __restrict__ out, long n) {
  long i = ((long)blockIdx.x * 256 + threadIdx.x) * 4;
  if (i + 3 < n) {
    float4 v = *(const float4*)(in + i);
    out[i] = f2b(v.x); out[i + 1] = f2b(v.y); out[i + 2] = f2b(v.z); out[i + 3] = f2b(v.w);
  } else {
    for (long j = i; j < n; j++) out[j] = f2b(in[j]);
  }
}

// ---------------------------------------------------------------------------
// MFMA bf16 GEMM: C(M,N) = A(M,K) * op(B), f32 accumulate.
//  BNN=0: B is (N,K) row-major (B^T form).  BNN=1: B is (K,N) row-major.
//  EPI 0: C = alpha*acc + bias? + beta*C (f32)
//  EPI 1: C = relu(acc + bias) (f32)
//  EPI 2: qkv head-split store bf16: cols [0,512)=q*alpha, [512,1024)=k, [1024,1536)=v
//  Split-K via blockIdx.z: k range [z*Kchunk, min(K, z*Kchunk+Kchunk)), C += z*zStrideC.
//  Requires: K % 32 == 0, Kchunk % 32 == 0, N % 16 == 0, 16B-aligned rows (lda/ldb % 8 == 0).
// ---------------------------------------------------------------------------
template <int BNN, int EPI>
__global__ __launch_bounds__(256) void mfma_gemm(
    const u16* __restrict__ A, const u16* __restrict__ B, float* __restrict__ C,
    const float* __restrict__ bias, int M, int N, int K,
    int lda, int ldb, int ldc, int Kchunk, long zStrideC,
    float alpha, float beta,
    u16* __restrict__ q_o, u16* __restrict__ k_o, u16* __restrict__ v_o, long s64)
{
  __shared__ u16 As[128][40];   // row stride 80B: 16B-aligned, spreads banks
  __shared__ u16 Bs[128][40];   // Bs[n][k]
  const int tid = threadIdx.x;
  const int m0 = blockIdx.y * 128, n0 = blockIdx.x * 128;
  const int kbeg = blockIdx.z * Kchunk;
  const int kend = min(K, kbeg + Kchunk);
  C += (long)blockIdx.z * zStrideC;
  const int wid = tid >> 6, lane = tid & 63;
  const int wr = wid >> 1, wc = wid & 1;
  const int l15 = lane & 15, l16 = lane >> 4;
  const int arow = tid >> 1, aseg = (tid & 1) * 16;
  float4_t acc[4][4] = {};

  for (int k0 = kbeg; k0 < kend; k0 += 32) {
    {
      int gm = m0 + arow;
      short8_t v0 = {}, v1 = {};
      if (gm < M) {
        const u16* src = A + (long)gm * lda + k0 + aseg;
        v0 = *(const short8_t*)src; v1 = *(const short8_t*)(src + 8);
      }
      *(short8_t*)&As[arow][aseg]     = v0;
      *(short8_t*)&As[arow][aseg + 8] = v1;
    }
    if constexpr (BNN == 0) {
      int gn = n0 + arow;
      short8_t v0 = {}, v1 = {};
      if (gn < N) {
        const u16* src = B + (long)gn * ldb + k0 + aseg;
        v0 = *(const short8_t*)src; v1 = *(const short8_t*)(src + 8);
      }
      *(short8_t*)&Bs[arow][aseg]     = v0;
      *(short8_t*)&Bs[arow][aseg + 8] = v1;
    } else {
      int kk = tid >> 3, nsg = (tid & 7) * 16;
      short8_t v0 = {}, v1 = {};
      if (n0 + nsg < N) {
        const u16* src = B + (long)(k0 + kk) * ldb + n0 + nsg;
        v0 = *(const short8_t*)src; v1 = *(const short8_t*)(src + 8);
      }
#pragma unroll
      for (int i = 0; i < 8; i++) {
        Bs[nsg + i][kk]     = (u16)v0[i];
        Bs[nsg + 8 + i][kk] = (u16)v1[i];
      }
    }
    __syncthreads();
    short8_t af[4], bfr[4];
#pragma unroll
    for (int i = 0; i < 4; i++)
      af[i] = *(const short8_t*)&As[wr * 64 + i * 16 + l15][l16 * 8];
#pragma unroll
    for (int i = 0; i < 4; i++)
      bfr[i] = *(const short8_t*)&Bs[wc * 64 + i * 16 + l15][l16 * 8];
#pragma unroll
    for (int i = 0; i < 4; i++)
#pragma unroll
      for (int j = 0; j < 4; j++)
        acc[i][j] = __builtin_amdgcn_mfma_f32_16x16x32_bf16(af[i], bfr[j], acc[i][j], 0, 0, 0);
    __syncthreads();
  }

#pragma unroll
  for (int mi = 0; mi < 4; mi++) {
#pragma unroll
    for (int ni = 0; ni < 4; ni++) {
#pragma unroll
      for (int j = 0; j < 4; j++) {
        int r = m0 + wr * 64 + mi * 16 + l16 * 4 + j;
        int c = n0 + wc * 64 + ni * 16 + l15;
        if (r >= M || c >= N) continue;
        float v = acc[mi][ni][j];
        if constexpr (EPI == 0) {
          long idx = (long)r * ldc + c;
          float o = alpha * v;
          if (bias) o += bias[c];
          if (beta != 0.f) o += beta * C[idx];
          C[idx] = o;
        } else if constexpr (EPI == 1) {
          long idx = (long)r * ldc + c;
          C[idx] = fmaxf(v + bias[c], 0.f);
        } else {  // EPI == 2: qkv split
          int sec = c >> 9, hcol = c & 511;
          int head = hcol >> 6, d = hcol & 63;
          u16* dst = (sec == 0) ? q_o : (sec == 1 ? k_o : v_o);
          float o = (sec == 0) ? v * alpha : v;
          dst[(long)head * s64 + (long)r * 64 + d] = f2b(o);
        }
      }
    }
  }
}

// ---------------------------------------------------------------------------
// SIMT f32 tiled matmul (kept for numerically-sensitive small GEMMs: a2, pinv, Wm)
template <bool BT, int MODE>
__global__ __launch_bounds__(256) void mm_kernel(
    const float* __restrict__ A, const float* __restrict__ Bm, float* __restrict__ C,
    const float* __restrict__ bias,
    int M, int N, int K, int lda, int ldb, int ldc,
    long sA, long sB, long sC, float alpha, float beta, long s64)
{
  __shared__ float As[16][64];
  __shared__ float Bs[16][64];
  const int bz = blockIdx.z;
  A  += (long)bz * sA;
  Bm += (long)bz * sB;
  C  += (long)bz * sC;
  const int m0 = blockIdx.y * 64, n0 = blockIdx.x * 64;
  const int tid = threadIdx.x;
  const int tm = tid >> 4, tn = tid & 15;
  const int ar = tid >> 2;
  const int ac = (tid & 3) << 2;
  float acc[4][4] = {};
  for (int k0 = 0; k0 < K; k0 += 16) {
#pragma unroll
    for (int i = 0; i < 4; i++) {
      int gm = m0 + ar, gk = k0 + ac + i;
      As[ac + i][ar] = (gm < M && gk < K) ? A[(long)gm * lda + gk] : 0.f;
    }
    if constexpr (BT) {
#pragma unroll
      for (int i = 0; i < 4; i++) {
        int gn = n0 + ar, gk = k0 + ac + i;
        Bs[ac + i][ar] = (gn < N && gk < K) ? Bm[(long)gn * ldb + gk] : 0.f;
      }
    } else {
      int bk = tid >> 4;
      int bn = (tid & 15) << 2;
#pragma unroll
      for (int i = 0; i < 4; i++) {
        int gk = k0 + bk, gn = n0 + bn + i;
        Bs[bk][bn + i] = (gk < K && gn < N) ? Bm[(long)gk * ldb + gn] : 0.f;
      }
    }
    __syncthreads();
#pragma unroll
    for (int kk = 0; kk < 16; kk++) {
      float a[4], b[4];
#pragma unroll
      for (int i = 0; i < 4; i++) { a[i] = As[kk][tm * 4 + i]; b[i] = Bs[kk][tn * 4 + i]; }
#pragma unroll
      for (int i = 0; i < 4; i++)
#pragma unroll
        for (int j = 0; j < 4; j++)
          acc[i][j] = fmaf(a[i], b[j], acc[i][j]);
    }
    __syncthreads();
  }
#pragma unroll
  for (int i = 0; i < 4; i++) {
    int row = m0 + tm * 4 + i;
    if (row >= M) continue;
#pragma unroll
    for (int j = 0; j < 4; j++) {
      int col = n0 + tn * 4 + j;
      if (col >= N) continue;
      float v = alpha * acc[i][j];
      if (bias) v += bias[col];
      if constexpr (MODE == 1) v = fmaxf(v, 0.f);
      long idx = (long)row * ldc + col;
      C[idx] = (beta != 0.f) ? v + beta * C[idx] : v;
    }
  }
}

// ---------------------------------------------------------------------------
__global__ void cls_copy(const float* __restrict__ c, float* __restrict__ h) {
  h[threadIdx.x] = c[threadIdx.x];
}

// LN of h rows -> padded bf16 buffer (rows [0,PADR) zero)
__global__ __launch_bounds__(256) void ln_pad_b(const float* __restrict__ h,
    const float* __restrict__ g, const float* __restrict__ b,
    u16* __restrict__ out, int pad)
{
  int s = blockIdx.x, t = threadIdx.x;
  u16* o = out + (long)s * CH;
  if (s < pad) { o[t] = 0; o[t + 256] = 0; return; }
  const float* x = h + (long)(s - pad) * CH;
  float x0 = x[t], x1 = x[t + 256];
  float mu = blockSum(x0 + x1) * (1.f / 512.f);
  float d0 = x0 - mu, d1 = x1 - mu;
  float var = blockSum(d0 * d0 + d1 * d1) * (1.f / 512.f);
  float rs = rsqrtf(var + 1e-5f);
  o[t]       = f2b(d0 * rs * g[t]       + b[t]);
  o[t + 256] = f2b(d1 * rs * g[t + 256] + b[t + 256]);
}

// landmark means from bf16 q/k -> f32 + bf16 outputs
__global__ __launch_bounds__(64) void landmark_b(const u16* __restrict__ q,
    float* __restrict__ ql, u16* __restrict__ qlb) {
  int hb = blockIdx.x;
  int d = threadIdx.x;
  int hh = hb >> 8, j = hb & 255;
  const u16* src = q + ((long)hh * S + (long)j * 65) * 64 + d;
  float s = 0.f;
  for (int g2 = 0; g2 < 65; g2++) s += b2f(src[(long)g2 * 64]);
  s *= (1.f / 65.f);
  ql[(long)hb * 64 + d] = s;
  qlb[(long)hb * 64 + d] = f2b(s);
}

// in-place f32 row softmax over 256 columns (a2)
__global__ __launch_bounds__(256) void rowsoftmax(float* __restrict__ X) {
  float* row = X + (long)blockIdx.x * 256;
  int t = threadIdx.x;
  float x = row[t];
  float m = blockMax(x);
  float e = __expf(x - m);
  float s = blockSum(e);
  row[t] = e / s;
}

// f32 row softmax over 256 cols -> bf16 out (a1 path)
__global__ __launch_bounds__(256) void rowsoftmax_b(const float* __restrict__ X,
                                                    u16* __restrict__ Y) {
  const float* row = X + (long)blockIdx.x * 256;
  u16* o = Y + (long)blockIdx.x * 256;
  int t = threadIdx.x;
  float x = row[t];
  float m = blockMax(x);
  float e = __expf(x - m);
  float s = blockSum(e);
  o[t] = f2b(e / s);
}

// f32 row softmax over 16640 cols -> bf16 out
__global__ __launch_bounds__(256) void softmax_wide_b(const float* __restrict__ X,
                                                      u16* __restrict__ Y) {
  const float* row = X + (long)blockIdx.x * 16640;
  u16* orow = Y + (long)blockIdx.x * 16640;
  int t = threadIdx.x;
  float r[65];
  float m = -1e30f;
#pragma unroll
  for (int i = 0; i < 65; i++) { r[i] = row[i * 256 + t]; m = fmaxf(m, r[i]); }
  m = blockMax(m);
  float s = 0.f;
#pragma unroll
  for (int i = 0; i < 65; i++) { r[i] = __expf(r[i] - m); s += r[i]; }
  s = blockSum(s);
  float inv = 1.f / s;
#pragma unroll
  for (int i = 0; i < 65; i++) orow[i * 256 + t] = f2b(r[i] * inv);
}

// w3v_h[i] = sum over 40 split-K partials
__global__ __launch_bounds__(256) void a3v_reduce(const float* __restrict__ partial,
                                                  float* __restrict__ w3v) {
  int i = blockIdx.x * 256 + threadIdx.x;
  float s = 0.f;
  for (int sp = 0; sp < 40; sp++) s += partial[(long)sp * 16384 + i];
  w3v[i] = s;
}

__global__ __launch_bounds__(256) void rowabs(const float* __restrict__ a2, float* __restrict__ rs) {
  int r = blockIdx.x;
  float s = blockSum(fabsf(a2[(long)r * 256 + threadIdx.x]));
  if (threadIdx.x == 0) rs[r] = s;
}
__global__ __launch_bounds__(256) void colabs(const float* __restrict__ a2, float* __restrict__ cs) {
  int hb = blockIdx.x; int hh = hb >> 8, j = hb & 255;
  float s = blockSum(fabsf(a2[((long)hh * 256 + threadIdx.x) * 256 + j]));
  if (threadIdx.x == 0) cs[hb] = s;
}
__global__ __launch_bounds__(256) void scaleinv(const float* __restrict__ rs,
                                                const float* __restrict__ cs, float* __restrict__ inv) {
  float m1 = -1e30f, m2 = -1e30f;
  for (int i = threadIdx.x; i < 2048; i += 256) { m1 = fmaxf(m1, rs[i]); m2 = fmaxf(m2, cs[i]); }
  m1 = blockMax(m1);
  m2 = blockMax(m2);
  if (threadIdx.x == 0) inv[0] = 1.f / (m1 * m2);
}
__global__ __launch_bounds__(256) void z0k(const float* __restrict__ a2,
                                           const float* __restrict__ inv, float* __restrict__ z) {
  int hb = blockIdx.x; int hh = hb >> 8, i = hb & 255; int j = threadIdx.x;
  z[(long)hb * 256 + j] = a2[((long)hh * 256 + j) * 256 + i] * inv[0];
}
__global__ __launch_bounds__(256) void aIminus(const float* __restrict__ X, float* __restrict__ Y, float c) {
  long r = blockIdx.x; int i = (int)(r & 255); int j = threadIdx.x;
  Y[r * 256 + j] = ((j == i) ? c : 0.f) - X[r * 256 + j];
}

// depthwise residual conv along sequence (kernel 33, pad 16), F += conv(v), v bf16
__global__ __launch_bounds__(64) void resconv(const u16* __restrict__ v,
    const float* __restrict__ w, float* __restrict__ F)
{
  int s = blockIdx.x, hh = blockIdx.y, d = threadIdx.x;
  const u16* vh = v + (long)hh * S * 64;
  float a = 0.f;
  for (int t = 0; t < 33; t++) {
    int j = s + t - 16;
    if (0 <= j && j < S) a += w[hh * 33 + t] * b2f(vh[(long)j * 64 + d]);
  }
  F[(long)s * CH + hh * 64 + d] += a;
}

// h feat rows (1..16384, 512 cols) -> f (512, 16384) CHW
__global__ __launch_bounds__(256) void transpose_feat(const float* __restrict__ h, float* __restrict__ f) {
  __shared__ float tile[32][33];
  int p0 = blockIdx.x * 32;
  int c0 = blockIdx.y * 32;
  int tx = threadIdx.x & 31, ty = threadIdx.x >> 5;
  for (int i = 0; i < 32; i += 8)
    tile[ty + i][tx] = h[(long)(1 + p0 + ty + i) * CH + c0 + tx];
  __syncthreads();
  for (int i = 0; i < 32; i += 8)
    f[(long)(c0 + ty + i) * 16384 + p0 + tx] = tile[tx][ty + i];
}

// h[1+p][c] = f + dw7 + dw5 + dw3 (+biases)
__global__ __launch_bounds__(128) void ppeg_conv(const float* __restrict__ f,
    const float* __restrict__ w7, const float* __restrict__ b7,
    const float* __restrict__ w5, const float* __restrict__ b5,
    const float* __restrict__ w3, const float* __restrict__ b3,
    float* __restrict__ h)
{
  int y = blockIdx.x, c = blockIdx.y, x = threadIdx.x;
  __shared__ float W7s[49], W5s[25], W3s[9];
  if (x < 49) W7s[x] = w7[c * 49 + x];
  if (x < 25) W5s[x] = w5[c * 25 + x];
  if (x < 9)  W3s[x] = w3[c * 9 + x];
  __syncthreads();
  const float* fc = f + (long)c * 16384;
  float acc = fc[y * 128 + x] + b7[c] + b5[c] + b3[c];
#pragma unroll
  for (int dy = 0; dy < 7; dy++) {
    int yy = y + dy - 3; if (yy < 0 || yy >= 128) continue;
    const float* row = fc + yy * 128;
#pragma unroll
    for (int dx = 0; dx < 7; dx++) {
      int xx = x + dx - 3; if (xx < 0 || xx >= 128) continue;
      acc += W7s[dy * 7 + dx] * row[xx];
    }
  }
#pragma unroll
  for (int dy = 0; dy < 5; dy++) {
    int yy = y + dy - 2; if (yy < 0 || yy >= 128) continue;
    const float* row = fc + yy * 128;
#pragma unroll
    for (int dx = 0; dx < 5; dx++) {
      int xx = x + dx - 2; if (xx < 0 || xx >= 128) continue;
      acc += W5s[dy * 5 + dx] * row[xx];
    }
  }
#pragma unroll
  for (int dy = 0; dy < 3; dy++) {
    int yy = y + dy - 1; if (yy < 0 || yy >= 128) continue;
    const float* row = fc + yy * 128;
#pragma unroll
    for (int dx = 0; dx < 3; dx++) {
      int xx = x + dx - 1; if (xx < 0 || xx >= 128) continue;
      acc += W3s[dy * 3 + dx] * row[xx];
    }
  }
  h[(long)(1 + y * 128 + x) * CH + c] = acc;
}

// final: LN(h row 0) then 2-class head, f32 out
__global__ __launch_bounds__(256) void final_k(const float* __restrict__ h,
    const float* __restrict__ g, const float* __restrict__ b,
    const float* __restrict__ w, const float* __restrict__ fb, float* __restrict__ out)
{
  int t = threadIdx.x;
  float x0 = h[t], x1 = h[t + 256];
  float mu = blockSum(x0 + x1) * (1.f / 512.f);
  float d0 = x0 - mu, d1 = x1 - mu;
  float var = blockSum(d0 * d0 + d1 * d1) * (1.f / 512.f);
  float rs = rsqrtf(var + 1e-5f);
  float y0 = d0 * rs * g[t]       + b[t];
  float y1 = d1 * rs * g[t + 256] + b[t + 256];
  float s0 = blockSum(y0 * w[t]       + y1 * w[t + 256]);
  float s1 = blockSum(y0 * w[512 + t] + y1 * w[512 + t + 256]);
  if (t == 0) {
    out[0] = s0 + fb[0];
    out[1] = s1 + fb[1];
  }
}

// ---------------------------------------------------------------------------
struct AttnW {
  const float *lng, *lnb, *qkvw, *outw, *outb, *resw;
};

static void run_attn(const AttnW& Wt, const u16* qkvw_b, const u16* outw_b,
                     float* h, u16* hn_b, u16* qb, u16* kb, u16* vb, float* F,
                     float* S1, u16* S1b, float* ql, float* kl, u16* qlb, u16* klb,
                     float* w3v, float* Wm, u16* Wm_b,
                     float* a2, float* xz, float* t1, float* t2, float* zA, float* zB,
                     float* rs, float* cs, float* inv, float* partial,
                     hipStream_t stream)
{
  const long s64 = (long)S * 64;
  ln_pad_b<<<S, 256, 0, stream>>>(h, Wt.lng, Wt.lnb, hn_b, PADR);
  // fused qkv: (S,1536) = hn_b @ qkvw^T, head-split bf16 store, q scaled 0.125
  mfma_gemm<0, 2><<<dim3(12, 130, 1), 256, 0, stream>>>(
      hn_b, qkvw_b, nullptr, nullptr, S, 1536, 512, 512, 512, 0, 512, 0,
      0.125f, 0.f, qb, kb, vb, s64);
  landmark_b<<<2048, 64, 0, stream>>>(qb, ql, qlb);
  landmark_b<<<2048, 64, 0, stream>>>(kb, kl, klb);
  // a2 = softmax(ql @ kl^T) — f32 SIMT (feeds ill-conditioned pinv)
  mm_kernel<true, 0><<<dim3(4, 4, 8), 256, 0, stream>>>(
      ql, kl, a2, nullptr, 256, 256, 64, 64, 64, 256, 16384, 16384, 65536, 1.f, 0.f, 0);
  rowsoftmax<<<2048, 256, 0, stream>>>(a2);
  rowabs<<<2048, 256, 0, stream>>>(a2, rs);
  colabs<<<2048, 256, 0, stream>>>(a2, cs);
  scaleinv<<<1, 256, 0, stream>>>(rs, cs, inv);
  z0k<<<2048, 256, 0, stream>>>(a2, inv, zA);
  float* zc = zA; float* zo = zB;
  for (int it = 0; it < 6; it++) {
    mm_kernel<false, 0><<<dim3(4, 4, 8), 256, 0, stream>>>(
        a2, zc, xz, nullptr, 256, 256, 256, 256, 256, 256, 65536, 65536, 65536, 1.f, 0.f, 0);
    aIminus<<<2048, 256, 0, stream>>>(xz, t1, 7.f);
    mm_kernel<false, 0><<<dim3(4, 4, 8), 256, 0, stream>>>(
        xz, t1, t2, nullptr, 256, 256, 256, 256, 256, 256, 65536, 65536, 65536, 1.f, 0.f, 0);
    aIminus<<<2048, 256, 0, stream>>>(t2, t1, 15.f);
    mm_kernel<false, 0><<<dim3(4, 4, 8), 256, 0, stream>>>(
        xz, t1, t2, nullptr, 256, 256, 256, 256, 256, 256, 65536, 65536, 65536, 1.f, 0.f, 0);
    aIminus<<<2048, 256, 0, stream>>>(t2, t1, 13.f);
    mm_kernel<false, 0><<<dim3(4, 4, 8), 256, 0, stream>>>(
        zc, t1, zo, nullptr, 256, 256, 256, 256, 256, 256, 65536, 65536, 65536, 0.25f, 0.f, 0);
    float* tmp = zc; zc = zo; zo = tmp;
  }
  // a3 path per head: scores (256,S) -> softmax -> @ v (split-K 40)
  for (int hh = 0; hh < 8; hh++) {
    mfma_gemm<0, 0><<<dim3(130, 2, 1), 256, 0, stream>>>(
        qlb + hh * 16384, kb + hh * s64, S1, nullptr,
        256, S, 64, 64, 64, 16640, 64, 0, 1.f, 0.f, nullptr, nullptr, nullptr, 0);
    softmax_wide_b<<<256, 256, 0, stream>>>(S1, S1b);
    mfma_gemm<1, 0><<<dim3(1, 2, 40), 256, 0, stream>>>(
        S1b, vb + hh * s64, partial, nullptr,
        256, 64, S, 16640, 64, 64, 416, 16384, 1.f, 0.f, nullptr, nullptr, nullptr, 0);
    a3v_reduce<<<64, 256, 0, stream>>>(partial, w3v + hh * 16384);
  }
  // Wm = pinv(a2) @ w3v — f32 SIMT
  mm_kernel<false, 0><<<dim3(1, 4, 8), 256, 0, stream>>>(
      zc, w3v, Wm, nullptr, 256, 64, 256, 256, 64, 64, 65536, 16384, 16384, 1.f, 0.f, 0);
  cvt_f2b<<<128, 256, 0, stream>>>(Wm, Wm_b, 131072);
  // a1 path per head: scores (S,256) -> softmax -> @ Wm into F columns
  for (int hh = 0; hh < 8; hh++) {
    mfma_gemm<0, 0><<<dim3(2, 130, 1), 256, 0, stream>>>(
        qb + hh * s64, klb + hh * 16384, S1, nullptr,
        S, 256, 64, 64, 64, 256, 64, 0, 1.f, 0.f, nullptr, nullptr, nullptr, 0);
    rowsoftmax_b<<<S, 256, 0, stream>>>(S1, S1b);
    mfma_gemm<1, 0><<<dim3(1, 130, 1), 256, 0, stream>>>(
        S1b, Wm_b + hh * 16384, F + hh * 64, nullptr,
        S, 64, 256, 256, 64, 512, 256, 0, 1.f, 0.f, nullptr, nullptr, nullptr, 0);
  }
  resconv<<<dim3(S, 8, 1), 64, 0, stream>>>(vb, Wt.resw, F);
  // h += F[PADR:, :] @ outw^T + outb   (A converted to bf16 into Fb := S1 region)
  u16* Fb = (u16*)S1;
  cvt_f2b<<<8193, 256, 0, stream>>>(F + (long)PADR * CH, Fb, (long)NT * CH);
  mfma_gemm<0, 0><<<dim3(4, 129, 1), 256, 0, stream>>>(
      Fb, outw_b, h, Wt.outb, NT, 512, 512, 512, 512, 512, 512, 0,
      1.f, 1.f, nullptr, nullptr, nullptr, 0);
}

extern "C" void kernel_launch(void* const* d_in, const int* in_sizes, int n_in,
                              void* d_out, int out_size, void* d_ws, size_t ws_size,
                              hipStream_t stream)
{
  const float* X      = (const float*)d_in[0];
  const float* fc1w   = (const float*)d_in[1];
  const float* fc1b   = (const float*)d_in[2];
  const float* clstok = (const float*)d_in[3];
  AttnW w1{ (const float*)d_in[4], (const float*)d_in[5], (const float*)d_in[6],
            (const float*)d_in[7], (const float*)d_in[8], (const float*)d_in[9] };
  const float* w7 = (const float*)d_in[10]; const float* b7 = (const float*)d_in[11];
  const float* w5 = (const float*)d_in[12]; const float* b5 = (const float*)d_in[13];
  const float* w3 = (const float*)d_in[14]; const float* b3 = (const float*)d_in[15];
  AttnW w2{ (const float*)d_in[16], (const float*)d_in[17], (const float*)d_in[18],
            (const float*)d_in[19], (const float*)d_in[20], (const float*)d_in[21] };
  const float* lnfg = (const float*)d_in[22];
  const float* lnfb = (const float*)d_in[23];
  const float* fc2w = (const float*)d_in[24];
  const float* fc2b = (const float*)d_in[25];
  float* out = (float*)d_out;

  char* wsb = (char*)d_ws;
  size_t off = 0;
  auto alloc = [&](size_t nbytes) {
    void* p = wsb + off;
    off = (off + nbytes + 255) & ~(size_t)255;
    return p;
  };
  float* h    = (float*)alloc((size_t)NT * CH * 4);
  float* F    = (float*)alloc((size_t)S * CH * 4);
  u16*  hn_b  = (u16*)alloc((size_t)S * CH * 2);
  u16*  qb    = (u16*)alloc((size_t)S * CH * 2);
  u16*  kb    = (u16*)alloc((size_t)S * CH * 2);
  u16*  vb    = (u16*)alloc((size_t)S * CH * 2);
  float* S1   = (float*)alloc((size_t)S * 256 * 4);   // also reused as Fb (bf16)
  u16*  S1b   = (u16*)alloc((size_t)S * 256 * 2);
  char* big   = (char*)alloc(33554432);               // Xb (bf16) / ppeg f (f32)
  u16*  fc1w_b = (u16*)alloc(524288 * 2);
  u16*  qkv1_b = (u16*)alloc(786432 * 2);
  u16*  qkv2_b = (u16*)alloc(786432 * 2);
  u16*  out1_b = (u16*)alloc(262144 * 2);
  u16*  out2_b = (u16*)alloc(262144 * 2);
  float* ql   = (float*)alloc(131072 * 4);
  float* kl   = (float*)alloc(131072 * 4);
  u16*  qlb   = (u16*)alloc(131072 * 2);
  u16*  klb   = (u16*)alloc(131072 * 2);
  float* w3v  = (float*)alloc(131072 * 4);
  float* Wm   = (float*)alloc(131072 * 4);
  u16*  Wm_b  = (u16*)alloc(131072 * 2);
  float* a2   = (float*)alloc(524288 * 4);
  float* xz   = (float*)alloc(524288 * 4);
  float* t1   = (float*)alloc(524288 * 4);
  float* t2   = (float*)alloc(524288 * 4);
  float* zA   = (float*)alloc(524288 * 4);
  float* zB   = (float*)alloc(524288 * 4);
  float* rs   = (float*)alloc(2048 * 4);
  float* cs   = (float*)alloc(2048 * 4);
  float* inv  = (float*)alloc(256);
  float* partial = (float*)alloc((size_t)40 * 16384 * 4);
  (void)in_sizes; (void)n_in; (void)out_size; (void)ws_size;

  // weight + input conversions (deterministic, every launch)
  u16* Xb = (u16*)big;
  cvt_f2b<<<16384, 256, 0, stream>>>(X, Xb, (long)16384 * 1024);
  cvt_f2b<<<512, 256, 0, stream>>>(fc1w, fc1w_b, 524288);
  cvt_f2b<<<768, 256, 0, stream>>>(w1.qkvw, qkv1_b, 786432);
  cvt_f2b<<<768, 256, 0, stream>>>(w2.qkvw, qkv2_b, 786432);
  cvt_f2b<<<256, 256, 0, stream>>>(w1.outw, out1_b, 262144);
  cvt_f2b<<<256, 256, 0, stream>>>(w2.outw, out2_b, 262144);

  // h[0] = cls ; h[1..16384] = relu(X @ fc1^T + b)
  cls_copy<<<1, 512, 0, stream>>>(clstok, h);
  mfma_gemm<0, 1><<<dim3(4, 128, 1), 256, 0, stream>>>(
      Xb, fc1w_b, h + CH, fc1b, 16384, 512, 1024, 1024, 1024, 512, 1024, 0,
      1.f, 0.f, nullptr, nullptr, nullptr, 0);

  run_attn(w1, qkv1_b, out1_b, h, hn_b, qb, kb, vb, F, S1, S1b, ql, kl, qlb, klb,
           w3v, Wm, Wm_b, a2, xz, t1, t2, zA, zB, rs, cs, inv, partial, stream);

  // PPEG
  float* fppeg = (float*)big;
  transpose_feat<<<dim3(512, 16, 1), 256, 0, stream>>>(h, fppeg);
  ppeg_conv<<<dim3(128, 512, 1), 128, 0, stream>>>(fppeg, w7, b7, w5, b5, w3, b3, h);

  run_attn(w2, qkv2_b, out2_b, h, hn_b, qb, kb, vb, F, S1, S1b, ql, kl, qlb, klb,
           w3v, Wm, Wm_b, a2, xz, t1, t2, zA, zB, rs, cs, inv, partial, stream);

  final_k<<<1, 256, 0, stream>>>(h, lnfg, lnfb, fc2w, fc2b, out);
}

// Round 5
// 3916.359 us; speedup vs baseline: 2.8958x; 1.0603x over previous
//
#include <hip/hip_runtime.h>
#include <hip/hip_bf16.h>

static const int S    = 16640;  // padded sequence (65*256)
static const int PADR = 255;    // zero rows prepended inside attention
static const int NT   = 16385;  // tokens incl cls
static const int CH   = 512;    // hidden dim

typedef unsigned short u16;
typedef __attribute__((ext_vector_type(8))) short short8_t;
typedef __attribute__((ext_vector_type(4))) float float4_t;

__device__ __forceinline__ float b2f(u16 x) {
  union { unsigned u; float f; } t; t.u = (unsigned)x << 16; return t.f;
}
__device__ __forceinline__ u16 f2b(float x) {
  union { float f; unsigned u; } t; t.f = x;
  unsigned r = t.u + 0x7fff + ((t.u >> 16) & 1);
  return (u16)(r >> 16);
}

__device__ __forceinline__ float warpSum(float v) {
#pragma unroll
  for (int off = 32; off; off >>= 1) v += __shfl_xor(v, off);
  return v;
}
__device__ __forceinline__ float warpMax(float v) {
#pragma unroll
  for (int off = 32; off; off >>= 1) v = fmaxf(v, __shfl_xor(v, off));
  return v;
}
__device__ __forceinline__ float blockSum(float v) {
  __shared__ float sm[8];
  int lane = threadIdx.x & 63, wv = threadIdx.x >> 6;
  v = warpSum(v);
  __syncthreads();
  if (lane == 0) sm[wv] = v;
  __syncthreads();
  float t = 0.f;
  int nw = blockDim.x >> 6;
  for (int i = 0; i < nw; i++) t += sm[i];
  return t;
}
__device__ __forceinline__ float blockMax(float v) {
  __shared__ float sm[8];
  int lane = threadIdx.x & 63, wv = threadIdx.x >> 6;
  v = warpMax(v);
  __syncthreads();
  if (lane == 0) sm[wv] = v;
  __syncthreads();
  float t = -1e30f;
  int nw = blockDim.x >> 6;
  for (int i = 0; i < nw; i++) t = fmaxf(t, sm[i]);
  return t;
}

// ---------------------------------------------------------------------------
__global__ __launch_bounds__(256) void cvt_f2b(const float* __restrict__ in,
                                               u16* __restrict__ out, long n) {
  long i = ((long)blockIdx.x * 256 + threadIdx.x) * 4;
  if (i + 3 < n) {
    float4 v = *(const float4*)(in + i);
    out[i] = f2b(v.x); out[i + 1] = f2b(v.y); out[i + 2] = f2b(v.z); out[i + 3] = f2b(v.w);
  } else {
    for (long j = i; j < n; j++) out[j] = f2b(in[j]);
  }
}

// WmT[head][n(64)][k(256)] bf16 <- Wm[head][k(256)][n(64)] f32
__global__ __launch_bounds__(256) void wm_transpose(const float* __restrict__ Wm,
                                                    u16* __restrict__ WmT) {
  int n = blockIdx.x, head = blockIdx.y, k = threadIdx.x;
  WmT[((long)head * 64 + n) * 256 + k] = f2b(Wm[(long)head * 16384 + k * 64 + n]);
}

// ---------------------------------------------------------------------------
// MFMA bf16 GEMM (verified layouts): C(M,N) = A(M,K) * B^T, f32 accumulate.
//  EPI 0: C = alpha*acc + bias? + beta*C (f32)
//  EPI 1: C = relu(acc + bias) (f32)
//  EPI 2: qkv head-split store bf16
// ---------------------------------------------------------------------------
template <int EPI>
__global__ __launch_bounds__(256) void mfma_gemm(
    const u16* __restrict__ A, const u16* __restrict__ B, float* __restrict__ C,
    const float* __restrict__ bias, int M, int N, int K,
    int lda, int ldb, int ldc,
    float alpha, float beta,
    u16* __restrict__ q_o, u16* __restrict__ k_o, u16* __restrict__ v_o, long s64)
{
  __shared__ u16 As[128][40];
  __shared__ u16 Bs[128][40];
  const int tid = threadIdx.x;
  const int m0 = blockIdx.y * 128, n0 = blockIdx.x * 128;
  const int wid = tid >> 6, lane = tid & 63;
  const int wr = wid >> 1, wc = wid & 1;
  const int l15 = lane & 15, l16 = lane >> 4;
  const int arow = tid >> 1, aseg = (tid & 1) * 16;
  float4_t acc[4][4] = {};

  for (int k0 = 0; k0 < K; k0 += 32) {
    {
      int gm = m0 + arow;
      short8_t v0 = {}, v1 = {};
      if (gm < M) {
        const u16* src = A + (long)gm * lda + k0 + aseg;
        v0 = *(const short8_t*)src; v1 = *(const short8_t*)(src + 8);
      }
      *(short8_t*)&As[arow][aseg]     = v0;
      *(short8_t*)&As[arow][aseg + 8] = v1;
    }
    {
      int gn = n0 + arow;
      short8_t v0 = {}, v1 = {};
      if (gn < N) {
        const u16* src = B + (long)gn * ldb + k0 + aseg;
        v0 = *(const short8_t*)src; v1 = *(const short8_t*)(src + 8);
      }
      *(short8_t*)&Bs[arow][aseg]     = v0;
      *(short8_t*)&Bs[arow][aseg + 8] = v1;
    }
    __syncthreads();
    short8_t af[4], bfr[4];
#pragma unroll
    for (int i = 0; i < 4; i++)
      af[i] = *(const short8_t*)&As[wr * 64 + i * 16 + l15][l16 * 8];
#pragma unroll
    for (int i = 0; i < 4; i++)
      bfr[i] = *(const short8_t*)&Bs[wc * 64 + i * 16 + l15][l16 * 8];
#pragma unroll
    for (int i = 0; i < 4; i++)
#pragma unroll
      for (int j = 0; j < 4; j++)
        acc[i][j] = __builtin_amdgcn_mfma_f32_16x16x32_bf16(af[i], bfr[j], acc[i][j], 0, 0, 0);
    __syncthreads();
  }

#pragma unroll
  for (int mi = 0; mi < 4; mi++) {
#pragma unroll
    for (int ni = 0; ni < 4; ni++) {
#pragma unroll
      for (int j = 0; j < 4; j++) {
        int r = m0 + wr * 64 + mi * 16 + l16 * 4 + j;
        int c = n0 + wc * 64 + ni * 16 + l15;
        if (r >= M || c >= N) continue;
        float v = acc[mi][ni][j];
        if constexpr (EPI == 0) {
          long idx = (long)r * ldc + c;
          float o = alpha * v;
          if (bias) o += bias[c];
          if (beta != 0.f) o += beta * C[idx];
          C[idx] = o;
        } else if constexpr (EPI == 1) {
          long idx = (long)r * ldc + c;
          C[idx] = fmaxf(v + bias[c], 0.f);
        } else {  // EPI == 2: qkv split
          int sec = c >> 9, hcol = c & 511;
          int head = hcol >> 6, d = hcol & 63;
          u16* dst = (sec == 0) ? q_o : (sec == 1 ? k_o : v_o);
          float o = (sec == 0) ? v * alpha : v;
          dst[(long)head * s64 + (long)r * 64 + d] = f2b(o);
        }
      }
    }
  }
}

// ---------------------------------------------------------------------------
// Fused a1 path: F[s][head*64+d] = softmax(q_h[s,:] @ kl_h^T) @ Wm_h
// grid (260 row-tiles, 8 heads), 256 thr (4 waves x 16 rows).
__global__ __launch_bounds__(256) void attn_a1(
    const u16* __restrict__ qb, const u16* __restrict__ klb,
    const u16* __restrict__ WmT, float* __restrict__ F, long s64)
{
  __shared__ u16 Ps[4][16][264];
  const int tid = threadIdx.x;
  const int w = tid >> 6, lane = tid & 63;
  const int l15 = lane & 15, l16 = lane >> 4;
  const int head = blockIdx.y;
  const int row0 = blockIdx.x * 64 + w * 16;

  // Q A-frags (row=l15, k=slab*32 + l16*8 + j)
  short8_t aq[2];
#pragma unroll
  for (int slab = 0; slab < 2; slab++)
    aq[slab] = *(const short8_t*)(qb + (long)head * s64 + (long)(row0 + l15) * 64 + slab * 32 + l16 * 8);

  // scores 16x256
  float4_t sacc[16] = {};
  const u16* klh = klb + (long)head * 16384;
#pragma unroll
  for (int nt = 0; nt < 16; nt++) {
#pragma unroll
    for (int slab = 0; slab < 2; slab++) {
      short8_t bfr = *(const short8_t*)(klh + (long)(nt * 16 + l15) * 64 + slab * 32 + l16 * 8);
      sacc[nt] = __builtin_amdgcn_mfma_f32_16x16x32_bf16(aq[slab], bfr, sacc[nt], 0, 0, 0);
    }
  }
  // softmax per row (rows r = 4*l16+reg; cols = nt*16 + l15)
  float rcp[4];
#pragma unroll
  for (int reg = 0; reg < 4; reg++) {
    float m = -1e30f;
#pragma unroll
    for (int nt = 0; nt < 16; nt++) m = fmaxf(m, sacc[nt][reg]);
#pragma unroll
    for (int mk = 1; mk <= 8; mk <<= 1) m = fmaxf(m, __shfl_xor(m, mk));
    float s = 0.f;
#pragma unroll
    for (int nt = 0; nt < 16; nt++) { float e = __expf(sacc[nt][reg] - m); sacc[nt][reg] = e; s += e; }
#pragma unroll
    for (int mk = 1; mk <= 8; mk <<= 1) s += __shfl_xor(s, mk);
    rcp[reg] = 1.f / s;
  }
  // store unnormalized P to LDS (per-wave region)
#pragma unroll
  for (int nt = 0; nt < 16; nt++)
#pragma unroll
    for (int reg = 0; reg < 4; reg++)
      Ps[w][4 * l16 + reg][nt * 16 + l15] = f2b(sacc[nt][reg]);
  __syncthreads();
  // PV: P(16x256) @ Wm(256x64) via WmT[n][k]
  float4_t oacc[4] = {};
  const u16* wmh = WmT + (long)head * 16384;
#pragma unroll
  for (int ks = 0; ks < 8; ks++) {
    short8_t pa = *(const short8_t*)&Ps[w][l15][ks * 32 + l16 * 8];
#pragma unroll
    for (int vt = 0; vt < 4; vt++) {
      short8_t bv = *(const short8_t*)(wmh + (long)(vt * 16 + l15) * 256 + ks * 32 + l16 * 8);
      oacc[vt] = __builtin_amdgcn_mfma_f32_16x16x32_bf16(pa, bv, oacc[vt], 0, 0, 0);
    }
  }
#pragma unroll
  for (int vt = 0; vt < 4; vt++)
#pragma unroll
    for (int reg = 0; reg < 4; reg++) {
      int r = row0 + 4 * l16 + reg;
      F[(long)r * CH + head * 64 + vt * 16 + l15] = oacc[vt][reg] * rcp[reg];
    }
}

// ---------------------------------------------------------------------------
// Fused a3@v: w3v_h = softmax(ql_h @ k_h^T) @ v_h  (online over 130 key-tiles)
// grid (4 row-quarters, 8 heads), 256 thr (4 waves x 16 rows).
__global__ __launch_bounds__(256) void attn_a3v(
    const u16* __restrict__ qlb, const u16* __restrict__ kb,
    const u16* __restrict__ vb, float* __restrict__ w3v, long s64)
{
  __shared__ u16 Vt[64][136];       // V^T tile: [d][key]
  __shared__ u16 Ps[4][16][136];
  const int tid = threadIdx.x;
  const int w = tid >> 6, lane = tid & 63;
  const int l15 = lane & 15, l16 = lane >> 4;
  const int head = blockIdx.y;
  const int row0 = blockIdx.x * 64 + w * 16;

  short8_t aq[2];
#pragma unroll
  for (int slab = 0; slab < 2; slab++)
    aq[slab] = *(const short8_t*)(qlb + (long)head * 16384 + (long)(row0 + l15) * 64 + slab * 32 + l16 * 8);

  float m[4], l[4];
  float4_t oacc[4] = {};
#pragma unroll
  for (int r = 0; r < 4; r++) { m[r] = -1e30f; l[r] = 0.f; }

  const u16* kh = kb + (long)head * s64;
  const u16* vh = vb + (long)head * s64;
  const int vrow = tid >> 1, vhalf = (tid & 1) * 32;

  for (int kt = 0; kt < 130; kt++) {
    const int j0 = kt * 128;
    __syncthreads();   // protect prior-iter Vt reads
    // stage V^T: Vt[d][key]
    {
      const u16* src = vh + (long)(j0 + vrow) * 64 + vhalf;
#pragma unroll
      for (int i = 0; i < 32; i++) Vt[vhalf + i][vrow] = src[i];
    }
    // scores 16x128
    float4_t sacc[8] = {};
#pragma unroll
    for (int nt = 0; nt < 8; nt++) {
#pragma unroll
      for (int slab = 0; slab < 2; slab++) {
        short8_t bfr = *(const short8_t*)(kh + (long)(j0 + nt * 16 + l15) * 64 + slab * 32 + l16 * 8);
        sacc[nt] = __builtin_amdgcn_mfma_f32_16x16x32_bf16(aq[slab], bfr, sacc[nt], 0, 0, 0);
      }
    }
    // online softmax update
    float scale[4];
#pragma unroll
    for (int reg = 0; reg < 4; reg++) {
      float tm = -1e30f;
#pragma unroll
      for (int nt = 0; nt < 8; nt++) tm = fmaxf(tm, sacc[nt][reg]);
#pragma unroll
      for (int mk = 1; mk <= 8; mk <<= 1) tm = fmaxf(tm, __shfl_xor(tm, mk));
      float nm = fmaxf(m[reg], tm);
      scale[reg] = __expf(m[reg] - nm);
      m[reg] = nm;
      float ts = 0.f;
#pragma unroll
      for (int nt = 0; nt < 8; nt++) {
        float e = __expf(sacc[nt][reg] - nm);
        sacc[nt][reg] = e; ts += e;
      }
#pragma unroll
      for (int mk = 1; mk <= 8; mk <<= 1) ts += __shfl_xor(ts, mk);
      l[reg] = l[reg] * scale[reg] + ts;
#pragma unroll
      for (int vt = 0; vt < 4; vt++) oacc[vt][reg] *= scale[reg];
    }
    __syncthreads();   // Vt staged
#pragma unroll
    for (int nt = 0; nt < 8; nt++)
#pragma unroll
      for (int reg = 0; reg < 4; reg++)
        Ps[w][4 * l16 + reg][nt * 16 + l15] = f2b(sacc[nt][reg]);
    // PV accumulate: 16x128 @ 128x64
#pragma unroll
    for (int ks = 0; ks < 4; ks++) {
      short8_t pa = *(const short8_t*)&Ps[w][l15][ks * 32 + l16 * 8];
#pragma unroll
      for (int vt = 0; vt < 4; vt++) {
        short8_t bv = *(const short8_t*)&Vt[vt * 16 + l15][ks * 32 + l16 * 8];
        oacc[vt] = __builtin_amdgcn_mfma_f32_16x16x32_bf16(pa, bv, oacc[vt], 0, 0, 0);
      }
    }
  }
#pragma unroll
  for (int vt = 0; vt < 4; vt++)
#pragma unroll
    for (int reg = 0; reg < 4; reg++) {
      int r = row0 + 4 * l16 + reg;
      w3v[(long)head * 16384 + (long)r * 64 + vt * 16 + l15] = oacc[vt][reg] / l[reg];
    }
}

// ---------------------------------------------------------------------------
// SIMT f32 tiled matmul for the pinv chain / a2.
// MODE 0: C = alpha*acc [+bias][+beta*C]
// MODE 3: C = acc; C2(=bias cast) = diag(beta) - acc
// MODE 4: C = diag(beta) - acc
template <bool BT, int MODE>
__global__ __launch_bounds__(256) void mm_kernel(
    const float* __restrict__ A, const float* __restrict__ Bm, float* __restrict__ C,
    const float* __restrict__ bias,
    int M, int N, int K, int lda, int ldb, int ldc,
    long sA, long sB, long sC, float alpha, float beta, long s64)
{
  __shared__ float As[16][64];
  __shared__ float Bs[16][64];
  const int bz = blockIdx.z;
  A  += (long)bz * sA;
  Bm += (long)bz * sB;
  C  += (long)bz * sC;
  float* C2 = nullptr;
  if constexpr (MODE == 3) C2 = const_cast<float*>(bias) + (long)bz * sC;
  const int m0 = blockIdx.y * 64, n0 = blockIdx.x * 64;
  const int tid = threadIdx.x;
  const int tm = tid >> 4, tn = tid & 15;
  const int ar = tid >> 2;
  const int ac = (tid & 3) << 2;
  float acc[4][4] = {};
  for (int k0 = 0; k0 < K; k0 += 16) {
#pragma unroll
    for (int i = 0; i < 4; i++) {
      int gm = m0 + ar, gk = k0 + ac + i;
      As[ac + i][ar] = (gm < M && gk < K) ? A[(long)gm * lda + gk] : 0.f;
    }
    if constexpr (BT) {
#pragma unroll
      for (int i = 0; i < 4; i++) {
        int gn = n0 + ar, gk = k0 + ac + i;
        Bs[ac + i][ar] = (gn < N && gk < K) ? Bm[(long)gn * ldb + gk] : 0.f;
      }
    } else {
      int bk = tid >> 4;
      int bn = (tid & 15) << 2;
#pragma unroll
      for (int i = 0; i < 4; i++) {
        int gk = k0 + bk, gn = n0 + bn + i;
        Bs[bk][bn + i] = (gk < K && gn < N) ? Bm[(long)gk * ldb + gn] : 0.f;
      }
    }
    __syncthreads();
#pragma unroll
    for (int kk = 0; kk < 16; kk++) {
      float a[4], b[4];
#pragma unroll
      for (int i = 0; i < 4; i++) { a[i] = As[kk][tm * 4 + i]; b[i] = Bs[kk][tn * 4 + i]; }
#pragma unroll
      for (int i = 0; i < 4; i++)
#pragma unroll
        for (int j = 0; j < 4; j++)
          acc[i][j] = fmaf(a[i], b[j], acc[i][j]);
    }
    __syncthreads();
  }
#pragma unroll
  for (int i = 0; i < 4; i++) {
    int row = m0 + tm * 4 + i;
    if (row >= M) continue;
#pragma unroll
    for (int j = 0; j < 4; j++) {
      int col = n0 + tn * 4 + j;
      if (col >= N) continue;
      long idx = (long)row * ldc + col;
      float v = acc[i][j];
      if constexpr (MODE == 0) {
        float o = alpha * v;
        if (bias) o += bias[col];
        C[idx] = (beta != 0.f) ? o + beta * C[idx] : o;
      } else if constexpr (MODE == 3) {
        C[idx] = v;
        C2[idx] = ((row == col) ? beta : 0.f) - v;
      } else if constexpr (MODE == 4) {
        C[idx] = ((row == col) ? beta : 0.f) - v;
      }
    }
  }
}

// ---------------------------------------------------------------------------
__global__ void cls_copy(const float* __restrict__ c, float* __restrict__ h) {
  h[threadIdx.x] = c[threadIdx.x];
}

__global__ __launch_bounds__(256) void ln_pad_b(const float* __restrict__ h,
    const float* __restrict__ g, const float* __restrict__ b,
    u16* __restrict__ out, int pad)
{
  int s = blockIdx.x, t = threadIdx.x;
  u16* o = out + (long)s * CH;
  if (s < pad) { o[t] = 0; o[t + 256] = 0; return; }
  const float* x = h + (long)(s - pad) * CH;
  float x0 = x[t], x1 = x[t + 256];
  float mu = blockSum(x0 + x1) * (1.f / 512.f);
  float d0 = x0 - mu, d1 = x1 - mu;
  float var = blockSum(d0 * d0 + d1 * d1) * (1.f / 512.f);
  float rs = rsqrtf(var + 1e-5f);
  o[t]       = f2b(d0 * rs * g[t]       + b[t]);
  o[t + 256] = f2b(d1 * rs * g[t + 256] + b[t + 256]);
}

__global__ __launch_bounds__(64) void landmark_b(const u16* __restrict__ q,
    float* __restrict__ ql, u16* __restrict__ qlb) {
  int hb = blockIdx.x;
  int d = threadIdx.x;
  int hh = hb >> 8, j = hb & 255;
  const u16* src = q + ((long)hh * S + (long)j * 65) * 64 + d;
  float s = 0.f;
  for (int g2 = 0; g2 < 65; g2++) s += b2f(src[(long)g2 * 64]);
  s *= (1.f / 65.f);
  ql[(long)hb * 64 + d] = s;
  qlb[(long)hb * 64 + d] = f2b(s);
}

__global__ __launch_bounds__(256) void rowsoftmax(float* __restrict__ X) {
  float* row = X + (long)blockIdx.x * 256;
  int t = threadIdx.x;
  float x = row[t];
  float m = blockMax(x);
  float e = __expf(x - m);
  float s = blockSum(e);
  row[t] = e / s;
}

__global__ __launch_bounds__(256) void rowabs(const float* __restrict__ a2, float* __restrict__ rs) {
  int r = blockIdx.x;
  float s = blockSum(fabsf(a2[(long)r * 256 + threadIdx.x]));
  if (threadIdx.x == 0) rs[r] = s;
}
__global__ __launch_bounds__(256) void colabs(const float* __restrict__ a2, float* __restrict__ cs) {
  int hb = blockIdx.x; int hh = hb >> 8, j = hb & 255;
  float s = blockSum(fabsf(a2[((long)hh * 256 + threadIdx.x) * 256 + j]));
  if (threadIdx.x == 0) cs[hb] = s;
}
__global__ __launch_bounds__(256) void scaleinv(const float* __restrict__ rs,
                                                const float* __restrict__ cs, float* __restrict__ inv) {
  float m1 = -1e30f, m2 = -1e30f;
  for (int i = threadIdx.x; i < 2048; i += 256) { m1 = fmaxf(m1, rs[i]); m2 = fmaxf(m2, cs[i]); }
  m1 = blockMax(m1);
  m2 = blockMax(m2);
  if (threadIdx.x == 0) inv[0] = 1.f / (m1 * m2);
}
__global__ __launch_bounds__(256) void z0k(const float* __restrict__ a2,
                                           const float* __restrict__ inv, float* __restrict__ z) {
  int hb = blockIdx.x; int hh = hb >> 8, i = hb & 255; int j = threadIdx.x;
  z[(long)hb * 256 + j] = a2[((long)hh * 256 + j) * 256 + i] * inv[0];
}

// depthwise residual conv (kernel 33, pad 16), F += conv(v); 256 thr = 4 pos x 64 d
__global__ __launch_bounds__(256) void resconv(const u16* __restrict__ v,
    const float* __restrict__ w, float* __restrict__ F)
{
  int s = blockIdx.x * 4 + (threadIdx.x >> 6), hh = blockIdx.y, d = threadIdx.x & 63;
  const u16* vh = v + (long)hh * S * 64;
  float a = 0.f;
  for (int t = 0; t < 33; t++) {
    int j = s + t - 16;
    if (0 <= j && j < S) a += w[hh * 33 + t] * b2f(vh[(long)j * 64 + d]);
  }
  F[(long)s * CH + hh * 64 + d] += a;
}

// h feat rows (1..16384, 512 cols) -> f (512, 16384) CHW
__global__ __launch_bounds__(256) void transpose_feat(const float* __restrict__ h, float* __restrict__ f) {
  __shared__ float tile[32][33];
  int p0 = blockIdx.x * 32;
  int c0 = blockIdx.y * 32;
  int tx = threadIdx.x & 31, ty = threadIdx.x >> 5;
  for (int i = 0; i < 32; i += 8)
    tile[ty + i][tx] = h[(long)(1 + p0 + ty + i) * CH + c0 + tx];
  __syncthreads();
  for (int i = 0; i < 32; i += 8)
    f[(long)(c0 + ty + i) * 16384 + p0 + tx] = tile[tx][ty + i];
}

// PPEG conv, LDS-tiled: out CHW = f + dw7 + dw5 + dw3 (+biases)
// grid (16 tiles of 32x32, 512 ch), 256 thr
__global__ __launch_bounds__(256) void ppeg_tile(const float* __restrict__ f,
    const float* __restrict__ w7, const float* __restrict__ b7,
    const float* __restrict__ w5, const float* __restrict__ b5,
    const float* __restrict__ w3, const float* __restrict__ b3,
    float* __restrict__ fo)
{
  __shared__ float T[38][40];
  __shared__ float W7s[49], W5s[25], W3s[9];
  int c = blockIdx.y;
  int ty0 = (blockIdx.x >> 2) * 32, tx0 = (blockIdx.x & 3) * 32;
  int tid = threadIdx.x;
  if (tid < 49) W7s[tid] = w7[c * 49 + tid];
  if (tid < 25) W5s[tid] = w5[c * 25 + tid];
  if (tid < 9)  W3s[tid] = w3[c * 9 + tid];
  const float* fc = f + (long)c * 16384;
  for (int idx = tid; idx < 38 * 38; idx += 256) {
    int r = idx / 38, cc = idx - r * 38;
    int y = ty0 + r - 3, x = tx0 + cc - 3;
    T[r][cc] = (0 <= y && y < 128 && 0 <= x && x < 128) ? fc[y * 128 + x] : 0.f;
  }
  __syncthreads();
  float bsum = b7[c] + b5[c] + b3[c];
#pragma unroll
  for (int p = 0; p < 4; p++) {
    int px = tid + p * 256;
    int y = px >> 5, x = px & 31;
    float acc = T[y + 3][x + 3] + bsum;
#pragma unroll
    for (int dy = 0; dy < 7; dy++)
#pragma unroll
      for (int dx = 0; dx < 7; dx++)
        acc += W7s[dy * 7 + dx] * T[y + dy][x + dx];
#pragma unroll
    for (int dy = 0; dy < 5; dy++)
#pragma unroll
      for (int dx = 0; dx < 5; dx++)
        acc += W5s[dy * 5 + dx] * T[y + dy + 1][x + dx + 1];
#pragma unroll
    for (int dy = 0; dy < 3; dy++)
#pragma unroll
      for (int dx = 0; dx < 3; dx++)
        acc += W3s[dy * 3 + dx] * T[y + dy + 2][x + dx + 2];
    fo[(long)c * 16384 + (ty0 + y) * 128 + tx0 + x] = acc;
  }
}

// fo (512,16384) CHW -> h rows 1..16384
__global__ __launch_bounds__(256) void transpose_back(const float* __restrict__ fo, float* __restrict__ h) {
  __shared__ float tile[32][33];
  int p0 = blockIdx.x * 32;
  int c0 = blockIdx.y * 32;
  int tx = threadIdx.x & 31, ty = threadIdx.x >> 5;
  for (int i = 0; i < 32; i += 8)
    tile[ty + i][tx] = fo[(long)(c0 + ty + i) * 16384 + p0 + tx];
  __syncthreads();
  for (int i = 0; i < 32; i += 8)
    h[(long)(1 + p0 + ty + i) * CH + c0 + tx] = tile[tx][ty + i];
}

// final: LN(h row 0) then 2-class head
__global__ __launch_bounds__(256) void final_k(const float* __restrict__ h,
    const float* __restrict__ g, const float* __restrict__ b,
    const float* __restrict__ w, const float* __restrict__ fb, float* __restrict__ out)
{
  int t = threadIdx.x;
  float x0 = h[t], x1 = h[t + 256];
  float mu = blockSum(x0 + x1) * (1.f / 512.f);
  float d0 = x0 - mu, d1 = x1 - mu;
  float var = blockSum(d0 * d0 + d1 * d1) * (1.f / 512.f);
  float rs = rsqrtf(var + 1e-5f);
  float y0 = d0 * rs * g[t]       + b[t];
  float y1 = d1 * rs * g[t + 256] + b[t + 256];
  float s0 = blockSum(y0 * w[t]       + y1 * w[t + 256]);
  float s1 = blockSum(y0 * w[512 + t] + y1 * w[512 + t + 256]);
  if (t == 0) {
    out[0] = s0 + fb[0];
    out[1] = s1 + fb[1];
  }
}

// ---------------------------------------------------------------------------
struct AttnW {
  const float *lng, *lnb, *qkvw, *outw, *outb, *resw;
};

static void run_attn(const AttnW& Wt, const u16* qkvw_b, const u16* outw_b,
                     float* h, u16* hn_b, u16* qb, u16* kb, u16* vb, float* F,
                     float* S1, float* ql, float* kl, u16* qlb, u16* klb,
                     float* w3v, float* Wm, u16* WmT_b,
                     float* a2, float* xz, float* t1, float* t2, float* zA, float* zB,
                     float* rs, float* cs, float* inv,
                     hipStream_t stream)
{
  const long s64 = (long)S * 64;
  ln_pad_b<<<S, 256, 0, stream>>>(h, Wt.lng, Wt.lnb, hn_b, PADR);
  mfma_gemm<2><<<dim3(12, 130, 1), 256, 0, stream>>>(
      hn_b, qkvw_b, nullptr, nullptr, S, 1536, 512, 512, 512, 0,
      0.125f, 0.f, qb, kb, vb, s64);
  landmark_b<<<2048, 64, 0, stream>>>(qb, ql, qlb);
  landmark_b<<<2048, 64, 0, stream>>>(kb, kl, klb);
  // a2 = softmax(ql @ kl^T) — f32 SIMT (feeds pinv)
  mm_kernel<true, 0><<<dim3(4, 4, 8), 256, 0, stream>>>(
      ql, kl, a2, nullptr, 256, 256, 64, 64, 64, 256, 16384, 16384, 65536, 1.f, 0.f, 0);
  rowsoftmax<<<2048, 256, 0, stream>>>(a2);
  rowabs<<<2048, 256, 0, stream>>>(a2, rs);
  colabs<<<2048, 256, 0, stream>>>(a2, cs);
  scaleinv<<<1, 256, 0, stream>>>(rs, cs, inv);
  z0k<<<2048, 256, 0, stream>>>(a2, inv, zA);
  float* zc = zA; float* zo = zB;
  for (int it = 0; it < 6; it++) {
    // xz = a2@zc ; t1 = 7I - xz
    mm_kernel<false, 3><<<dim3(4, 4, 8), 256, 0, stream>>>(
        a2, zc, xz, t1, 256, 256, 256, 256, 256, 256, 65536, 65536, 65536, 1.f, 7.f, 0);
    // t2 = 15I - xz@t1
    mm_kernel<false, 4><<<dim3(4, 4, 8), 256, 0, stream>>>(
        xz, t1, t2, nullptr, 256, 256, 256, 256, 256, 256, 65536, 65536, 65536, 1.f, 15.f, 0);
    // t1 = 13I - xz@t2
    mm_kernel<false, 4><<<dim3(4, 4, 8), 256, 0, stream>>>(
        xz, t2, t1, nullptr, 256, 256, 256, 256, 256, 256, 65536, 65536, 65536, 1.f, 13.f, 0);
    // zo = 0.25 * zc@t1
    mm_kernel<false, 0><<<dim3(4, 4, 8), 256, 0, stream>>>(
        zc, t1, zo, nullptr, 256, 256, 256, 256, 256, 256, 65536, 65536, 65536, 0.25f, 0.f, 0);
    float* tmp = zc; zc = zo; zo = tmp;
  }
  // fused a3@v (all heads)
  attn_a3v<<<dim3(4, 8, 1), 256, 0, stream>>>(qlb, kb, vb, w3v, s64);
  // Wm = pinv(a2) @ w3v — f32 SIMT
  mm_kernel<false, 0><<<dim3(1, 4, 8), 256, 0, stream>>>(
      zc, w3v, Wm, nullptr, 256, 64, 256, 256, 64, 64, 65536, 16384, 16384, 1.f, 0.f, 0);
  wm_transpose<<<dim3(64, 8, 1), 256, 0, stream>>>(Wm, WmT_b);
  // fused a1 path (all heads) -> F
  attn_a1<<<dim3(260, 8, 1), 256, 0, stream>>>(qb, klb, WmT_b, F, s64);
  resconv<<<dim3(4160, 8, 1), 256, 0, stream>>>(vb, Wt.resw, F);
  // h += F[PADR:, :] @ outw^T + outb
  u16* Fb = (u16*)S1;
  cvt_f2b<<<8193, 256, 0, stream>>>(F + (long)PADR * CH, Fb, (long)NT * CH);
  mfma_gemm<0><<<dim3(4, 129, 1), 256, 0, stream>>>(
      Fb, outw_b, h, Wt.outb, NT, 512, 512, 512, 512, 512,
      1.f, 1.f, nullptr, nullptr, nullptr, 0);
}

extern "C" void kernel_launch(void* const* d_in, const int* in_sizes, int n_in,
                              void* d_out, int out_size, void* d_ws, size_t ws_size,
                              hipStream_t stream)
{
  const float* X      = (const float*)d_in[0];
  const float* fc1w   = (const float*)d_in[1];
  const float* fc1b   = (const float*)d_in[2];
  const float* clstok = (const float*)d_in[3];
  AttnW w1{ (const float*)d_in[4], (const float*)d_in[5], (const float*)d_in[6],
            (const float*)d_in[7], (const float*)d_in[8], (const float*)d_in[9] };
  const float* w7 = (const float*)d_in[10]; const float* b7 = (const float*)d_in[11];
  const float* w5 = (const float*)d_in[12]; const float* b5 = (const float*)d_in[13];
  const float* w3 = (const float*)d_in[14]; const float* b3 = (const float*)d_in[15];
  AttnW w2{ (const float*)d_in[16], (const float*)d_in[17], (const float*)d_in[18],
            (const float*)d_in[19], (const float*)d_in[20], (const float*)d_in[21] };
  const float* lnfg = (const float*)d_in[22];
  const float* lnfb = (const float*)d_in[23];
  const float* fc2w = (const float*)d_in[24];
  const float* fc2b = (const float*)d_in[25];
  float* out = (float*)d_out;

  char* wsb = (char*)d_ws;
  size_t off = 0;
  auto alloc = [&](size_t nbytes) {
    void* p = wsb + off;
    off = (off + nbytes + 255) & ~(size_t)255;
    return p;
  };
  float* h    = (float*)alloc((size_t)NT * CH * 4);
  float* F    = (float*)alloc((size_t)S * CH * 4);      // attn out; ppeg CHW temp
  u16*  hn_b  = (u16*)alloc((size_t)S * CH * 2);
  u16*  qb    = (u16*)alloc((size_t)S * CH * 2);
  u16*  kb    = (u16*)alloc((size_t)S * CH * 2);
  u16*  vb    = (u16*)alloc((size_t)S * CH * 2);
  float* S1   = (float*)alloc((size_t)S * 256 * 4);     // Fb staging
  char* big   = (char*)alloc(33554432);                 // Xb (bf16) / ppeg f (f32)
  u16*  fc1w_b = (u16*)alloc(524288 * 2);
  u16*  qkv1_b = (u16*)alloc(786432 * 2);
  u16*  qkv2_b = (u16*)alloc(786432 * 2);
  u16*  out1_b = (u16*)alloc(262144 * 2);
  u16*  out2_b = (u16*)alloc(262144 * 2);
  float* ql   = (float*)alloc(131072 * 4);
  float* kl   = (float*)alloc(131072 * 4);
  u16*  qlb   = (u16*)alloc(131072 * 2);
  u16*  klb   = (u16*)alloc(131072 * 2);
  float* w3v  = (float*)alloc(131072 * 4);
  float* Wm   = (float*)alloc(131072 * 4);
  u16*  WmT_b = (u16*)alloc(131072 * 2);
  float* a2   = (float*)alloc(524288 * 4);
  float* xz   = (float*)alloc(524288 * 4);
  float* t1   = (float*)alloc(524288 * 4);
  float* t2   = (float*)alloc(524288 * 4);
  float* zA   = (float*)alloc(524288 * 4);
  float* zB   = (float*)alloc(524288 * 4);
  float* rs   = (float*)alloc(2048 * 4);
  float* cs   = (float*)alloc(2048 * 4);
  float* inv  = (float*)alloc(256);
  (void)in_sizes; (void)n_in; (void)out_size; (void)ws_size;

  u16* Xb = (u16*)big;
  cvt_f2b<<<16384, 256, 0, stream>>>(X, Xb, (long)16384 * 1024);
  cvt_f2b<<<512, 256, 0, stream>>>(fc1w, fc1w_b, 524288);
  cvt_f2b<<<768, 256, 0, stream>>>(w1.qkvw, qkv1_b, 786432);
  cvt_f2b<<<768, 256, 0, stream>>>(w2.qkvw, qkv2_b, 786432);
  cvt_f2b<<<256, 256, 0, stream>>>(w1.outw, out1_b, 262144);
  cvt_f2b<<<256, 256, 0, stream>>>(w2.outw, out2_b, 262144);

  cls_copy<<<1, 512, 0, stream>>>(clstok, h);
  mfma_gemm<1><<<dim3(4, 128, 1), 256, 0, stream>>>(
      Xb, fc1w_b, h + CH, fc1b, 16384, 512, 1024, 1024, 1024, 512,
      1.f, 0.f, nullptr, nullptr, nullptr, 0);

  run_attn(w1, qkv1_b, out1_b, h, hn_b, qb, kb, vb, F, S1, ql, kl, qlb, klb,
           w3v, Wm, WmT_b, a2, xz, t1, t2, zA, zB, rs, cs, inv, stream);

  // PPEG: h -> CHW(big) -> conv -> CHW(F) -> h
  float* fppeg = (float*)big;
  transpose_feat<<<dim3(512, 16, 1), 256, 0, stream>>>(h, fppeg);
  ppeg_tile<<<dim3(16, 512, 1), 256, 0, stream>>>(fppeg, w7, b7, w5, b5, w3, b3, F);
  transpose_back<<<dim3(512, 16, 1), 256, 0, stream>>>(F, h);

  run_attn(w2, qkv2_b, out2_b, h, hn_b, qb, kb, vb, F, S1, ql, kl, qlb, klb,
           w3v, Wm, WmT_b, a2, xz, t1, t2, zA, zB, rs, cs, inv, stream);

  final_k<<<1, 256, 0, stream>>>(h, lnfg, lnfb, fc2w, fc2b, out);
}

// Round 6
// 1864.635 us; speedup vs baseline: 6.0822x; 2.1003x over previous
//
#include <hip/hip_runtime.h>
#include <hip/hip_bf16.h>

static const int S    = 16640;  // padded sequence (65*256)
static const int PADR = 255;    // zero rows prepended inside attention
static const int NT   = 16385;  // tokens incl cls
static const int CH   = 512;    // hidden dim

typedef unsigned short u16;
typedef __attribute__((ext_vector_type(8))) short short8_t;
typedef __attribute__((ext_vector_type(4))) float float4_t;

__device__ __forceinline__ float b2f(u16 x) {
  union { unsigned u; float f; } t; t.u = (unsigned)x << 16; return t.f;
}
__device__ __forceinline__ u16 f2b(float x) {
  union { float f; unsigned u; } t; t.f = x;
  unsigned r = t.u + 0x7fff + ((t.u >> 16) & 1);
  return (u16)(r >> 16);
}

__device__ __forceinline__ float warpSum(float v) {
#pragma unroll
  for (int off = 32; off; off >>= 1) v += __shfl_xor(v, off);
  return v;
}
__device__ __forceinline__ float warpMax(float v) {
#pragma unroll
  for (int off = 32; off; off >>= 1) v = fmaxf(v, __shfl_xor(v, off));
  return v;
}
__device__ __forceinline__ float blockSum(float v) {
  __shared__ float sm[8];
  int lane = threadIdx.x & 63, wv = threadIdx.x >> 6;
  v = warpSum(v);
  __syncthreads();
  if (lane == 0) sm[wv] = v;
  __syncthreads();
  float t = 0.f;
  int nw = blockDim.x >> 6;
  for (int i = 0; i < nw; i++) t += sm[i];
  return t;
}
__device__ __forceinline__ float blockMax(float v) {
  __shared__ float sm[8];
  int lane = threadIdx.x & 63, wv = threadIdx.x >> 6;
  v = warpMax(v);
  __syncthreads();
  if (lane == 0) sm[wv] = v;
  __syncthreads();
  float t = -1e30f;
  int nw = blockDim.x >> 6;
  for (int i = 0; i < nw; i++) t = fmaxf(t, sm[i]);
  return t;
}

// ---------------------------------------------------------------------------
__global__ __launch_bounds__(256) void cvt_f2b(const float* __restrict__ in,
                                               u16* __restrict__ out, long n) {
  long i = ((long)blockIdx.x * 256 + threadIdx.x) * 4;
  if (i + 3 < n) {
    float4 v = *(const float4*)(in + i);
    out[i] = f2b(v.x); out[i + 1] = f2b(v.y); out[i + 2] = f2b(v.z); out[i + 3] = f2b(v.w);
  } else {
    for (long j = i; j < n; j++) out[j] = f2b(in[j]);
  }
}

// WmT[head][n(64)][k(256)] bf16 <- Wm[head][k(256)][n(64)] f32
__global__ __launch_bounds__(256) void wm_transpose(const float* __restrict__ Wm,
                                                    u16* __restrict__ WmT) {
  int n = blockIdx.x, head = blockIdx.y, k = threadIdx.x;
  WmT[((long)head * 64 + n) * 256 + k] = f2b(Wm[(long)head * 16384 + k * 64 + n]);
}

// ---------------------------------------------------------------------------
// MFMA bf16 GEMM (verified layouts): C(M,N) = A(M,K) * B^T, f32 accumulate.
//  EPI 0: C = alpha*acc + bias? + beta*C (f32)
//  EPI 1: C = relu(acc + bias) (f32)
//  EPI 2: qkv head-split store bf16
// ---------------------------------------------------------------------------
template <int EPI>
__global__ __launch_bounds__(256) void mfma_gemm(
    const u16* __restrict__ A, const u16* __restrict__ B, float* __restrict__ C,
    const float* __restrict__ bias, int M, int N, int K,
    int lda, int ldb, int ldc,
    float alpha, float beta,
    u16* __restrict__ q_o, u16* __restrict__ k_o, u16* __restrict__ v_o, long s64)
{
  __shared__ u16 As[128][40];
  __shared__ u16 Bs[128][40];
  const int tid = threadIdx.x;
  const int m0 = blockIdx.y * 128, n0 = blockIdx.x * 128;
  const int wid = tid >> 6, lane = tid & 63;
  const int wr = wid >> 1, wc = wid & 1;
  const int l15 = lane & 15, l16 = lane >> 4;
  const int arow = tid >> 1, aseg = (tid & 1) * 16;
  float4_t acc[4][4] = {};

  for (int k0 = 0; k0 < K; k0 += 32) {
    {
      int gm = m0 + arow;
      short8_t v0 = {}, v1 = {};
      if (gm < M) {
        const u16* src = A + (long)gm * lda + k0 + aseg;
        v0 = *(const short8_t*)src; v1 = *(const short8_t*)(src + 8);
      }
      *(short8_t*)&As[arow][aseg]     = v0;
      *(short8_t*)&As[arow][aseg + 8] = v1;
    }
    {
      int gn = n0 + arow;
      short8_t v0 = {}, v1 = {};
      if (gn < N) {
        const u16* src = B + (long)gn * ldb + k0 + aseg;
        v0 = *(const short8_t*)src; v1 = *(const short8_t*)(src + 8);
      }
      *(short8_t*)&Bs[arow][aseg]     = v0;
      *(short8_t*)&Bs[arow][aseg + 8] = v1;
    }
    __syncthreads();
    short8_t af[4], bfr[4];
#pragma unroll
    for (int i = 0; i < 4; i++)
      af[i] = *(const short8_t*)&As[wr * 64 + i * 16 + l15][l16 * 8];
#pragma unroll
    for (int i = 0; i < 4; i++)
      bfr[i] = *(const short8_t*)&Bs[wc * 64 + i * 16 + l15][l16 * 8];
#pragma unroll
    for (int i = 0; i < 4; i++)
#pragma unroll
      for (int j = 0; j < 4; j++)
        acc[i][j] = __builtin_amdgcn_mfma_f32_16x16x32_bf16(af[i], bfr[j], acc[i][j], 0, 0, 0);
    __syncthreads();
  }

#pragma unroll
  for (int mi = 0; mi < 4; mi++) {
#pragma unroll
    for (int ni = 0; ni < 4; ni++) {
#pragma unroll
      for (int j = 0; j < 4; j++) {
        int r = m0 + wr * 64 + mi * 16 + l16 * 4 + j;
        int c = n0 + wc * 64 + ni * 16 + l15;
        if (r >= M || c >= N) continue;
        float v = acc[mi][ni][j];
        if constexpr (EPI == 0) {
          long idx = (long)r * ldc + c;
          float o = alpha * v;
          if (bias) o += bias[c];
          if (beta != 0.f) o += beta * C[idx];
          C[idx] = o;
        } else if constexpr (EPI == 1) {
          long idx = (long)r * ldc + c;
          C[idx] = fmaxf(v + bias[c], 0.f);
        } else {  // EPI == 2: qkv split
          int sec = c >> 9, hcol = c & 511;
          int head = hcol >> 6, d = hcol & 63;
          u16* dst = (sec == 0) ? q_o : (sec == 1 ? k_o : v_o);
          float o = (sec == 0) ? v * alpha : v;
          dst[(long)head * s64 + (long)r * 64 + d] = f2b(o);
        }
      }
    }
  }
}

// ---------------------------------------------------------------------------
// f32-grade MFMA GEMM via bf16 hi/lo split (3 MFMAs per product).
// 256x256x256 per head, batched over blockIdx.z heads. 64x64 tile per block.
// MODE 0: C = alpha*acc ; MODE 3: C = acc, C2 = beta*I - acc ; MODE 4: C = beta*I - acc
template <int MODE>
__global__ __launch_bounds__(256) void pinv_gemm(
    const float* __restrict__ A, const float* __restrict__ B,
    float* __restrict__ C, float* __restrict__ C2, float alpha, float beta)
{
  __shared__ u16 Ah[64][40], Al[64][40], Bh[64][40], Bl[64][40];
  const int tid = threadIdx.x;
  const long zoff = (long)blockIdx.z << 16;
  A += zoff; B += zoff; C += zoff;
  if constexpr (MODE == 3) C2 += zoff;
  const int m0 = blockIdx.y * 64, n0 = blockIdx.x * 64;
  const int wid = tid >> 6, lane = tid & 63;
  const int wr = wid >> 1, wc = wid & 1;
  const int l15 = lane & 15, l16 = lane >> 4;
  const int arow = tid >> 2, aseg = (tid & 3) * 8;
  const int bk = tid >> 3, bn = (tid & 7) * 8;
  float4_t acc[2][2] = {};

  for (int k0 = 0; k0 < 256; k0 += 32) {
    {
      const float* src = A + (long)(m0 + arow) * 256 + k0 + aseg;
#pragma unroll
      for (int i = 0; i < 8; i++) {
        float v = src[i];
        u16 hi = f2b(v);
        Ah[arow][aseg + i] = hi;
        Al[arow][aseg + i] = f2b(v - b2f(hi));
      }
    }
    {
      const float* src = B + (long)(k0 + bk) * 256 + n0 + bn;
#pragma unroll
      for (int i = 0; i < 8; i++) {
        float v = src[i];
        u16 hi = f2b(v);
        Bh[bn + i][bk] = hi;
        Bl[bn + i][bk] = f2b(v - b2f(hi));
      }
    }
    __syncthreads();
    short8_t ah[2], al[2], bh[2], bl[2];
#pragma unroll
    for (int i = 0; i < 2; i++) {
      ah[i] = *(const short8_t*)&Ah[wr * 32 + i * 16 + l15][l16 * 8];
      al[i] = *(const short8_t*)&Al[wr * 32 + i * 16 + l15][l16 * 8];
      bh[i] = *(const short8_t*)&Bh[wc * 32 + i * 16 + l15][l16 * 8];
      bl[i] = *(const short8_t*)&Bl[wc * 32 + i * 16 + l15][l16 * 8];
    }
#pragma unroll
    for (int i = 0; i < 2; i++)
#pragma unroll
      for (int j = 0; j < 2; j++) {
        acc[i][j] = __builtin_amdgcn_mfma_f32_16x16x32_bf16(ah[i], bh[j], acc[i][j], 0, 0, 0);
        acc[i][j] = __builtin_amdgcn_mfma_f32_16x16x32_bf16(ah[i], bl[j], acc[i][j], 0, 0, 0);
        acc[i][j] = __builtin_amdgcn_mfma_f32_16x16x32_bf16(al[i], bh[j], acc[i][j], 0, 0, 0);
      }
    __syncthreads();
  }

#pragma unroll
  for (int i = 0; i < 2; i++)
#pragma unroll
    for (int n2 = 0; n2 < 2; n2++)
#pragma unroll
      for (int j = 0; j < 4; j++) {
        int r = m0 + wr * 32 + i * 16 + l16 * 4 + j;
        int c = n0 + wc * 32 + n2 * 16 + l15;
        long idx = (long)r * 256 + c;
        float v = acc[i][n2][j];
        if constexpr (MODE == 0) {
          C[idx] = alpha * v;
        } else if constexpr (MODE == 3) {
          C[idx] = v;
          C2[idx] = ((r == c) ? beta : 0.f) - v;
        } else {
          C[idx] = ((r == c) ? beta : 0.f) - v;
        }
      }
}

// ---------------------------------------------------------------------------
// Fused a1 path: F[s][head*64+d] = softmax(q_h[s,:] @ kl_h^T) @ Wm_h
// grid (260 row-tiles, 8 heads), 256 thr (4 waves x 16 rows).
__global__ __launch_bounds__(256) void attn_a1(
    const u16* __restrict__ qb, const u16* __restrict__ klb,
    const u16* __restrict__ WmT, float* __restrict__ F, long s64)
{
  __shared__ u16 Ps[4][16][264];
  const int tid = threadIdx.x;
  const int w = tid >> 6, lane = tid & 63;
  const int l15 = lane & 15, l16 = lane >> 4;
  const int head = blockIdx.y;
  const int row0 = blockIdx.x * 64 + w * 16;

  short8_t aq[2];
#pragma unroll
  for (int slab = 0; slab < 2; slab++)
    aq[slab] = *(const short8_t*)(qb + (long)head * s64 + (long)(row0 + l15) * 64 + slab * 32 + l16 * 8);

  float4_t sacc[16] = {};
  const u16* klh = klb + (long)head * 16384;
#pragma unroll
  for (int nt = 0; nt < 16; nt++) {
#pragma unroll
    for (int slab = 0; slab < 2; slab++) {
      short8_t bfr = *(const short8_t*)(klh + (long)(nt * 16 + l15) * 64 + slab * 32 + l16 * 8);
      sacc[nt] = __builtin_amdgcn_mfma_f32_16x16x32_bf16(aq[slab], bfr, sacc[nt], 0, 0, 0);
    }
  }
  float rcp[4];
#pragma unroll
  for (int reg = 0; reg < 4; reg++) {
    float m = -1e30f;
#pragma unroll
    for (int nt = 0; nt < 16; nt++) m = fmaxf(m, sacc[nt][reg]);
#pragma unroll
    for (int mk = 1; mk <= 8; mk <<= 1) m = fmaxf(m, __shfl_xor(m, mk));
    float s = 0.f;
#pragma unroll
    for (int nt = 0; nt < 16; nt++) { float e = __expf(sacc[nt][reg] - m); sacc[nt][reg] = e; s += e; }
#pragma unroll
    for (int mk = 1; mk <= 8; mk <<= 1) s += __shfl_xor(s, mk);
    rcp[reg] = 1.f / s;
  }
#pragma unroll
  for (int nt = 0; nt < 16; nt++)
#pragma unroll
    for (int reg = 0; reg < 4; reg++)
      Ps[w][4 * l16 + reg][nt * 16 + l15] = f2b(sacc[nt][reg]);
  __syncthreads();
  float4_t oacc[4] = {};
  const u16* wmh = WmT + (long)head * 16384;
#pragma unroll
  for (int ks = 0; ks < 8; ks++) {
    short8_t pa = *(const short8_t*)&Ps[w][l15][ks * 32 + l16 * 8];
#pragma unroll
    for (int vt = 0; vt < 4; vt++) {
      short8_t bv = *(const short8_t*)(wmh + (long)(vt * 16 + l15) * 256 + ks * 32 + l16 * 8);
      oacc[vt] = __builtin_amdgcn_mfma_f32_16x16x32_bf16(pa, bv, oacc[vt], 0, 0, 0);
    }
  }
#pragma unroll
  for (int vt = 0; vt < 4; vt++)
#pragma unroll
    for (int reg = 0; reg < 4; reg++) {
      int r = row0 + 4 * l16 + reg;
      F[(long)r * CH + head * 64 + vt * 16 + l15] = oacc[vt][reg] * rcp[reg];
    }
}

// ---------------------------------------------------------------------------
// Split-K fused a3@v: each block handles 10 key-tiles (1280 keys) of one head,
// with local online softmax; writes per-split partials (m, l, unnormalized O).
// grid (4 row-quarters, 8 heads, 13 splits), 256 thr (4 waves x 16 rows).
__global__ __launch_bounds__(256) void attn_a3v_split(
    const u16* __restrict__ qlb, const u16* __restrict__ kb,
    const u16* __restrict__ vb,
    float* __restrict__ pm, float* __restrict__ pl, float* __restrict__ poacc,
    long s64)
{
  __shared__ u16 Vt[64][136];       // V^T tile: [d][key]
  __shared__ u16 Ps[4][16][136];
  const int tid = threadIdx.x;
  const int w = tid >> 6, lane = tid & 63;
  const int l15 = lane & 15, l16 = lane >> 4;
  const int head = blockIdx.y;
  const int split = blockIdx.z;
  const int row0 = blockIdx.x * 64 + w * 16;

  short8_t aq[2];
#pragma unroll
  for (int slab = 0; slab < 2; slab++)
    aq[slab] = *(const short8_t*)(qlb + (long)head * 16384 + (long)(row0 + l15) * 64 + slab * 32 + l16 * 8);

  float m[4], l[4];
  float4_t oacc[4] = {};
#pragma unroll
  for (int r = 0; r < 4; r++) { m[r] = -1e30f; l[r] = 0.f; }

  const u16* kh = kb + (long)head * s64;
  const u16* vh = vb + (long)head * s64;
  const int vrow = tid >> 1, vhalf = (tid & 1) * 32;

  const int kt0 = split * 10;
  for (int kt = kt0; kt < kt0 + 10; kt++) {
    const int j0 = kt * 128;
    __syncthreads();
    {
      const u16* src = vh + (long)(j0 + vrow) * 64 + vhalf;
#pragma unroll
      for (int i = 0; i < 32; i++) Vt[vhalf + i][vrow] = src[i];
    }
    float4_t sacc[8] = {};
#pragma unroll
    for (int nt = 0; nt < 8; nt++) {
#pragma unroll
      for (int slab = 0; slab < 2; slab++) {
        short8_t bfr = *(const short8_t*)(kh + (long)(j0 + nt * 16 + l15) * 64 + slab * 32 + l16 * 8);
        sacc[nt] = __builtin_amdgcn_mfma_f32_16x16x32_bf16(aq[slab], bfr, sacc[nt], 0, 0, 0);
      }
    }
    float scale[4];
#pragma unroll
    for (int reg = 0; reg < 4; reg++) {
      float tm = -1e30f;
#pragma unroll
      for (int nt = 0; nt < 8; nt++) tm = fmaxf(tm, sacc[nt][reg]);
#pragma unroll
      for (int mk = 1; mk <= 8; mk <<= 1) tm = fmaxf(tm, __shfl_xor(tm, mk));
      float nm = fmaxf(m[reg], tm);
      scale[reg] = __expf(m[reg] - nm);
      m[reg] = nm;
      float ts = 0.f;
#pragma unroll
      for (int nt = 0; nt < 8; nt++) {
        float e = __expf(sacc[nt][reg] - nm);
        sacc[nt][reg] = e; ts += e;
      }
#pragma unroll
      for (int mk = 1; mk <= 8; mk <<= 1) ts += __shfl_xor(ts, mk);
      l[reg] = l[reg] * scale[reg] + ts;
#pragma unroll
      for (int vt = 0; vt < 4; vt++) oacc[vt][reg] *= scale[reg];
    }
    __syncthreads();
#pragma unroll
    for (int nt = 0; nt < 8; nt++)
#pragma unroll
      for (int reg = 0; reg < 4; reg++)
        Ps[w][4 * l16 + reg][nt * 16 + l15] = f2b(sacc[nt][reg]);
#pragma unroll
    for (int ks = 0; ks < 4; ks++) {
      short8_t pa = *(const short8_t*)&Ps[w][l15][ks * 32 + l16 * 8];
#pragma unroll
      for (int vt = 0; vt < 4; vt++) {
        short8_t bv = *(const short8_t*)&Vt[vt * 16 + l15][ks * 32 + l16 * 8];
        oacc[vt] = __builtin_amdgcn_mfma_f32_16x16x32_bf16(pa, bv, oacc[vt], 0, 0, 0);
      }
    }
  }
  // write partials: index (head*13 + split)*256 + row
#pragma unroll
  for (int reg = 0; reg < 4; reg++) {
    int r = row0 + 4 * l16 + reg;
    long pidx = ((long)(head * 13 + split) << 8) + r;
    if (l15 == 0) { pm[pidx] = m[reg]; pl[pidx] = l[reg]; }
#pragma unroll
    for (int vt = 0; vt < 4; vt++)
      poacc[(pidx << 6) + vt * 16 + l15] = oacc[vt][reg];
  }
}

// merge split partials: w3v[head][row][d] = sum_s e^{m_s-M} O_s / sum_s e^{m_s-M} l_s
__global__ __launch_bounds__(64) void a3v_merge(const float* __restrict__ pm,
    const float* __restrict__ pl, const float* __restrict__ poacc,
    float* __restrict__ w3v)
{
  int hb = blockIdx.x;            // head*256 + row
  int head = hb >> 8, row = hb & 255;
  int d = threadIdx.x;
  float M = -1e30f;
  for (int sp = 0; sp < 13; sp++)
    M = fmaxf(M, pm[((long)(head * 13 + sp) << 8) + row]);
  float num = 0.f, den = 0.f;
  for (int sp = 0; sp < 13; sp++) {
    long pidx = ((long)(head * 13 + sp) << 8) + row;
    float sc = __expf(pm[pidx] - M);
    den += pl[pidx] * sc;
    num += poacc[(pidx << 6) + d] * sc;
  }
  w3v[((long)head << 14) + ((long)row << 6) + d] = num / den;
}

// ---------------------------------------------------------------------------
// SIMT f32 tiled matmul (a2 scores, Wm) — MODE 0 only used now.
template <bool BT, int MODE>
__global__ __launch_bounds__(256) void mm_kernel(
    const float* __restrict__ A, const float* __restrict__ Bm, float* __restrict__ C,
    const float* __restrict__ bias,
    int M, int N, int K, int lda, int ldb, int ldc,
    long sA, long sB, long sC, float alpha, float beta, long s64)
{
  __shared__ float As[16][64];
  __shared__ float Bs[16][64];
  const int bz = blockIdx.z;
  A  += (long)bz * sA;
  Bm += (long)bz * sB;
  C  += (long)bz * sC;
  const int m0 = blockIdx.y * 64, n0 = blockIdx.x * 64;
  const int tid = threadIdx.x;
  const int tm = tid >> 4, tn = tid & 15;
  const int ar = tid >> 2;
  const int ac = (tid & 3) << 2;
  float acc[4][4] = {};
  for (int k0 = 0; k0 < K; k0 += 16) {
#pragma unroll
    for (int i = 0; i < 4; i++) {
      int gm = m0 + ar, gk = k0 + ac + i;
      As[ac + i][ar] = (gm < M && gk < K) ? A[(long)gm * lda + gk] : 0.f;
    }
    if constexpr (BT) {
#pragma unroll
      for (int i = 0; i < 4; i++) {
        int gn = n0 + ar, gk = k0 + ac + i;
        Bs[ac + i][ar] = (gn < N && gk < K) ? Bm[(long)gn * ldb + gk] : 0.f;
      }
    } else {
      int bk = tid >> 4;
      int bn = (tid & 15) << 2;
#pragma unroll
      for (int i = 0; i < 4; i++) {
        int gk = k0 + bk, gn = n0 + bn + i;
        Bs[bk][bn + i] = (gk < K && gn < N) ? Bm[(long)gk * ldb + gn] : 0.f;
      }
    }
    __syncthreads();
#pragma unroll
    for (int kk = 0; kk < 16; kk++) {
      float a[4], b[4];
#pragma unroll
      for (int i = 0; i < 4; i++) { a[i] = As[kk][tm * 4 + i]; b[i] = Bs[kk][tn * 4 + i]; }
#pragma unroll
      for (int i = 0; i < 4; i++)
#pragma unroll
        for (int j = 0; j < 4; j++)
          acc[i][j] = fmaf(a[i], b[j], acc[i][j]);
    }
    __syncthreads();
  }
#pragma unroll
  for (int i = 0; i < 4; i++) {
    int row = m0 + tm * 4 + i;
    if (row >= M) continue;
#pragma unroll
    for (int j = 0; j < 4; j++) {
      int col = n0 + tn * 4 + j;
      if (col >= N) continue;
      long idx = (long)row * ldc + col;
      float v = acc[i][j];
      float o = alpha * v;
      if (bias) o += bias[col];
      C[idx] = (beta != 0.f) ? o + beta * C[idx] : o;
    }
  }
}

// ---------------------------------------------------------------------------
__global__ void cls_copy(const float* __restrict__ c, float* __restrict__ h) {
  h[threadIdx.x] = c[threadIdx.x];
}

__global__ __launch_bounds__(256) void ln_pad_b(const float* __restrict__ h,
    const float* __restrict__ g, const float* __restrict__ b,
    u16* __restrict__ out, int pad)
{
  int s = blockIdx.x, t = threadIdx.x;
  u16* o = out + (long)s * CH;
  if (s < pad) { o[t] = 0; o[t + 256] = 0; return; }
  const float* x = h + (long)(s - pad) * CH;
  float x0 = x[t], x1 = x[t + 256];
  float mu = blockSum(x0 + x1) * (1.f / 512.f);
  float d0 = x0 - mu, d1 = x1 - mu;
  float var = blockSum(d0 * d0 + d1 * d1) * (1.f / 512.f);
  float rs = rsqrtf(var + 1e-5f);
  o[t]       = f2b(d0 * rs * g[t]       + b[t]);
  o[t + 256] = f2b(d1 * rs * g[t + 256] + b[t + 256]);
}

__global__ __launch_bounds__(64) void landmark_b(const u16* __restrict__ q,
    float* __restrict__ ql, u16* __restrict__ qlb) {
  int hb = blockIdx.x;
  int d = threadIdx.x;
  int hh = hb >> 8, j = hb & 255;
  const u16* src = q + ((long)hh * S + (long)j * 65) * 64 + d;
  float s = 0.f;
  for (int g2 = 0; g2 < 65; g2++) s += b2f(src[(long)g2 * 64]);
  s *= (1.f / 65.f);
  ql[(long)hb * 64 + d] = s;
  qlb[(long)hb * 64 + d] = f2b(s);
}

__global__ __launch_bounds__(256) void rowsoftmax(float* __restrict__ X) {
  float* row = X + (long)blockIdx.x * 256;
  int t = threadIdx.x;
  float x = row[t];
  float m = blockMax(x);
  float e = __expf(x - m);
  float s = blockSum(e);
  row[t] = e / s;
}

__global__ __launch_bounds__(256) void rowabs(const float* __restrict__ a2, float* __restrict__ rs) {
  int r = blockIdx.x;
  float s = blockSum(fabsf(a2[(long)r * 256 + threadIdx.x]));
  if (threadIdx.x == 0) rs[r] = s;
}
__global__ __launch_bounds__(256) void colabs(const float* __restrict__ a2, float* __restrict__ cs) {
  int hb = blockIdx.x; int hh = hb >> 8, j = hb & 255;
  float s = blockSum(fabsf(a2[((long)hh * 256 + threadIdx.x) * 256 + j]));
  if (threadIdx.x == 0) cs[hb] = s;
}
__global__ __launch_bounds__(256) void scaleinv(const float* __restrict__ rs,
                                                const float* __restrict__ cs, float* __restrict__ inv) {
  float m1 = -1e30f, m2 = -1e30f;
  for (int i = threadIdx.x; i < 2048; i += 256) { m1 = fmaxf(m1, rs[i]); m2 = fmaxf(m2, cs[i]); }
  m1 = blockMax(m1);
  m2 = blockMax(m2);
  if (threadIdx.x == 0) inv[0] = 1.f / (m1 * m2);
}
__global__ __launch_bounds__(256) void z0k(const float* __restrict__ a2,
                                           const float* __restrict__ inv, float* __restrict__ z) {
  int hb = blockIdx.x; int hh = hb >> 8, i = hb & 255; int j = threadIdx.x;
  z[(long)hb * 256 + j] = a2[((long)hh * 256 + j) * 256 + i] * inv[0];
}

// depthwise residual conv (kernel 33, pad 16), F += conv(v); 256 thr = 4 pos x 64 d
__global__ __launch_bounds__(256) void resconv(const u16* __restrict__ v,
    const float* __restrict__ w, float* __restrict__ F)
{
  int s = blockIdx.x * 4 + (threadIdx.x >> 6), hh = blockIdx.y, d = threadIdx.x & 63;
  const u16* vh = v + (long)hh * S * 64;
  float a = 0.f;
  for (int t = 0; t < 33; t++) {
    int j = s + t - 16;
    if (0 <= j && j < S) a += w[hh * 33 + t] * b2f(vh[(long)j * 64 + d]);
  }
  F[(long)s * CH + hh * 64 + d] += a;
}

// h feat rows (1..16384, 512 cols) -> f (512, 16384) CHW
__global__ __launch_bounds__(256) void transpose_feat(const float* __restrict__ h, float* __restrict__ f) {
  __shared__ float tile[32][33];
  int p0 = blockIdx.x * 32;
  int c0 = blockIdx.y * 32;
  int tx = threadIdx.x & 31, ty = threadIdx.x >> 5;
  for (int i = 0; i < 32; i += 8)
    tile[ty + i][tx] = h[(long)(1 + p0 + ty + i) * CH + c0 + tx];
  __syncthreads();
  for (int i = 0; i < 32; i += 8)
    f[(long)(c0 + ty + i) * 16384 + p0 + tx] = tile[tx][ty + i];
}

// PPEG conv, LDS-tiled
__global__ __launch_bounds__(256) void ppeg_tile(const float* __restrict__ f,
    const float* __restrict__ w7, const float* __restrict__ b7,
    const float* __restrict__ w5, const float* __restrict__ b5,
    const float* __restrict__ w3, const float* __restrict__ b3,
    float* __restrict__ fo)
{
  __shared__ float T[38][40];
  __shared__ float W7s[49], W5s[25], W3s[9];
  int c = blockIdx.y;
  int ty0 = (blockIdx.x >> 2) * 32, tx0 = (blockIdx.x & 3) * 32;
  int tid = threadIdx.x;
  if (tid < 49) W7s[tid] = w7[c * 49 + tid];
  if (tid < 25) W5s[tid] = w5[c * 25 + tid];
  if (tid < 9)  W3s[tid] = w3[c * 9 + tid];
  const float* fc = f + (long)c * 16384;
  for (int idx = tid; idx < 38 * 38; idx += 256) {
    int r = idx / 38, cc = idx - r * 38;
    int y = ty0 + r - 3, x = tx0 + cc - 3;
    T[r][cc] = (0 <= y && y < 128 && 0 <= x && x < 128) ? fc[y * 128 + x] : 0.f;
  }
  __syncthreads();
  float bsum = b7[c] + b5[c] + b3[c];
#pragma unroll
  for (int p = 0; p < 4; p++) {
    int px = tid + p * 256;
    int y = px >> 5, x = px & 31;
    float acc = T[y + 3][x + 3] + bsum;
#pragma unroll
    for (int dy = 0; dy < 7; dy++)
#pragma unroll
      for (int dx = 0; dx < 7; dx++)
        acc += W7s[dy * 7 + dx] * T[y + dy][x + dx];
#pragma unroll
    for (int dy = 0; dy < 5; dy++)
#pragma unroll
      for (int dx = 0; dx < 5; dx++)
        acc += W5s[dy * 5 + dx] * T[y + dy + 1][x + dx + 1];
#pragma unroll
    for (int dy = 0; dy < 3; dy++)
#pragma unroll
      for (int dx = 0; dx < 3; dx++)
        acc += W3s[dy * 3 + dx] * T[y + dy + 2][x + dx + 2];
    fo[(long)c * 16384 + (ty0 + y) * 128 + tx0 + x] = acc;
  }
}

// fo (512,16384) CHW -> h rows 1..16384
__global__ __launch_bounds__(256) void transpose_back(const float* __restrict__ fo, float* __restrict__ h) {
  __shared__ float tile[32][33];
  int p0 = blockIdx.x * 32;
  int c0 = blockIdx.y * 32;
  int tx = threadIdx.x & 31, ty = threadIdx.x >> 5;
  for (int i = 0; i < 32; i += 8)
    tile[ty + i][tx] = fo[(long)(c0 + ty + i) * 16384 + p0 + tx];
  __syncthreads();
  for (int i = 0; i < 32; i += 8)
    h[(long)(1 + p0 + ty + i) * CH + c0 + tx] = tile[tx][ty + i];
}

// final: LN(h row 0) then 2-class head
__global__ __launch_bounds__(256) void final_k(const float* __restrict__ h,
    const float* __restrict__ g, const float* __restrict__ b,
    const float* __restrict__ w, const float* __restrict__ fb, float* __restrict__ out)
{
  int t = threadIdx.x;
  float x0 = h[t], x1 = h[t + 256];
  float mu = blockSum(x0 + x1) * (1.f / 512.f);
  float d0 = x0 - mu, d1 = x1 - mu;
  float var = blockSum(d0 * d0 + d1 * d1) * (1.f / 512.f);
  float rs = rsqrtf(var + 1e-5f);
  float y0 = d0 * rs * g[t]       + b[t];
  float y1 = d1 * rs * g[t + 256] + b[t + 256];
  float s0 = blockSum(y0 * w[t]       + y1 * w[t + 256]);
  float s1 = blockSum(y0 * w[512 + t] + y1 * w[512 + t + 256]);
  if (t == 0) {
    out[0] = s0 + fb[0];
    out[1] = s1 + fb[1];
  }
}

// ---------------------------------------------------------------------------
struct AttnW {
  const float *lng, *lnb, *qkvw, *outw, *outb, *resw;
};

static void run_attn(const AttnW& Wt, const u16* qkvw_b, const u16* outw_b,
                     float* h, u16* hn_b, u16* qb, u16* kb, u16* vb, float* F,
                     float* S1, float* ql, float* kl, u16* qlb, u16* klb,
                     float* w3v, float* Wm, u16* WmT_b,
                     float* a2, float* xz, float* t1, float* t2, float* zA, float* zB,
                     float* rs, float* cs, float* inv,
                     float* pm, float* pl, float* poacc,
                     hipStream_t stream)
{
  const long s64 = (long)S * 64;
  ln_pad_b<<<S, 256, 0, stream>>>(h, Wt.lng, Wt.lnb, hn_b, PADR);
  mfma_gemm<2><<<dim3(12, 130, 1), 256, 0, stream>>>(
      hn_b, qkvw_b, nullptr, nullptr, S, 1536, 512, 512, 512, 0,
      0.125f, 0.f, qb, kb, vb, s64);
  landmark_b<<<2048, 64, 0, stream>>>(qb, ql, qlb);
  landmark_b<<<2048, 64, 0, stream>>>(kb, kl, klb);
  // a2 = softmax(ql @ kl^T) — f32 SIMT (feeds pinv)
  mm_kernel<true, 0><<<dim3(4, 4, 8), 256, 0, stream>>>(
      ql, kl, a2, nullptr, 256, 256, 64, 64, 64, 256, 16384, 16384, 65536, 1.f, 0.f, 0);
  rowsoftmax<<<2048, 256, 0, stream>>>(a2);
  rowabs<<<2048, 256, 0, stream>>>(a2, rs);
  colabs<<<2048, 256, 0, stream>>>(a2, cs);
  scaleinv<<<1, 256, 0, stream>>>(rs, cs, inv);
  z0k<<<2048, 256, 0, stream>>>(a2, inv, zA);
  float* zc = zA; float* zo = zB;
  for (int it = 0; it < 6; it++) {
    // xz = a2@zc ; t1 = 7I - xz
    pinv_gemm<3><<<dim3(4, 4, 8), 256, 0, stream>>>(a2, zc, xz, t1, 1.f, 7.f);
    // t2 = 15I - xz@t1
    pinv_gemm<4><<<dim3(4, 4, 8), 256, 0, stream>>>(xz, t1, t2, nullptr, 1.f, 15.f);
    // t1 = 13I - xz@t2
    pinv_gemm<4><<<dim3(4, 4, 8), 256, 0, stream>>>(xz, t2, t1, nullptr, 1.f, 13.f);
    // zo = 0.25 * zc@t1
    pinv_gemm<0><<<dim3(4, 4, 8), 256, 0, stream>>>(zc, t1, zo, nullptr, 0.25f, 0.f);
    float* tmp = zc; zc = zo; zo = tmp;
  }
  // split-K fused a3@v (all heads) + merge
  attn_a3v_split<<<dim3(4, 8, 13), 256, 0, stream>>>(qlb, kb, vb, pm, pl, poacc, s64);
  a3v_merge<<<2048, 64, 0, stream>>>(pm, pl, poacc, w3v);
  // Wm = pinv(a2) @ w3v — f32 SIMT
  mm_kernel<false, 0><<<dim3(1, 4, 8), 256, 0, stream>>>(
      zc, w3v, Wm, nullptr, 256, 64, 256, 256, 64, 64, 65536, 16384, 16384, 1.f, 0.f, 0);
  wm_transpose<<<dim3(64, 8, 1), 256, 0, stream>>>(Wm, WmT_b);
  // fused a1 path (all heads) -> F
  attn_a1<<<dim3(260, 8, 1), 256, 0, stream>>>(qb, klb, WmT_b, F, s64);
  resconv<<<dim3(4160, 8, 1), 256, 0, stream>>>(vb, Wt.resw, F);
  // h += F[PADR:, :] @ outw^T + outb
  u16* Fb = (u16*)S1;
  cvt_f2b<<<8193, 256, 0, stream>>>(F + (long)PADR * CH, Fb, (long)NT * CH);
  mfma_gemm<0><<<dim3(4, 129, 1), 256, 0, stream>>>(
      Fb, outw_b, h, Wt.outb, NT, 512, 512, 512, 512, 512,
      1.f, 1.f, nullptr, nullptr, nullptr, 0);
}

extern "C" void kernel_launch(void* const* d_in, const int* in_sizes, int n_in,
                              void* d_out, int out_size, void* d_ws, size_t ws_size,
                              hipStream_t stream)
{
  const float* X      = (const float*)d_in[0];
  const float* fc1w   = (const float*)d_in[1];
  const float* fc1b   = (const float*)d_in[2];
  const float* clstok = (const float*)d_in[3];
  AttnW w1{ (const float*)d_in[4], (const float*)d_in[5], (const float*)d_in[6],
            (const float*)d_in[7], (const float*)d_in[8], (const float*)d_in[9] };
  const float* w7 = (const float*)d_in[10]; const float* b7 = (const float*)d_in[11];
  const float* w5 = (const float*)d_in[12]; const float* b5 = (const float*)d_in[13];
  const float* w3 = (const float*)d_in[14]; const float* b3 = (const float*)d_in[15];
  AttnW w2{ (const float*)d_in[16], (const float*)d_in[17], (const float*)d_in[18],
            (const float*)d_in[19], (const float*)d_in[20], (const float*)d_in[21] };
  const float* lnfg = (const float*)d_in[22];
  const float* lnfb = (const float*)d_in[23];
  const float* fc2w = (const float*)d_in[24];
  const float* fc2b = (const float*)d_in[25];
  float* out = (float*)d_out;

  char* wsb = (char*)d_ws;
  size_t off = 0;
  auto alloc = [&](size_t nbytes) {
    void* p = wsb + off;
    off = (off + nbytes + 255) & ~(size_t)255;
    return p;
  };
  float* h    = (float*)alloc((size_t)NT * CH * 4);
  float* F    = (float*)alloc((size_t)S * CH * 4);      // attn out; ppeg CHW temp
  u16*  hn_b  = (u16*)alloc((size_t)S * CH * 2);
  u16*  qb    = (u16*)alloc((size_t)S * CH * 2);
  u16*  kb    = (u16*)alloc((size_t)S * CH * 2);
  u16*  vb    = (u16*)alloc((size_t)S * CH * 2);
  float* S1   = (float*)alloc((size_t)S * 256 * 4);     // Fb staging
  char* big   = (char*)alloc(33554432);                 // Xb (bf16) / ppeg f (f32)
  u16*  fc1w_b = (u16*)alloc(524288 * 2);
  u16*  qkv1_b = (u16*)alloc(786432 * 2);
  u16*  qkv2_b = (u16*)alloc(786432 * 2);
  u16*  out1_b = (u16*)alloc(262144 * 2);
  u16*  out2_b = (u16*)alloc(262144 * 2);
  float* ql   = (float*)alloc(131072 * 4);
  float* kl   = (float*)alloc(131072 * 4);
  u16*  qlb   = (u16*)alloc(131072 * 2);
  u16*  klb   = (u16*)alloc(131072 * 2);
  float* w3v  = (float*)alloc(131072 * 4);
  float* Wm   = (float*)alloc(131072 * 4);
  u16*  WmT_b = (u16*)alloc(131072 * 2);
  float* a2   = (float*)alloc(524288 * 4);
  float* xz   = (float*)alloc(524288 * 4);
  float* t1   = (float*)alloc(524288 * 4);
  float* t2   = (float*)alloc(524288 * 4);
  float* zA   = (float*)alloc(524288 * 4);
  float* zB   = (float*)alloc(524288 * 4);
  float* rs   = (float*)alloc(2048 * 4);
  float* cs   = (float*)alloc(2048 * 4);
  float* inv  = (float*)alloc(256);
  float* pm   = (float*)alloc((size_t)8 * 13 * 256 * 4);
  float* pl   = (float*)alloc((size_t)8 * 13 * 256 * 4);
  float* poacc = (float*)alloc((size_t)8 * 13 * 256 * 64 * 4);
  (void)in_sizes; (void)n_in; (void)out_size; (void)ws_size;

  u16* Xb = (u16*)big;
  cvt_f2b<<<16384, 256, 0, stream>>>(X, Xb, (long)16384 * 1024);
  cvt_f2b<<<512, 256, 0, stream>>>(fc1w, fc1w_b, 524288);
  cvt_f2b<<<768, 256, 0, stream>>>(w1.qkvw, qkv1_b, 786432);
  cvt_f2b<<<768, 256, 0, stream>>>(w2.qkvw, qkv2_b, 786432);
  cvt_f2b<<<256, 256, 0, stream>>>(w1.outw, out1_b, 262144);
  cvt_f2b<<<256, 256, 0, stream>>>(w2.outw, out2_b, 262144);

  cls_copy<<<1, 512, 0, stream>>>(clstok, h);
  mfma_gemm<1><<<dim3(4, 128, 1), 256, 0, stream>>>(
      Xb, fc1w_b, h + CH, fc1b, 16384, 512, 1024, 1024, 1024, 512,
      1.f, 0.f, nullptr, nullptr, nullptr, 0);

  run_attn(w1, qkv1_b, out1_b, h, hn_b, qb, kb, vb, F, S1, ql, kl, qlb, klb,
           w3v, Wm, WmT_b, a2, xz, t1, t2, zA, zB, rs, cs, inv,
           pm, pl, poacc, stream);

  // PPEG: h -> CHW(big) -> conv -> CHW(F) -> h
  float* fppeg = (float*)big;
  transpose_feat<<<dim3(512, 16, 1), 256, 0, stream>>>(h, fppeg);
  ppeg_tile<<<dim3(16, 512, 1), 256, 0, stream>>>(fppeg, w7, b7, w5, b5, w3, b3, F);
  transpose_back<<<dim3(512, 16, 1), 256, 0, stream>>>(F, h);

  run_attn(w2, qkv2_b, out2_b, h, hn_b, qb, kb, vb, F, S1, ql, kl, qlb, klb,
           w3v, Wm, WmT_b, a2, xz, t1, t2, zA, zB, rs, cs, inv,
           pm, pl, poacc, stream);

  final_k<<<1, 256, 0, stream>>>(h, lnfg, lnfb, fc2w, fc2b, out);
}

// Round 7
// 1531.038 us; speedup vs baseline: 7.4075x; 1.2179x over previous
//
#include <hip/hip_runtime.h>
#include <hip/hip_bf16.h>

static const int S    = 16640;  // padded sequence (65*256)
static const int PADR = 255;    // zero rows prepended inside attention
static const int NT   = 16385;  // tokens incl cls
static const int CH   = 512;    // hidden dim

typedef unsigned short u16;
typedef __attribute__((ext_vector_type(8))) short short8_t;
typedef __attribute__((ext_vector_type(4))) float float4_t;

__device__ __forceinline__ float b2f(u16 x) {
  union { unsigned u; float f; } t; t.u = (unsigned)x << 16; return t.f;
}
__device__ __forceinline__ u16 f2b(float x) {
  union { float f; unsigned u; } t; t.f = x;
  unsigned r = t.u + 0x7fff + ((t.u >> 16) & 1);
  return (u16)(r >> 16);
}

__device__ __forceinline__ float warpSum(float v) {
#pragma unroll
  for (int off = 32; off; off >>= 1) v += __shfl_xor(v, off);
  return v;
}
__device__ __forceinline__ float warpMax(float v) {
#pragma unroll
  for (int off = 32; off; off >>= 1) v = fmaxf(v, __shfl_xor(v, off));
  return v;
}
__device__ __forceinline__ float blockSum(float v) {
  __shared__ float sm[8];
  int lane = threadIdx.x & 63, wv = threadIdx.x >> 6;
  v = warpSum(v);
  __syncthreads();
  if (lane == 0) sm[wv] = v;
  __syncthreads();
  float t = 0.f;
  int nw = blockDim.x >> 6;
  for (int i = 0; i < nw; i++) t += sm[i];
  return t;
}
__device__ __forceinline__ float blockMax(float v) {
  __shared__ float sm[8];
  int lane = threadIdx.x & 63, wv = threadIdx.x >> 6;
  v = warpMax(v);
  __syncthreads();
  if (lane == 0) sm[wv] = v;
  __syncthreads();
  float t = -1e30f;
  int nw = blockDim.x >> 6;
  for (int i = 0; i < nw; i++) t = fmaxf(t, sm[i]);
  return t;
}

// ---------------------------------------------------------------------------
__global__ __launch_bounds__(256) void cvt_f2b(const float* __restrict__ in,
                                               u16* __restrict__ out, long n) {
  long i = ((long)blockIdx.x * 256 + threadIdx.x) * 4;
  if (i + 3 < n) {
    float4 v = *(const float4*)(in + i);
    out[i] = f2b(v.x); out[i + 1] = f2b(v.y); out[i + 2] = f2b(v.z); out[i + 3] = f2b(v.w);
  } else {
    for (long j = i; j < n; j++) out[j] = f2b(in[j]);
  }
}

// WmT[head][n(64)][k(256)] bf16 <- Wm[head][k(256)][n(64)] f32
__global__ __launch_bounds__(256) void wm_transpose(const float* __restrict__ Wm,
                                                    u16* __restrict__ WmT) {
  int n = blockIdx.x, head = blockIdx.y, k = threadIdx.x;
  WmT[((long)head * 64 + n) * 256 + k] = f2b(Wm[(long)head * 16384 + k * 64 + n]);
}

// ---------------------------------------------------------------------------
// MFMA bf16 GEMM: C(M,N) = A(M,K) * B^T, f32 accumulate. A dtype templated:
//  TA = u16 (bf16) or float (converted to bf16 in staging registers).
//  EPI 0: C = alpha*acc + bias? + beta*C (f32)
//  EPI 1: C = relu(acc + bias) (f32)
//  EPI 2: qkv head-split store bf16
// ---------------------------------------------------------------------------
template <typename TA, int EPI>
__global__ __launch_bounds__(256) void mfma_gemm(
    const TA* __restrict__ A, const u16* __restrict__ B, float* __restrict__ C,
    const float* __restrict__ bias, int M, int N, int K,
    int lda, int ldb, int ldc,
    float alpha, float beta,
    u16* __restrict__ q_o, u16* __restrict__ k_o, u16* __restrict__ v_o, long s64)
{
  __shared__ u16 As[128][40];
  __shared__ u16 Bs[128][40];
  const int tid = threadIdx.x;
  const int m0 = blockIdx.y * 128, n0 = blockIdx.x * 128;
  const int wid = tid >> 6, lane = tid & 63;
  const int wr = wid >> 1, wc = wid & 1;
  const int l15 = lane & 15, l16 = lane >> 4;
  const int arow = tid >> 1, aseg = (tid & 1) * 16;
  float4_t acc[4][4] = {};

  for (int k0 = 0; k0 < K; k0 += 32) {
    {
      int gm = m0 + arow;
      u16 tmp[16];
      if (gm < M) {
        const TA* src = A + (long)gm * lda + k0 + aseg;
        if constexpr (sizeof(TA) == 2) {
          *(short8_t*)&tmp[0] = *(const short8_t*)src;
          *(short8_t*)&tmp[8] = *(const short8_t*)(src + 8);
        } else {
#pragma unroll
          for (int i4 = 0; i4 < 4; i4++) {
            float4 f = *(const float4*)((const float*)src + i4 * 4);
            tmp[i4 * 4 + 0] = f2b(f.x); tmp[i4 * 4 + 1] = f2b(f.y);
            tmp[i4 * 4 + 2] = f2b(f.z); tmp[i4 * 4 + 3] = f2b(f.w);
          }
        }
      } else {
#pragma unroll
        for (int i = 0; i < 16; i++) tmp[i] = 0;
      }
      *(short8_t*)&As[arow][aseg]     = *(short8_t*)&tmp[0];
      *(short8_t*)&As[arow][aseg + 8] = *(short8_t*)&tmp[8];
    }
    {
      int gn = n0 + arow;
      short8_t v0 = {}, v1 = {};
      if (gn < N) {
        const u16* src = B + (long)gn * ldb + k0 + aseg;
        v0 = *(const short8_t*)src; v1 = *(const short8_t*)(src + 8);
      }
      *(short8_t*)&Bs[arow][aseg]     = v0;
      *(short8_t*)&Bs[arow][aseg + 8] = v1;
    }
    __syncthreads();
    short8_t af[4], bfr[4];
#pragma unroll
    for (int i = 0; i < 4; i++)
      af[i] = *(const short8_t*)&As[wr * 64 + i * 16 + l15][l16 * 8];
#pragma unroll
    for (int i = 0; i < 4; i++)
      bfr[i] = *(const short8_t*)&Bs[wc * 64 + i * 16 + l15][l16 * 8];
#pragma unroll
    for (int i = 0; i < 4; i++)
#pragma unroll
      for (int j = 0; j < 4; j++)
        acc[i][j] = __builtin_amdgcn_mfma_f32_16x16x32_bf16(af[i], bfr[j], acc[i][j], 0, 0, 0);
    __syncthreads();
  }

#pragma unroll
  for (int mi = 0; mi < 4; mi++) {
#pragma unroll
    for (int ni = 0; ni < 4; ni++) {
#pragma unroll
      for (int j = 0; j < 4; j++) {
        int r = m0 + wr * 64 + mi * 16 + l16 * 4 + j;
        int c = n0 + wc * 64 + ni * 16 + l15;
        if (r >= M || c >= N) continue;
        float v = acc[mi][ni][j];
        if constexpr (EPI == 0) {
          long idx = (long)r * ldc + c;
          float o = alpha * v;
          if (bias) o += bias[c];
          if (beta != 0.f) o += beta * C[idx];
          C[idx] = o;
        } else if constexpr (EPI == 1) {
          long idx = (long)r * ldc + c;
          C[idx] = fmaxf(v + bias[c], 0.f);
        } else {  // EPI == 2: qkv split
          int sec = c >> 9, hcol = c & 511;
          int head = hcol >> 6, d = hcol & 63;
          u16* dst = (sec == 0) ? q_o : (sec == 1 ? k_o : v_o);
          float o = (sec == 0) ? v * alpha : v;
          dst[(long)head * s64 + (long)r * 64 + d] = f2b(o);
        }
      }
    }
  }
}

// ---------------------------------------------------------------------------
// f32-grade MFMA GEMM via bf16 hi/lo split (3 MFMAs per product).
// 256x256x256 per head, batched over blockIdx.z heads. 64x64 tile per block.
// MODE 0: C = alpha*acc ; MODE 3: C = acc, C2 = beta*I - acc ; MODE 4: C = beta*I - acc
template <int MODE>
__global__ __launch_bounds__(256) void pinv_gemm(
    const float* __restrict__ A, const float* __restrict__ B,
    float* __restrict__ C, float* __restrict__ C2, float alpha, float beta)
{
  __shared__ u16 Ah[64][40], Al[64][40], Bh[64][40], Bl[64][40];
  const int tid = threadIdx.x;
  const long zoff = (long)blockIdx.z << 16;
  A += zoff; B += zoff; C += zoff;
  if constexpr (MODE == 3) C2 += zoff;
  const int m0 = blockIdx.y * 64, n0 = blockIdx.x * 64;
  const int wid = tid >> 6, lane = tid & 63;
  const int wr = wid >> 1, wc = wid & 1;
  const int l15 = lane & 15, l16 = lane >> 4;
  const int arow = tid >> 2, aseg = (tid & 3) * 8;
  const int bk = tid >> 3, bn = (tid & 7) * 8;
  float4_t acc[2][2] = {};

  for (int k0 = 0; k0 < 256; k0 += 32) {
    {
      const float* src = A + (long)(m0 + arow) * 256 + k0 + aseg;
#pragma unroll
      for (int i = 0; i < 8; i++) {
        float v = src[i];
        u16 hi = f2b(v);
        Ah[arow][aseg + i] = hi;
        Al[arow][aseg + i] = f2b(v - b2f(hi));
      }
    }
    {
      const float* src = B + (long)(k0 + bk) * 256 + n0 + bn;
#pragma unroll
      for (int i = 0; i < 8; i++) {
        float v = src[i];
        u16 hi = f2b(v);
        Bh[bn + i][bk] = hi;
        Bl[bn + i][bk] = f2b(v - b2f(hi));
      }
    }
    __syncthreads();
    short8_t ah[2], al[2], bh[2], bl[2];
#pragma unroll
    for (int i = 0; i < 2; i++) {
      ah[i] = *(const short8_t*)&Ah[wr * 32 + i * 16 + l15][l16 * 8];
      al[i] = *(const short8_t*)&Al[wr * 32 + i * 16 + l15][l16 * 8];
      bh[i] = *(const short8_t*)&Bh[wc * 32 + i * 16 + l15][l16 * 8];
      bl[i] = *(const short8_t*)&Bl[wc * 32 + i * 16 + l15][l16 * 8];
    }
#pragma unroll
    for (int i = 0; i < 2; i++)
#pragma unroll
      for (int j = 0; j < 2; j++) {
        acc[i][j] = __builtin_amdgcn_mfma_f32_16x16x32_bf16(ah[i], bh[j], acc[i][j], 0, 0, 0);
        acc[i][j] = __builtin_amdgcn_mfma_f32_16x16x32_bf16(ah[i], bl[j], acc[i][j], 0, 0, 0);
        acc[i][j] = __builtin_amdgcn_mfma_f32_16x16x32_bf16(al[i], bh[j], acc[i][j], 0, 0, 0);
      }
    __syncthreads();
  }

#pragma unroll
  for (int i = 0; i < 2; i++)
#pragma unroll
    for (int n2 = 0; n2 < 2; n2++)
#pragma unroll
      for (int j = 0; j < 4; j++) {
        int r = m0 + wr * 32 + i * 16 + l16 * 4 + j;
        int c = n0 + wc * 32 + n2 * 16 + l15;
        long idx = (long)r * 256 + c;
        float v = acc[i][n2][j];
        if constexpr (MODE == 0) {
          C[idx] = alpha * v;
        } else if constexpr (MODE == 3) {
          C[idx] = v;
          C2[idx] = ((r == c) ? beta : 0.f) - v;
        } else {
          C[idx] = ((r == c) ? beta : 0.f) - v;
        }
      }
}

// ---------------------------------------------------------------------------
// Fused a1 path: F[s][head*64+d] = softmax(q_h[s,:] @ kl_h^T) @ Wm_h
// grid (260 row-tiles, 8 heads), 256 thr (4 waves x 16 rows).
__global__ __launch_bounds__(256) void attn_a1(
    const u16* __restrict__ qb, const u16* __restrict__ klb,
    const u16* __restrict__ WmT, float* __restrict__ F, long s64)
{
  __shared__ u16 Ps[4][16][264];
  const int tid = threadIdx.x;
  const int w = tid >> 6, lane = tid & 63;
  const int l15 = lane & 15, l16 = lane >> 4;
  const int head = blockIdx.y;
  const int row0 = blockIdx.x * 64 + w * 16;

  short8_t aq[2];
#pragma unroll
  for (int slab = 0; slab < 2; slab++)
    aq[slab] = *(const short8_t*)(qb + (long)head * s64 + (long)(row0 + l15) * 64 + slab * 32 + l16 * 8);

  float4_t sacc[16] = {};
  const u16* klh = klb + (long)head * 16384;
#pragma unroll
  for (int nt = 0; nt < 16; nt++) {
#pragma unroll
    for (int slab = 0; slab < 2; slab++) {
      short8_t bfr = *(const short8_t*)(klh + (long)(nt * 16 + l15) * 64 + slab * 32 + l16 * 8);
      sacc[nt] = __builtin_amdgcn_mfma_f32_16x16x32_bf16(aq[slab], bfr, sacc[nt], 0, 0, 0);
    }
  }
  float rcp[4];
#pragma unroll
  for (int reg = 0; reg < 4; reg++) {
    float m = -1e30f;
#pragma unroll
    for (int nt = 0; nt < 16; nt++) m = fmaxf(m, sacc[nt][reg]);
#pragma unroll
    for (int mk = 1; mk <= 8; mk <<= 1) m = fmaxf(m, __shfl_xor(m, mk));
    float s = 0.f;
#pragma unroll
    for (int nt = 0; nt < 16; nt++) { float e = __expf(sacc[nt][reg] - m); sacc[nt][reg] = e; s += e; }
#pragma unroll
    for (int mk = 1; mk <= 8; mk <<= 1) s += __shfl_xor(s, mk);
    rcp[reg] = 1.f / s;
  }
#pragma unroll
  for (int nt = 0; nt < 16; nt++)
#pragma unroll
    for (int reg = 0; reg < 4; reg++)
      Ps[w][4 * l16 + reg][nt * 16 + l15] = f2b(sacc[nt][reg]);
  __syncthreads();
  float4_t oacc[4] = {};
  const u16* wmh = WmT + (long)head * 16384;
#pragma unroll
  for (int ks = 0; ks < 8; ks++) {
    short8_t pa = *(const short8_t*)&Ps[w][l15][ks * 32 + l16 * 8];
#pragma unroll
    for (int vt = 0; vt < 4; vt++) {
      short8_t bv = *(const short8_t*)(wmh + (long)(vt * 16 + l15) * 256 + ks * 32 + l16 * 8);
      oacc[vt] = __builtin_amdgcn_mfma_f32_16x16x32_bf16(pa, bv, oacc[vt], 0, 0, 0);
    }
  }
#pragma unroll
  for (int vt = 0; vt < 4; vt++)
#pragma unroll
    for (int reg = 0; reg < 4; reg++) {
      int r = row0 + 4 * l16 + reg;
      F[(long)r * CH + head * 64 + vt * 16 + l15] = oacc[vt][reg] * rcp[reg];
    }
}

// ---------------------------------------------------------------------------
// Split-K fused a3@v: each block handles 10 key-tiles (1280 keys) of one head,
// with local online softmax; writes per-split partials (m, l, unnormalized O).
// grid (4 row-quarters, 8 heads, 13 splits), 256 thr (4 waves x 16 rows).
__global__ __launch_bounds__(256) void attn_a3v_split(
    const u16* __restrict__ qlb, const u16* __restrict__ kb,
    const u16* __restrict__ vb,
    float* __restrict__ pm, float* __restrict__ pl, float* __restrict__ poacc,
    long s64)
{
  __shared__ u16 Vt[64][136];       // V^T tile: [d][key]
  __shared__ u16 Ps[4][16][136];
  const int tid = threadIdx.x;
  const int w = tid >> 6, lane = tid & 63;
  const int l15 = lane & 15, l16 = lane >> 4;
  const int head = blockIdx.y;
  const int split = blockIdx.z;
  const int row0 = blockIdx.x * 64 + w * 16;

  short8_t aq[2];
#pragma unroll
  for (int slab = 0; slab < 2; slab++)
    aq[slab] = *(const short8_t*)(qlb + (long)head * 16384 + (long)(row0 + l15) * 64 + slab * 32 + l16 * 8);

  float m[4], l[4];
  float4_t oacc[4] = {};
#pragma unroll
  for (int r = 0; r < 4; r++) { m[r] = -1e30f; l[r] = 0.f; }

  const u16* kh = kb + (long)head * s64;
  const u16* vh = vb + (long)head * s64;
  const int vrow = tid >> 1, vhalf = (tid & 1) * 32;

  const int kt0 = split * 10;
  for (int kt = kt0; kt < kt0 + 10; kt++) {
    const int j0 = kt * 128;
    __syncthreads();
    {
      const u16* src = vh + (long)(j0 + vrow) * 64 + vhalf;
#pragma unroll
      for (int i = 0; i < 32; i++) Vt[vhalf + i][vrow] = src[i];
    }
    float4_t sacc[8] = {};
#pragma unroll
    for (int nt = 0; nt < 8; nt++) {
#pragma unroll
      for (int slab = 0; slab < 2; slab++) {
        short8_t bfr = *(const short8_t*)(kh + (long)(j0 + nt * 16 + l15) * 64 + slab * 32 + l16 * 8);
        sacc[nt] = __builtin_amdgcn_mfma_f32_16x16x32_bf16(aq[slab], bfr, sacc[nt], 0, 0, 0);
      }
    }
    float scale[4];
#pragma unroll
    for (int reg = 0; reg < 4; reg++) {
      float tm = -1e30f;
#pragma unroll
      for (int nt = 0; nt < 8; nt++) tm = fmaxf(tm, sacc[nt][reg]);
#pragma unroll
      for (int mk = 1; mk <= 8; mk <<= 1) tm = fmaxf(tm, __shfl_xor(tm, mk));
      float nm = fmaxf(m[reg], tm);
      scale[reg] = __expf(m[reg] - nm);
      m[reg] = nm;
      float ts = 0.f;
#pragma unroll
      for (int nt = 0; nt < 8; nt++) {
        float e = __expf(sacc[nt][reg] - nm);
        sacc[nt][reg] = e; ts += e;
      }
#pragma unroll
      for (int mk = 1; mk <= 8; mk <<= 1) ts += __shfl_xor(ts, mk);
      l[reg] = l[reg] * scale[reg] + ts;
#pragma unroll
      for (int vt = 0; vt < 4; vt++) oacc[vt][reg] *= scale[reg];
    }
    __syncthreads();
#pragma unroll
    for (int nt = 0; nt < 8; nt++)
#pragma unroll
      for (int reg = 0; reg < 4; reg++)
        Ps[w][4 * l16 + reg][nt * 16 + l15] = f2b(sacc[nt][reg]);
#pragma unroll
    for (int ks = 0; ks < 4; ks++) {
      short8_t pa = *(const short8_t*)&Ps[w][l15][ks * 32 + l16 * 8];
#pragma unroll
      for (int vt = 0; vt < 4; vt++) {
        short8_t bv = *(const short8_t*)&Vt[vt * 16 + l15][ks * 32 + l16 * 8];
        oacc[vt] = __builtin_amdgcn_mfma_f32_16x16x32_bf16(pa, bv, oacc[vt], 0, 0, 0);
      }
    }
  }
#pragma unroll
  for (int reg = 0; reg < 4; reg++) {
    int r = row0 + 4 * l16 + reg;
    long pidx = ((long)(head * 13 + split) << 8) + r;
    if (l15 == 0) { pm[pidx] = m[reg]; pl[pidx] = l[reg]; }
#pragma unroll
    for (int vt = 0; vt < 4; vt++)
      poacc[(pidx << 6) + vt * 16 + l15] = oacc[vt][reg];
  }
}

// merge split partials
__global__ __launch_bounds__(64) void a3v_merge(const float* __restrict__ pm,
    const float* __restrict__ pl, const float* __restrict__ poacc,
    float* __restrict__ w3v)
{
  int hb = blockIdx.x;            // head*256 + row
  int head = hb >> 8, row = hb & 255;
  int d = threadIdx.x;
  float M = -1e30f;
  for (int sp = 0; sp < 13; sp++)
    M = fmaxf(M, pm[((long)(head * 13 + sp) << 8) + row]);
  float num = 0.f, den = 0.f;
  for (int sp = 0; sp < 13; sp++) {
    long pidx = ((long)(head * 13 + sp) << 8) + row;
    float sc = __expf(pm[pidx] - M);
    den += pl[pidx] * sc;
    num += poacc[(pidx << 6) + d] * sc;
  }
  w3v[((long)head << 14) + ((long)row << 6) + d] = num / den;
}

// ---------------------------------------------------------------------------
// SIMT f32 tiled matmul (a2 scores, Wm).
template <bool BT, int MODE>
__global__ __launch_bounds__(256) void mm_kernel(
    const float* __restrict__ A, const float* __restrict__ Bm, float* __restrict__ C,
    const float* __restrict__ bias,
    int M, int N, int K, int lda, int ldb, int ldc,
    long sA, long sB, long sC, float alpha, float beta, long s64)
{
  __shared__ float As[16][64];
  __shared__ float Bs[16][64];
  const int bz = blockIdx.z;
  A  += (long)bz * sA;
  Bm += (long)bz * sB;
  C  += (long)bz * sC;
  const int m0 = blockIdx.y * 64, n0 = blockIdx.x * 64;
  const int tid = threadIdx.x;
  const int tm = tid >> 4, tn = tid & 15;
  const int ar = tid >> 2;
  const int ac = (tid & 3) << 2;
  float acc[4][4] = {};
  for (int k0 = 0; k0 < K; k0 += 16) {
#pragma unroll
    for (int i = 0; i < 4; i++) {
      int gm = m0 + ar, gk = k0 + ac + i;
      As[ac + i][ar] = (gm < M && gk < K) ? A[(long)gm * lda + gk] : 0.f;
    }
    if constexpr (BT) {
#pragma unroll
      for (int i = 0; i < 4; i++) {
        int gn = n0 + ar, gk = k0 + ac + i;
        Bs[ac + i][ar] = (gn < N && gk < K) ? Bm[(long)gn * ldb + gk] : 0.f;
      }
    } else {
      int bk = tid >> 4;
      int bn = (tid & 15) << 2;
#pragma unroll
      for (int i = 0; i < 4; i++) {
        int gk = k0 + bk, gn = n0 + bn + i;
        Bs[bk][bn + i] = (gk < K && gn < N) ? Bm[(long)gk * ldb + gn] : 0.f;
      }
    }
    __syncthreads();
#pragma unroll
    for (int kk = 0; kk < 16; kk++) {
      float a[4], b[4];
#pragma unroll
      for (int i = 0; i < 4; i++) { a[i] = As[kk][tm * 4 + i]; b[i] = Bs[kk][tn * 4 + i]; }
#pragma unroll
      for (int i = 0; i < 4; i++)
#pragma unroll
        for (int j = 0; j < 4; j++)
          acc[i][j] = fmaf(a[i], b[j], acc[i][j]);
    }
    __syncthreads();
  }
#pragma unroll
  for (int i = 0; i < 4; i++) {
    int row = m0 + tm * 4 + i;
    if (row >= M) continue;
#pragma unroll
    for (int j = 0; j < 4; j++) {
      int col = n0 + tn * 4 + j;
      if (col >= N) continue;
      long idx = (long)row * ldc + col;
      float v = acc[i][j];
      float o = alpha * v;
      if (bias) o += bias[col];
      C[idx] = (beta != 0.f) ? o + beta * C[idx] : o;
    }
  }
}

// ---------------------------------------------------------------------------
__global__ void cls_copy(const float* __restrict__ c, float* __restrict__ h) {
  h[threadIdx.x] = c[threadIdx.x];
}

__global__ __launch_bounds__(256) void ln_pad_b(const float* __restrict__ h,
    const float* __restrict__ g, const float* __restrict__ b,
    u16* __restrict__ out, int pad)
{
  int s = blockIdx.x, t = threadIdx.x;
  u16* o = out + (long)s * CH;
  if (s < pad) { o[t] = 0; o[t + 256] = 0; return; }
  const float* x = h + (long)(s - pad) * CH;
  float x0 = x[t], x1 = x[t + 256];
  float mu = blockSum(x0 + x1) * (1.f / 512.f);
  float d0 = x0 - mu, d1 = x1 - mu;
  float var = blockSum(d0 * d0 + d1 * d1) * (1.f / 512.f);
  float rs = rsqrtf(var + 1e-5f);
  o[t]       = f2b(d0 * rs * g[t]       + b[t]);
  o[t + 256] = f2b(d1 * rs * g[t + 256] + b[t + 256]);
}

__global__ __launch_bounds__(64) void landmark_b(const u16* __restrict__ q,
    float* __restrict__ ql, u16* __restrict__ qlb) {
  int hb = blockIdx.x;
  int d = threadIdx.x;
  int hh = hb >> 8, j = hb & 255;
  const u16* src = q + ((long)hh * S + (long)j * 65) * 64 + d;
  float s = 0.f;
  for (int g2 = 0; g2 < 65; g2++) s += b2f(src[(long)g2 * 64]);
  s *= (1.f / 65.f);
  ql[(long)hb * 64 + d] = s;
  qlb[(long)hb * 64 + d] = f2b(s);
}

__global__ __launch_bounds__(256) void rowsoftmax(float* __restrict__ X) {
  float* row = X + (long)blockIdx.x * 256;
  int t = threadIdx.x;
  float x = row[t];
  float m = blockMax(x);
  float e = __expf(x - m);
  float s = blockSum(e);
  row[t] = e / s;
}

__global__ __launch_bounds__(256) void rowabs(const float* __restrict__ a2, float* __restrict__ rs) {
  int r = blockIdx.x;
  float s = blockSum(fabsf(a2[(long)r * 256 + threadIdx.x]));
  if (threadIdx.x == 0) rs[r] = s;
}
__global__ __launch_bounds__(256) void colabs(const float* __restrict__ a2, float* __restrict__ cs) {
  int hb = blockIdx.x; int hh = hb >> 8, j = hb & 255;
  float s = blockSum(fabsf(a2[((long)hh * 256 + threadIdx.x) * 256 + j]));
  if (threadIdx.x == 0) cs[hb] = s;
}
__global__ __launch_bounds__(256) void scaleinv(const float* __restrict__ rs,
                                                const float* __restrict__ cs, float* __restrict__ inv) {
  float m1 = -1e30f, m2 = -1e30f;
  for (int i = threadIdx.x; i < 2048; i += 256) { m1 = fmaxf(m1, rs[i]); m2 = fmaxf(m2, cs[i]); }
  m1 = blockMax(m1);
  m2 = blockMax(m2);
  if (threadIdx.x == 0) inv[0] = 1.f / (m1 * m2);
}
__global__ __launch_bounds__(256) void z0k(const float* __restrict__ a2,
                                           const float* __restrict__ inv, float* __restrict__ z) {
  int hb = blockIdx.x; int hh = hb >> 8, i = hb & 255; int j = threadIdx.x;
  z[(long)hb * 256 + j] = a2[((long)hh * 256 + j) * 256 + i] * inv[0];
}

// ---------------------------------------------------------------------------
// LDS-tiled depthwise residual conv (kernel 33, pad 16): F += conv(v).
// grid (130 position-chunks of 128, 8 heads); 256 thr = 4 pos-groups x 64 d.
// Stage 160 rows of v in LDS; register sliding window (8 outputs / 40 taps).
__global__ __launch_bounds__(256) void resconv2(const u16* __restrict__ v,
    const float* __restrict__ w, float* __restrict__ F)
{
  __shared__ u16 T[160][64];
  __shared__ float ws[33];
  const int hh = blockIdx.y;
  const int p0 = blockIdx.x * 128;
  const int tid = threadIdx.x;
  if (tid < 33) ws[tid] = w[hh * 33 + tid];
  const u16* vh = v + (long)hh * S * 64;
  // stage rows p0-16 .. p0+143 (160 rows x 64 d), 16-elem chunks
  for (int idx = tid; idx < 640; idx += 256) {
    int row = idx >> 2, seg = (idx & 3) * 16;
    int j = p0 - 16 + row;
    short8_t a = {}, b = {};
    if (0 <= j && j < S) {
      const u16* src = vh + (long)j * 64 + seg;
      a = *(const short8_t*)src; b = *(const short8_t*)(src + 8);
    }
    *(short8_t*)&T[row][seg]     = a;
    *(short8_t*)&T[row][seg + 8] = b;
  }
  __syncthreads();
  const int d = tid & 63;
  const int pg = tid >> 6;            // 32 positions per thread
  float wreg[33];
#pragma unroll
  for (int t = 0; t < 33; t++) wreg[t] = ws[t];
#pragma unroll
  for (int g = 0; g < 4; g++) {
    const int base = pg * 32 + g * 8;  // local output position of group start
    float win[40];
#pragma unroll
    for (int i = 0; i < 40; i++) win[i] = b2f(T[base + i][d]);
#pragma unroll
    for (int p = 0; p < 8; p++) {
      float acc = 0.f;
#pragma unroll
      for (int t = 0; t < 33; t++) acc = fmaf(wreg[t], win[p + t], acc);
      F[(long)(p0 + base + p) * CH + hh * 64 + d] += acc;
    }
  }
}

// h feat rows (1..16384, 512 cols) -> f (512, 16384) CHW
__global__ __launch_bounds__(256) void transpose_feat(const float* __restrict__ h, float* __restrict__ f) {
  __shared__ float tile[32][33];
  int p0 = blockIdx.x * 32;
  int c0 = blockIdx.y * 32;
  int tx = threadIdx.x & 31, ty = threadIdx.x >> 5;
  for (int i = 0; i < 32; i += 8)
    tile[ty + i][tx] = h[(long)(1 + p0 + ty + i) * CH + c0 + tx];
  __syncthreads();
  for (int i = 0; i < 32; i += 8)
    f[(long)(c0 + ty + i) * 16384 + p0 + tx] = tile[tx][ty + i];
}

// PPEG conv, LDS-tiled
__global__ __launch_bounds__(256) void ppeg_tile(const float* __restrict__ f,
    const float* __restrict__ w7, const float* __restrict__ b7,
    const float* __restrict__ w5, const float* __restrict__ b5,
    const float* __restrict__ w3, const float* __restrict__ b3,
    float* __restrict__ fo)
{
  __shared__ float T[38][40];
  __shared__ float W7s[49], W5s[25], W3s[9];
  int c = blockIdx.y;
  int ty0 = (blockIdx.x >> 2) * 32, tx0 = (blockIdx.x & 3) * 32;
  int tid = threadIdx.x;
  if (tid < 49) W7s[tid] = w7[c * 49 + tid];
  if (tid < 25) W5s[tid] = w5[c * 25 + tid];
  if (tid < 9)  W3s[tid] = w3[c * 9 + tid];
  const float* fc = f + (long)c * 16384;
  for (int idx = tid; idx < 38 * 38; idx += 256) {
    int r = idx / 38, cc = idx - r * 38;
    int y = ty0 + r - 3, x = tx0 + cc - 3;
    T[r][cc] = (0 <= y && y < 128 && 0 <= x && x < 128) ? fc[y * 128 + x] : 0.f;
  }
  __syncthreads();
  float bsum = b7[c] + b5[c] + b3[c];
#pragma unroll
  for (int p = 0; p < 4; p++) {
    int px = tid + p * 256;
    int y = px >> 5, x = px & 31;
    float acc = T[y + 3][x + 3] + bsum;
#pragma unroll
    for (int dy = 0; dy < 7; dy++)
#pragma unroll
      for (int dx = 0; dx < 7; dx++)
        acc += W7s[dy * 7 + dx] * T[y + dy][x + dx];
#pragma unroll
    for (int dy = 0; dy < 5; dy++)
#pragma unroll
      for (int dx = 0; dx < 5; dx++)
        acc += W5s[dy * 5 + dx] * T[y + dy + 1][x + dx + 1];
#pragma unroll
    for (int dy = 0; dy < 3; dy++)
#pragma unroll
      for (int dx = 0; dx < 3; dx++)
        acc += W3s[dy * 3 + dx] * T[y + dy + 2][x + dx + 2];
    fo[(long)c * 16384 + (ty0 + y) * 128 + tx0 + x] = acc;
  }
}

// fo (512,16384) CHW -> h rows 1..16384
__global__ __launch_bounds__(256) void transpose_back(const float* __restrict__ fo, float* __restrict__ h) {
  __shared__ float tile[32][33];
  int p0 = blockIdx.x * 32;
  int c0 = blockIdx.y * 32;
  int tx = threadIdx.x & 31, ty = threadIdx.x >> 5;
  for (int i = 0; i < 32; i += 8)
    tile[ty + i][tx] = fo[(long)(c0 + ty + i) * 16384 + p0 + tx];
  __syncthreads();
  for (int i = 0; i < 32; i += 8)
    h[(long)(1 + p0 + ty + i) * CH + c0 + tx] = tile[tx][ty + i];
}

// final: LN(h row 0) then 2-class head
__global__ __launch_bounds__(256) void final_k(const float* __restrict__ h,
    const float* __restrict__ g, const float* __restrict__ b,
    const float* __restrict__ w, const float* __restrict__ fb, float* __restrict__ out)
{
  int t = threadIdx.x;
  float x0 = h[t], x1 = h[t + 256];
  float mu = blockSum(x0 + x1) * (1.f / 512.f);
  float d0 = x0 - mu, d1 = x1 - mu;
  float var = blockSum(d0 * d0 + d1 * d1) * (1.f / 512.f);
  float rs = rsqrtf(var + 1e-5f);
  float y0 = d0 * rs * g[t]       + b[t];
  float y1 = d1 * rs * g[t + 256] + b[t + 256];
  float s0 = blockSum(y0 * w[t]       + y1 * w[t + 256]);
  float s1 = blockSum(y0 * w[512 + t] + y1 * w[512 + t + 256]);
  if (t == 0) {
    out[0] = s0 + fb[0];
    out[1] = s1 + fb[1];
  }
}

// ---------------------------------------------------------------------------
struct AttnW {
  const float *lng, *lnb, *qkvw, *outw, *outb, *resw;
};

static void run_attn(const AttnW& Wt, const u16* qkvw_b, const u16* outw_b,
                     float* h, u16* hn_b, u16* qb, u16* kb, u16* vb, float* F,
                     float* ql, float* kl, u16* qlb, u16* klb,
                     float* w3v, float* Wm, u16* WmT_b,
                     float* a2, float* xz, float* t1, float* t2, float* zA, float* zB,
                     float* rs, float* cs, float* inv,
                     float* pm, float* pl, float* poacc,
                     hipStream_t stream)
{
  const long s64 = (long)S * 64;
  ln_pad_b<<<S, 256, 0, stream>>>(h, Wt.lng, Wt.lnb, hn_b, PADR);
  mfma_gemm<u16, 2><<<dim3(12, 130, 1), 256, 0, stream>>>(
      hn_b, qkvw_b, nullptr, nullptr, S, 1536, 512, 512, 512, 0,
      0.125f, 0.f, qb, kb, vb, s64);
  landmark_b<<<2048, 64, 0, stream>>>(qb, ql, qlb);
  landmark_b<<<2048, 64, 0, stream>>>(kb, kl, klb);
  // a2 = softmax(ql @ kl^T) — f32 SIMT (feeds pinv)
  mm_kernel<true, 0><<<dim3(4, 4, 8), 256, 0, stream>>>(
      ql, kl, a2, nullptr, 256, 256, 64, 64, 64, 256, 16384, 16384, 65536, 1.f, 0.f, 0);
  rowsoftmax<<<2048, 256, 0, stream>>>(a2);
  rowabs<<<2048, 256, 0, stream>>>(a2, rs);
  colabs<<<2048, 256, 0, stream>>>(a2, cs);
  scaleinv<<<1, 256, 0, stream>>>(rs, cs, inv);
  z0k<<<2048, 256, 0, stream>>>(a2, inv, zA);
  float* zc = zA; float* zo = zB;
  for (int it = 0; it < 6; it++) {
    pinv_gemm<3><<<dim3(4, 4, 8), 256, 0, stream>>>(a2, zc, xz, t1, 1.f, 7.f);
    pinv_gemm<4><<<dim3(4, 4, 8), 256, 0, stream>>>(xz, t1, t2, nullptr, 1.f, 15.f);
    pinv_gemm<4><<<dim3(4, 4, 8), 256, 0, stream>>>(xz, t2, t1, nullptr, 1.f, 13.f);
    pinv_gemm<0><<<dim3(4, 4, 8), 256, 0, stream>>>(zc, t1, zo, nullptr, 0.25f, 0.f);
    float* tmp = zc; zc = zo; zo = tmp;
  }
  attn_a3v_split<<<dim3(4, 8, 13), 256, 0, stream>>>(qlb, kb, vb, pm, pl, poacc, s64);
  a3v_merge<<<2048, 64, 0, stream>>>(pm, pl, poacc, w3v);
  mm_kernel<false, 0><<<dim3(1, 4, 8), 256, 0, stream>>>(
      zc, w3v, Wm, nullptr, 256, 64, 256, 256, 64, 64, 65536, 16384, 16384, 1.f, 0.f, 0);
  wm_transpose<<<dim3(64, 8, 1), 256, 0, stream>>>(Wm, WmT_b);
  attn_a1<<<dim3(260, 8, 1), 256, 0, stream>>>(qb, klb, WmT_b, F, s64);
  resconv2<<<dim3(130, 8, 1), 256, 0, stream>>>(vb, Wt.resw, F);
  // h += F[PADR:, :] @ outw^T + outb  (A read as f32 directly)
  mfma_gemm<float, 0><<<dim3(4, 129, 1), 256, 0, stream>>>(
      F + (long)PADR * CH, outw_b, h, Wt.outb, NT, 512, 512, 512, 512, 512,
      1.f, 1.f, nullptr, nullptr, nullptr, 0);
}

extern "C" void kernel_launch(void* const* d_in, const int* in_sizes, int n_in,
                              void* d_out, int out_size, void* d_ws, size_t ws_size,
                              hipStream_t stream)
{
  const float* X      = (const float*)d_in[0];
  const float* fc1w   = (const float*)d_in[1];
  const float* fc1b   = (const float*)d_in[2];
  const float* clstok = (const float*)d_in[3];
  AttnW w1{ (const float*)d_in[4], (const float*)d_in[5], (const float*)d_in[6],
            (const float*)d_in[7], (const float*)d_in[8], (const float*)d_in[9] };
  const float* w7 = (const float*)d_in[10]; const float* b7 = (const float*)d_in[11];
  const float* w5 = (const float*)d_in[12]; const float* b5 = (const float*)d_in[13];
  const float* w3 = (const float*)d_in[14]; const float* b3 = (const float*)d_in[15];
  AttnW w2{ (const float*)d_in[16], (const float*)d_in[17], (const float*)d_in[18],
            (const float*)d_in[19], (const float*)d_in[20], (const float*)d_in[21] };
  const float* lnfg = (const float*)d_in[22];
  const float* lnfb = (const float*)d_in[23];
  const float* fc2w = (const float*)d_in[24];
  const float* fc2b = (const float*)d_in[25];
  float* out = (float*)d_out;

  char* wsb = (char*)d_ws;
  size_t off = 0;
  auto alloc = [&](size_t nbytes) {
    void* p = wsb + off;
    off = (off + nbytes + 255) & ~(size_t)255;
    return p;
  };
  float* h    = (float*)alloc((size_t)NT * CH * 4);
  float* F    = (float*)alloc((size_t)S * CH * 4);      // attn out; ppeg CHW temp
  u16*  hn_b  = (u16*)alloc((size_t)S * CH * 2);
  u16*  qb    = (u16*)alloc((size_t)S * CH * 2);
  u16*  kb    = (u16*)alloc((size_t)S * CH * 2);
  u16*  vb    = (u16*)alloc((size_t)S * CH * 2);
  char* big   = (char*)alloc(33554432);                 // ppeg CHW f32
  u16*  fc1w_b = (u16*)alloc(524288 * 2);
  u16*  qkv1_b = (u16*)alloc(786432 * 2);
  u16*  qkv2_b = (u16*)alloc(786432 * 2);
  u16*  out1_b = (u16*)alloc(262144 * 2);
  u16*  out2_b = (u16*)alloc(262144 * 2);
  float* ql   = (float*)alloc(131072 * 4);
  float* kl   = (float*)alloc(131072 * 4);
  u16*  qlb   = (u16*)alloc(131072 * 2);
  u16*  klb   = (u16*)alloc(131072 * 2);
  float* w3v  = (float*)alloc(131072 * 4);
  float* Wm   = (float*)alloc(131072 * 4);
  u16*  WmT_b = (u16*)alloc(131072 * 2);
  float* a2   = (float*)alloc(524288 * 4);
  float* xz   = (float*)alloc(524288 * 4);
  float* t1   = (float*)alloc(524288 * 4);
  float* t2   = (float*)alloc(524288 * 4);
  float* zA   = (float*)alloc(524288 * 4);
  float* zB   = (float*)alloc(524288 * 4);
  float* rs   = (float*)alloc(2048 * 4);
  float* cs   = (float*)alloc(2048 * 4);
  float* inv  = (float*)alloc(256);
  float* pm   = (float*)alloc((size_t)8 * 13 * 256 * 4);
  float* pl   = (float*)alloc((size_t)8 * 13 * 256 * 4);
  float* poacc = (float*)alloc((size_t)8 * 13 * 256 * 64 * 4);
  (void)in_sizes; (void)n_in; (void)out_size; (void)ws_size;

  // weight conversions (small; X and F are consumed as f32 directly now)
  cvt_f2b<<<512, 256, 0, stream>>>(fc1w, fc1w_b, 524288);
  cvt_f2b<<<768, 256, 0, stream>>>(w1.qkvw, qkv1_b, 786432);
  cvt_f2b<<<768, 256, 0, stream>>>(w2.qkvw, qkv2_b, 786432);
  cvt_f2b<<<256, 256, 0, stream>>>(w1.outw, out1_b, 262144);
  cvt_f2b<<<256, 256, 0, stream>>>(w2.outw, out2_b, 262144);

  cls_copy<<<1, 512, 0, stream>>>(clstok, h);
  mfma_gemm<float, 1><<<dim3(4, 128, 1), 256, 0, stream>>>(
      X, fc1w_b, h + CH, fc1b, 16384, 512, 1024, 1024, 1024, 512,
      1.f, 0.f, nullptr, nullptr, nullptr, 0);

  run_attn(w1, qkv1_b, out1_b, h, hn_b, qb, kb, vb, F, ql, kl, qlb, klb,
           w3v, Wm, WmT_b, a2, xz, t1, t2, zA, zB, rs, cs, inv,
           pm, pl, poacc, stream);

  // PPEG: h -> CHW(big) -> conv -> CHW(F) -> h
  float* fppeg = (float*)big;
  transpose_feat<<<dim3(512, 16, 1), 256, 0, stream>>>(h, fppeg);
  ppeg_tile<<<dim3(16, 512, 1), 256, 0, stream>>>(fppeg, w7, b7, w5, b5, w3, b3, F);
  transpose_back<<<dim3(512, 16, 1), 256, 0, stream>>>(F, h);

  run_attn(w2, qkv2_b, out2_b, h, hn_b, qb, kb, vb, F, ql, kl, qlb, klb,
           w3v, Wm, WmT_b, a2, xz, t1, t2, zA, zB, rs, cs, inv,
           pm, pl, poacc, stream);

  final_k<<<1, 256, 0, stream>>>(h, lnfg, lnfb, fc2w, fc2b, out);
}

// Round 8
// 1218.199 us; speedup vs baseline: 9.3098x; 1.2568x over previous
//
#include <hip/hip_runtime.h>
#include <hip/hip_bf16.h>

static const int S    = 16640;  // padded sequence (65*256)
static const int PADR = 255;    // zero rows prepended inside attention
static const int NT   = 16385;  // tokens incl cls
static const int CH   = 512;    // hidden dim

typedef unsigned short u16;
typedef __attribute__((ext_vector_type(8))) short short8_t;
typedef __attribute__((ext_vector_type(4))) float float4_t;

__device__ __forceinline__ float b2f(u16 x) {
  union { unsigned u; float f; } t; t.u = (unsigned)x << 16; return t.f;
}
__device__ __forceinline__ u16 f2b(float x) {
  union { float f; unsigned u; } t; t.f = x;
  unsigned r = t.u + 0x7fff + ((t.u >> 16) & 1);
  return (u16)(r >> 16);
}

__device__ __forceinline__ float warpSum(float v) {
#pragma unroll
  for (int off = 32; off; off >>= 1) v += __shfl_xor(v, off);
  return v;
}
__device__ __forceinline__ float warpMax(float v) {
#pragma unroll
  for (int off = 32; off; off >>= 1) v = fmaxf(v, __shfl_xor(v, off));
  return v;
}
__device__ __forceinline__ float blockSum(float v) {
  __shared__ float sm[8];
  int lane = threadIdx.x & 63, wv = threadIdx.x >> 6;
  v = warpSum(v);
  __syncthreads();
  if (lane == 0) sm[wv] = v;
  __syncthreads();
  float t = 0.f;
  int nw = blockDim.x >> 6;
  for (int i = 0; i < nw; i++) t += sm[i];
  return t;
}
__device__ __forceinline__ float blockMax(float v) {
  __shared__ float sm[8];
  int lane = threadIdx.x & 63, wv = threadIdx.x >> 6;
  v = warpMax(v);
  __syncthreads();
  if (lane == 0) sm[wv] = v;
  __syncthreads();
  float t = -1e30f;
  int nw = blockDim.x >> 6;
  for (int i = 0; i < nw; i++) t = fmaxf(t, sm[i]);
  return t;
}

// ---------------------------------------------------------------------------
__global__ __launch_bounds__(256) void cvt_f2b(const float* __restrict__ in,
                                               u16* __restrict__ out, long n) {
  long i = ((long)blockIdx.x * 256 + threadIdx.x) * 4;
  if (i + 3 < n) {
    float4 v = *(const float4*)(in + i);
    out[i] = f2b(v.x); out[i + 1] = f2b(v.y); out[i + 2] = f2b(v.z); out[i + 3] = f2b(v.w);
  } else {
    for (long j = i; j < n; j++) out[j] = f2b(in[j]);
  }
}

// WmT[head][n(64)][k(256)] bf16 <- Wm[head][k(256)][n(64)] f32
__global__ __launch_bounds__(256) void wm_transpose(const float* __restrict__ Wm,
                                                    u16* __restrict__ WmT) {
  int n = blockIdx.x, head = blockIdx.y, k = threadIdx.x;
  WmT[((long)head * 64 + n) * 256 + k] = f2b(Wm[(long)head * 16384 + k * 64 + n]);
}

// ---------------------------------------------------------------------------
// MFMA bf16 GEMM: C(M,N) = A(M,K) * B^T, f32 accumulate. A dtype templated.
template <typename TA, int EPI>
__global__ __launch_bounds__(256) void mfma_gemm(
    const TA* __restrict__ A, const u16* __restrict__ B, float* __restrict__ C,
    const float* __restrict__ bias, int M, int N, int K,
    int lda, int ldb, int ldc,
    float alpha, float beta,
    u16* __restrict__ q_o, u16* __restrict__ k_o, u16* __restrict__ v_o, long s64)
{
  __shared__ u16 As[128][40];
  __shared__ u16 Bs[128][40];
  const int tid = threadIdx.x;
  const int m0 = blockIdx.y * 128, n0 = blockIdx.x * 128;
  const int wid = tid >> 6, lane = tid & 63;
  const int wr = wid >> 1, wc = wid & 1;
  const int l15 = lane & 15, l16 = lane >> 4;
  const int arow = tid >> 1, aseg = (tid & 1) * 16;
  float4_t acc[4][4] = {};

  for (int k0 = 0; k0 < K; k0 += 32) {
    {
      int gm = m0 + arow;
      u16 tmp[16];
      if (gm < M) {
        const TA* src = A + (long)gm * lda + k0 + aseg;
        if constexpr (sizeof(TA) == 2) {
          *(short8_t*)&tmp[0] = *(const short8_t*)src;
          *(short8_t*)&tmp[8] = *(const short8_t*)(src + 8);
        } else {
#pragma unroll
          for (int i4 = 0; i4 < 4; i4++) {
            float4 f = *(const float4*)((const float*)src + i4 * 4);
            tmp[i4 * 4 + 0] = f2b(f.x); tmp[i4 * 4 + 1] = f2b(f.y);
            tmp[i4 * 4 + 2] = f2b(f.z); tmp[i4 * 4 + 3] = f2b(f.w);
          }
        }
      } else {
#pragma unroll
        for (int i = 0; i < 16; i++) tmp[i] = 0;
      }
      *(short8_t*)&As[arow][aseg]     = *(short8_t*)&tmp[0];
      *(short8_t*)&As[arow][aseg + 8] = *(short8_t*)&tmp[8];
    }
    {
      int gn = n0 + arow;
      short8_t v0 = {}, v1 = {};
      if (gn < N) {
        const u16* src = B + (long)gn * ldb + k0 + aseg;
        v0 = *(const short8_t*)src; v1 = *(const short8_t*)(src + 8);
      }
      *(short8_t*)&Bs[arow][aseg]     = v0;
      *(short8_t*)&Bs[arow][aseg + 8] = v1;
    }
    __syncthreads();
    short8_t af[4], bfr[4];
#pragma unroll
    for (int i = 0; i < 4; i++)
      af[i] = *(const short8_t*)&As[wr * 64 + i * 16 + l15][l16 * 8];
#pragma unroll
    for (int i = 0; i < 4; i++)
      bfr[i] = *(const short8_t*)&Bs[wc * 64 + i * 16 + l15][l16 * 8];
#pragma unroll
    for (int i = 0; i < 4; i++)
#pragma unroll
      for (int j = 0; j < 4; j++)
        acc[i][j] = __builtin_amdgcn_mfma_f32_16x16x32_bf16(af[i], bfr[j], acc[i][j], 0, 0, 0);
    __syncthreads();
  }

#pragma unroll
  for (int mi = 0; mi < 4; mi++) {
#pragma unroll
    for (int ni = 0; ni < 4; ni++) {
#pragma unroll
      for (int j = 0; j < 4; j++) {
        int r = m0 + wr * 64 + mi * 16 + l16 * 4 + j;
        int c = n0 + wc * 64 + ni * 16 + l15;
        if (r >= M || c >= N) continue;
        float v = acc[mi][ni][j];
        if constexpr (EPI == 0) {
          long idx = (long)r * ldc + c;
          float o = alpha * v;
          if (bias) o += bias[c];
          if (beta != 0.f) o += beta * C[idx];
          C[idx] = o;
        } else if constexpr (EPI == 1) {
          long idx = (long)r * ldc + c;
          C[idx] = fmaxf(v + bias[c], 0.f);
        } else {  // EPI == 2: qkv split
          int sec = c >> 9, hcol = c & 511;
          int head = hcol >> 6, d = hcol & 63;
          u16* dst = (sec == 0) ? q_o : (sec == 1 ? k_o : v_o);
          float o = (sec == 0) ? v * alpha : v;
          dst[(long)head * s64 + (long)r * 64 + d] = f2b(o);
        }
      }
    }
  }
}

// ---------------------------------------------------------------------------
// f32-grade MFMA GEMM via bf16 hi/lo split. 32x32 tile/block, grid (8,8,8).
// MODE 0: C = alpha*acc ; MODE 3: C = acc, C2 = beta*I - acc ; MODE 4: C = beta*I - acc
template <int MODE>
__global__ __launch_bounds__(256) void pinv_gemm(
    const float* __restrict__ A, const float* __restrict__ B,
    float* __restrict__ C, float* __restrict__ C2, float alpha, float beta)
{
  __shared__ u16 Ah[32][40], Al[32][40], Bh[32][40], Bl[32][40];
  const int tid = threadIdx.x;
  const long zoff = (long)blockIdx.z << 16;
  A += zoff; B += zoff; C += zoff;
  if constexpr (MODE == 3) C2 += zoff;
  const int m0 = blockIdx.y * 32, n0 = blockIdx.x * 32;
  const int wid = tid >> 6, lane = tid & 63;
  const int wr = wid >> 1, wc = wid & 1;
  const int l15 = lane & 15, l16 = lane >> 4;
  const int arow = tid >> 3, acol = (tid & 7) * 4;
  float4_t acc = {};

  for (int k0 = 0; k0 < 256; k0 += 32) {
    {
      float4 va = *(const float4*)(A + (long)(m0 + arow) * 256 + k0 + acol);
      float4 vb = *(const float4*)(B + (long)(k0 + arow) * 256 + n0 + acol);
      float fa[4] = {va.x, va.y, va.z, va.w};
      float fb[4] = {vb.x, vb.y, vb.z, vb.w};
#pragma unroll
      for (int i = 0; i < 4; i++) {
        u16 hi = f2b(fa[i]);
        Ah[arow][acol + i] = hi;
        Al[arow][acol + i] = f2b(fa[i] - b2f(hi));
        u16 hj = f2b(fb[i]);
        Bh[acol + i][arow] = hj;
        Bl[acol + i][arow] = f2b(fb[i] - b2f(hj));
      }
    }
    __syncthreads();
    short8_t ah = *(const short8_t*)&Ah[wr * 16 + l15][l16 * 8];
    short8_t al = *(const short8_t*)&Al[wr * 16 + l15][l16 * 8];
    short8_t bh = *(const short8_t*)&Bh[wc * 16 + l15][l16 * 8];
    short8_t bl = *(const short8_t*)&Bl[wc * 16 + l15][l16 * 8];
    acc = __builtin_amdgcn_mfma_f32_16x16x32_bf16(ah, bh, acc, 0, 0, 0);
    acc = __builtin_amdgcn_mfma_f32_16x16x32_bf16(ah, bl, acc, 0, 0, 0);
    acc = __builtin_amdgcn_mfma_f32_16x16x32_bf16(al, bh, acc, 0, 0, 0);
    __syncthreads();
  }

#pragma unroll
  for (int j = 0; j < 4; j++) {
    int r = m0 + wr * 16 + l16 * 4 + j;
    int c = n0 + wc * 16 + l15;
    long idx = (long)r * 256 + c;
    float v = acc[j];
    if constexpr (MODE == 0) {
      C[idx] = alpha * v;
    } else if constexpr (MODE == 3) {
      C[idx] = v;
      C2[idx] = ((r == c) ? beta : 0.f) - v;
    } else {
      C[idx] = ((r == c) ? beta : 0.f) - v;
    }
  }
}

// ---------------------------------------------------------------------------
// Fused a1 path (LDS-staged): F[s][head*64+d] = softmax(q_h[s,:] @ kl_h^T) @ Wm_h
// grid (260 row-tiles, 8 heads), 256 thr (4 waves x 16 rows).
// KW: kl staged [256][72]; reused for WmT [64][264] in PV phase.
// Ps: half-width P (bf16), wave-private rows; PV runs in two k-halves.
__global__ __launch_bounds__(256) void attn_a1(
    const u16* __restrict__ qb, const u16* __restrict__ klb,
    const u16* __restrict__ WmT, float* __restrict__ F, long s64)
{
  __shared__ u16 KW[256 * 72];   // 36.9 KB
  __shared__ u16 Ps[64 * 136];   // 17.4 KB
  const int tid = threadIdx.x;
  const int w = tid >> 6, lane = tid & 63;
  const int l15 = lane & 15, l16 = lane >> 4;
  const int head = blockIdx.y;
  const int row0 = blockIdx.x * 64 + w * 16;

  // stage kl -> KW[256][72] (coalesced, once per block)
  const u16* klh = klb + (long)head * 16384;
#pragma unroll
  for (int i = 0; i < 4; i++) {
    int idx = tid + i * 256;
    int row = idx >> 2, seg = (idx & 3) << 4;
    const u16* src = klh + row * 64 + seg;
    *(short8_t*)&KW[row * 72 + seg]     = *(const short8_t*)src;
    *(short8_t*)&KW[row * 72 + seg + 8] = *(const short8_t*)(src + 8);
  }
  short8_t aq[2];
#pragma unroll
  for (int slab = 0; slab < 2; slab++)
    aq[slab] = *(const short8_t*)(qb + (long)head * s64 + (long)(row0 + l15) * 64 + slab * 32 + l16 * 8);
  __syncthreads();

  // scores 16x256 from LDS
  float4_t sacc[16] = {};
#pragma unroll
  for (int nt = 0; nt < 16; nt++)
#pragma unroll
    for (int slab = 0; slab < 2; slab++) {
      short8_t bfr = *(const short8_t*)&KW[(nt * 16 + l15) * 72 + slab * 32 + l16 * 8];
      sacc[nt] = __builtin_amdgcn_mfma_f32_16x16x32_bf16(aq[slab], bfr, sacc[nt], 0, 0, 0);
    }
  // softmax per row
  float rcp[4];
#pragma unroll
  for (int reg = 0; reg < 4; reg++) {
    float m = -1e30f;
#pragma unroll
    for (int nt = 0; nt < 16; nt++) m = fmaxf(m, sacc[nt][reg]);
#pragma unroll
    for (int mk = 1; mk <= 8; mk <<= 1) m = fmaxf(m, __shfl_xor(m, mk));
    float s = 0.f;
#pragma unroll
    for (int nt = 0; nt < 16; nt++) { float e = __expf(sacc[nt][reg] - m); sacc[nt][reg] = e; s += e; }
#pragma unroll
    for (int mk = 1; mk <= 8; mk <<= 1) s += __shfl_xor(s, mk);
    rcp[reg] = 1.f / s;
  }
  __syncthreads();   // all waves done reading kl from KW

  // stage WmT -> KW[64][264]; store P half 0 (cols 0..127)
  const u16* wmh = WmT + (long)head * 16384;
#pragma unroll
  for (int i = 0; i < 4; i++) {
    int idx = tid + i * 256;
    int row = idx >> 4, seg = (idx & 15) << 4;
    const u16* src = wmh + row * 256 + seg;
    *(short8_t*)&KW[row * 264 + seg]     = *(const short8_t*)src;
    *(short8_t*)&KW[row * 264 + seg + 8] = *(const short8_t*)(src + 8);
  }
#pragma unroll
  for (int nt = 0; nt < 8; nt++)
#pragma unroll
    for (int reg = 0; reg < 4; reg++)
      Ps[(w * 16 + 4 * l16 + reg) * 136 + nt * 16 + l15] = f2b(sacc[nt][reg]);
  __syncthreads();   // WmT staged

  float4_t oacc[4] = {};
#pragma unroll
  for (int ks = 0; ks < 4; ks++) {
    short8_t pa = *(const short8_t*)&Ps[(w * 16 + l15) * 136 + ks * 32 + l16 * 8];
#pragma unroll
    for (int vt = 0; vt < 4; vt++) {
      short8_t bv = *(const short8_t*)&KW[(vt * 16 + l15) * 264 + ks * 32 + l16 * 8];
      oacc[vt] = __builtin_amdgcn_mfma_f32_16x16x32_bf16(pa, bv, oacc[vt], 0, 0, 0);
    }
  }
  // P half 1 (cols 128..255) — wave-private rows, in-wave LDS order suffices
#pragma unroll
  for (int nt = 8; nt < 16; nt++)
#pragma unroll
    for (int reg = 0; reg < 4; reg++)
      Ps[(w * 16 + 4 * l16 + reg) * 136 + (nt - 8) * 16 + l15] = f2b(sacc[nt][reg]);
#pragma unroll
  for (int ks = 4; ks < 8; ks++) {
    short8_t pa = *(const short8_t*)&Ps[(w * 16 + l15) * 136 + (ks - 4) * 32 + l16 * 8];
#pragma unroll
    for (int vt = 0; vt < 4; vt++) {
      short8_t bv = *(const short8_t*)&KW[(vt * 16 + l15) * 264 + ks * 32 + l16 * 8];
      oacc[vt] = __builtin_amdgcn_mfma_f32_16x16x32_bf16(pa, bv, oacc[vt], 0, 0, 0);
    }
  }
#pragma unroll
  for (int vt = 0; vt < 4; vt++)
#pragma unroll
    for (int reg = 0; reg < 4; reg++) {
      int r = row0 + 4 * l16 + reg;
      F[(long)r * CH + head * 64 + vt * 16 + l15] = oacc[vt][reg] * rcp[reg];
    }
}

// ---------------------------------------------------------------------------
// Split-K fused a3@v with K and V both LDS-staged.
// grid (4 row-quarters, 8 heads, 13 splits), 256 thr (4 waves x 16 rows).
__global__ __launch_bounds__(256) void attn_a3v_split(
    const u16* __restrict__ qlb, const u16* __restrict__ kb,
    const u16* __restrict__ vb,
    float* __restrict__ pm, float* __restrict__ pl, float* __restrict__ poacc,
    long s64)
{
  __shared__ u16 Vt[64][136];       // V^T tile: [d][key]  (17.4 KB)
  __shared__ u16 Kt[128 * 72];      // K tile [128][72]    (18.4 KB)
  __shared__ u16 Ps[4][16][136];    // per-wave P          (17.4 KB)
  const int tid = threadIdx.x;
  const int w = tid >> 6, lane = tid & 63;
  const int l15 = lane & 15, l16 = lane >> 4;
  const int head = blockIdx.y;
  const int split = blockIdx.z;
  const int row0 = blockIdx.x * 64 + w * 16;

  short8_t aq[2];
#pragma unroll
  for (int slab = 0; slab < 2; slab++)
    aq[slab] = *(const short8_t*)(qlb + (long)head * 16384 + (long)(row0 + l15) * 64 + slab * 32 + l16 * 8);

  float m[4], l[4];
  float4_t oacc[4] = {};
#pragma unroll
  for (int r = 0; r < 4; r++) { m[r] = -1e30f; l[r] = 0.f; }

  const u16* kh = kb + (long)head * s64;
  const u16* vh = vb + (long)head * s64;
  const int vrow = tid >> 1, vhalf = (tid & 1) * 32;

  const int kt0 = split * 10;
  for (int kt = kt0; kt < kt0 + 10; kt++) {
    const int j0 = kt * 128;
    __syncthreads();   // prior-iter Kt/Vt reads done
    // stage V^T
    {
      const u16* src = vh + (long)(j0 + vrow) * 64 + vhalf;
#pragma unroll
      for (int i = 0; i < 32; i++) Vt[vhalf + i][vrow] = src[i];
    }
    // stage K tile [128][72]
#pragma unroll
    for (int i = 0; i < 2; i++) {
      int idx = tid + i * 256;
      int row = idx >> 2, seg = (idx & 3) << 4;
      const u16* src = kh + (long)(j0 + row) * 64 + seg;
      *(short8_t*)&Kt[row * 72 + seg]     = *(const short8_t*)src;
      *(short8_t*)&Kt[row * 72 + seg + 8] = *(const short8_t*)(src + 8);
    }
    __syncthreads();   // staged
    // scores 16x128 from LDS
    float4_t sacc[8] = {};
#pragma unroll
    for (int nt = 0; nt < 8; nt++)
#pragma unroll
      for (int slab = 0; slab < 2; slab++) {
        short8_t bfr = *(const short8_t*)&Kt[(nt * 16 + l15) * 72 + slab * 32 + l16 * 8];
        sacc[nt] = __builtin_amdgcn_mfma_f32_16x16x32_bf16(aq[slab], bfr, sacc[nt], 0, 0, 0);
      }
    // online softmax update
    float scale[4];
#pragma unroll
    for (int reg = 0; reg < 4; reg++) {
      float tm = -1e30f;
#pragma unroll
      for (int nt = 0; nt < 8; nt++) tm = fmaxf(tm, sacc[nt][reg]);
#pragma unroll
      for (int mk = 1; mk <= 8; mk <<= 1) tm = fmaxf(tm, __shfl_xor(tm, mk));
      float nm = fmaxf(m[reg], tm);
      scale[reg] = __expf(m[reg] - nm);
      m[reg] = nm;
      float ts = 0.f;
#pragma unroll
      for (int nt = 0; nt < 8; nt++) {
        float e = __expf(sacc[nt][reg] - nm);
        sacc[nt][reg] = e; ts += e;
      }
#pragma unroll
      for (int mk = 1; mk <= 8; mk <<= 1) ts += __shfl_xor(ts, mk);
      l[reg] = l[reg] * scale[reg] + ts;
#pragma unroll
      for (int vt = 0; vt < 4; vt++) oacc[vt][reg] *= scale[reg];
    }
#pragma unroll
    for (int nt = 0; nt < 8; nt++)
#pragma unroll
      for (int reg = 0; reg < 4; reg++)
        Ps[w][4 * l16 + reg][nt * 16 + l15] = f2b(sacc[nt][reg]);
#pragma unroll
    for (int ks = 0; ks < 4; ks++) {
      short8_t pa = *(const short8_t*)&Ps[w][l15][ks * 32 + l16 * 8];
#pragma unroll
      for (int vt = 0; vt < 4; vt++) {
        short8_t bv = *(const short8_t*)&Vt[vt * 16 + l15][ks * 32 + l16 * 8];
        oacc[vt] = __builtin_amdgcn_mfma_f32_16x16x32_bf16(pa, bv, oacc[vt], 0, 0, 0);
      }
    }
  }
#pragma unroll
  for (int reg = 0; reg < 4; reg++) {
    int r = row0 + 4 * l16 + reg;
    long pidx = ((long)(head * 13 + split) << 8) + r;
    if (l15 == 0) { pm[pidx] = m[reg]; pl[pidx] = l[reg]; }
#pragma unroll
    for (int vt = 0; vt < 4; vt++)
      poacc[(pidx << 6) + vt * 16 + l15] = oacc[vt][reg];
  }
}

// merge split partials
__global__ __launch_bounds__(64) void a3v_merge(const float* __restrict__ pm,
    const float* __restrict__ pl, const float* __restrict__ poacc,
    float* __restrict__ w3v)
{
  int hb = blockIdx.x;            // head*256 + row
  int head = hb >> 8, row = hb & 255;
  int d = threadIdx.x;
  float M = -1e30f;
  for (int sp = 0; sp < 13; sp++)
    M = fmaxf(M, pm[((long)(head * 13 + sp) << 8) + row]);
  float num = 0.f, den = 0.f;
  for (int sp = 0; sp < 13; sp++) {
    long pidx = ((long)(head * 13 + sp) << 8) + row;
    float sc = __expf(pm[pidx] - M);
    den += pl[pidx] * sc;
    num += poacc[(pidx << 6) + d] * sc;
  }
  w3v[((long)head << 14) + ((long)row << 6) + d] = num / den;
}

// ---------------------------------------------------------------------------
// SIMT f32 tiled matmul (a2 scores, Wm).
template <bool BT, int MODE>
__global__ __launch_bounds__(256) void mm_kernel(
    const float* __restrict__ A, const float* __restrict__ Bm, float* __restrict__ C,
    const float* __restrict__ bias,
    int M, int N, int K, int lda, int ldb, int ldc,
    long sA, long sB, long sC, float alpha, float beta, long s64)
{
  __shared__ float As[16][64];
  __shared__ float Bs[16][64];
  const int bz = blockIdx.z;
  A  += (long)bz * sA;
  Bm += (long)bz * sB;
  C  += (long)bz * sC;
  const int m0 = blockIdx.y * 64, n0 = blockIdx.x * 64;
  const int tid = threadIdx.x;
  const int tm = tid >> 4, tn = tid & 15;
  const int ar = tid >> 2;
  const int ac = (tid & 3) << 2;
  float acc[4][4] = {};
  for (int k0 = 0; k0 < K; k0 += 16) {
#pragma unroll
    for (int i = 0; i < 4; i++) {
      int gm = m0 + ar, gk = k0 + ac + i;
      As[ac + i][ar] = (gm < M && gk < K) ? A[(long)gm * lda + gk] : 0.f;
    }
    if constexpr (BT) {
#pragma unroll
      for (int i = 0; i < 4; i++) {
        int gn = n0 + ar, gk = k0 + ac + i;
        Bs[ac + i][ar] = (gn < N && gk < K) ? Bm[(long)gn * ldb + gk] : 0.f;
      }
    } else {
      int bk = tid >> 4;
      int bn = (tid & 15) << 2;
#pragma unroll
      for (int i = 0; i < 4; i++) {
        int gk = k0 + bk, gn = n0 + bn + i;
        Bs[bk][bn + i] = (gk < K && gn < N) ? Bm[(long)gk * ldb + gn] : 0.f;
      }
    }
    __syncthreads();
#pragma unroll
    for (int kk = 0; kk < 16; kk++) {
      float a[4], b[4];
#pragma unroll
      for (int i = 0; i < 4; i++) { a[i] = As[kk][tm * 4 + i]; b[i] = Bs[kk][tn * 4 + i]; }
#pragma unroll
      for (int i = 0; i < 4; i++)
#pragma unroll
        for (int j = 0; j < 4; j++)
          acc[i][j] = fmaf(a[i], b[j], acc[i][j]);
    }
    __syncthreads();
  }
#pragma unroll
  for (int i = 0; i < 4; i++) {
    int row = m0 + tm * 4 + i;
    if (row >= M) continue;
#pragma unroll
    for (int j = 0; j < 4; j++) {
      int col = n0 + tn * 4 + j;
      if (col >= N) continue;
      long idx = (long)row * ldc + col;
      float v = acc[i][j];
      float o = alpha * v;
      if (bias) o += bias[col];
      C[idx] = (beta != 0.f) ? o + beta * C[idx] : o;
    }
  }
}

// ---------------------------------------------------------------------------
__global__ void cls_copy(const float* __restrict__ c, float* __restrict__ h) {
  h[threadIdx.x] = c[threadIdx.x];
}

__global__ __launch_bounds__(256) void ln_pad_b(const float* __restrict__ h,
    const float* __restrict__ g, const float* __restrict__ b,
    u16* __restrict__ out, int pad)
{
  int s = blockIdx.x, t = threadIdx.x;
  u16* o = out + (long)s * CH;
  if (s < pad) { o[t] = 0; o[t + 256] = 0; return; }
  const float* x = h + (long)(s - pad) * CH;
  float x0 = x[t], x1 = x[t + 256];
  float mu = blockSum(x0 + x1) * (1.f / 512.f);
  float d0 = x0 - mu, d1 = x1 - mu;
  float var = blockSum(d0 * d0 + d1 * d1) * (1.f / 512.f);
  float rs = rsqrtf(var + 1e-5f);
  o[t]       = f2b(d0 * rs * g[t]       + b[t]);
  o[t + 256] = f2b(d1 * rs * g[t + 256] + b[t + 256]);
}

__global__ __launch_bounds__(64) void landmark_b(const u16* __restrict__ q,
    float* __restrict__ ql, u16* __restrict__ qlb) {
  int hb = blockIdx.x;
  int d = threadIdx.x;
  int hh = hb >> 8, j = hb & 255;
  const u16* src = q + ((long)hh * S + (long)j * 65) * 64 + d;
  float s = 0.f;
  for (int g2 = 0; g2 < 65; g2++) s += b2f(src[(long)g2 * 64]);
  s *= (1.f / 65.f);
  ql[(long)hb * 64 + d] = s;
  qlb[(long)hb * 64 + d] = f2b(s);
}

__global__ __launch_bounds__(256) void rowsoftmax(float* __restrict__ X) {
  float* row = X + (long)blockIdx.x * 256;
  int t = threadIdx.x;
  float x = row[t];
  float m = blockMax(x);
  float e = __expf(x - m);
  float s = blockSum(e);
  row[t] = e / s;
}

__global__ __launch_bounds__(256) void colabs(const float* __restrict__ a2, float* __restrict__ cs) {
  int hb = blockIdx.x; int hh = hb >> 8, j = hb & 255;
  float s = blockSum(fabsf(a2[((long)hh * 256 + threadIdx.x) * 256 + j]));
  if (threadIdx.x == 0) cs[hb] = s;
}
// row-sums of softmax'd a2 are identically 1 -> scale = 1 / max colsum
__global__ __launch_bounds__(256) void scaleinv(const float* __restrict__ cs,
                                                float* __restrict__ inv) {
  float m2 = -1e30f;
  for (int i = threadIdx.x; i < 2048; i += 256) m2 = fmaxf(m2, cs[i]);
  m2 = blockMax(m2);
  if (threadIdx.x == 0) inv[0] = 1.f / m2;
}
__global__ __launch_bounds__(256) void z0k(const float* __restrict__ a2,
                                           const float* __restrict__ inv, float* __restrict__ z) {
  int hb = blockIdx.x; int hh = hb >> 8, i = hb & 255; int j = threadIdx.x;
  z[(long)hb * 256 + j] = a2[((long)hh * 256 + j) * 256 + i] * inv[0];
}

// ---------------------------------------------------------------------------
// LDS-tiled depthwise residual conv (kernel 33, pad 16): F += conv(v).
__global__ __launch_bounds__(256) void resconv2(const u16* __restrict__ v,
    const float* __restrict__ w, float* __restrict__ F)
{
  __shared__ u16 T[160][64];
  __shared__ float ws[33];
  const int hh = blockIdx.y;
  const int p0 = blockIdx.x * 128;
  const int tid = threadIdx.x;
  if (tid < 33) ws[tid] = w[hh * 33 + tid];
  const u16* vh = v + (long)hh * S * 64;
  for (int idx = tid; idx < 640; idx += 256) {
    int row = idx >> 2, seg = (idx & 3) * 16;
    int j = p0 - 16 + row;
    short8_t a = {}, b = {};
    if (0 <= j && j < S) {
      const u16* src = vh + (long)j * 64 + seg;
      a = *(const short8_t*)src; b = *(const short8_t*)(src + 8);
    }
    *(short8_t*)&T[row][seg]     = a;
    *(short8_t*)&T[row][seg + 8] = b;
  }
  __syncthreads();
  const int d = tid & 63;
  const int pg = tid >> 6;
  float wreg[33];
#pragma unroll
  for (int t = 0; t < 33; t++) wreg[t] = ws[t];
#pragma unroll
  for (int g = 0; g < 4; g++) {
    const int base = pg * 32 + g * 8;
    float win[40];
#pragma unroll
    for (int i = 0; i < 40; i++) win[i] = b2f(T[base + i][d]);
#pragma unroll
    for (int p = 0; p < 8; p++) {
      float acc = 0.f;
#pragma unroll
      for (int t = 0; t < 33; t++) acc = fmaf(wreg[t], win[p + t], acc);
      F[(long)(p0 + base + p) * CH + hh * 64 + d] += acc;
    }
  }
}

// h feat rows (1..16384, 512 cols) -> f (512, 16384) CHW
__global__ __launch_bounds__(256) void transpose_feat(const float* __restrict__ h, float* __restrict__ f) {
  __shared__ float tile[32][33];
  int p0 = blockIdx.x * 32;
  int c0 = blockIdx.y * 32;
  int tx = threadIdx.x & 31, ty = threadIdx.x >> 5;
  for (int i = 0; i < 32; i += 8)
    tile[ty + i][tx] = h[(long)(1 + p0 + ty + i) * CH + c0 + tx];
  __syncthreads();
  for (int i = 0; i < 32; i += 8)
    f[(long)(c0 + ty + i) * 16384 + p0 + tx] = tile[tx][ty + i];
}

// PPEG conv, LDS-tiled
__global__ __launch_bounds__(256) void ppeg_tile(const float* __restrict__ f,
    const float* __restrict__ w7, const float* __restrict__ b7,
    const float* __restrict__ w5, const float* __restrict__ b5,
    const float* __restrict__ w3, const float* __restrict__ b3,
    float* __restrict__ fo)
{
  __shared__ float T[38][40];
  __shared__ float W7s[49], W5s[25], W3s[9];
  int c = blockIdx.y;
  int ty0 = (blockIdx.x >> 2) * 32, tx0 = (blockIdx.x & 3) * 32;
  int tid = threadIdx.x;
  if (tid < 49) W7s[tid] = w7[c * 49 + tid];
  if (tid < 25) W5s[tid] = w5[c * 25 + tid];
  if (tid < 9)  W3s[tid] = w3[c * 9 + tid];
  const float* fc = f + (long)c * 16384;
  for (int idx = tid; idx < 38 * 38; idx += 256) {
    int r = idx / 38, cc = idx - r * 38;
    int y = ty0 + r - 3, x = tx0 + cc - 3;
    T[r][cc] = (0 <= y && y < 128 && 0 <= x && x < 128) ? fc[y * 128 + x] : 0.f;
  }
  __syncthreads();
  float bsum = b7[c] + b5[c] + b3[c];
#pragma unroll
  for (int p = 0; p < 4; p++) {
    int px = tid + p * 256;
    int y = px >> 5, x = px & 31;
    float acc = T[y + 3][x + 3] + bsum;
#pragma unroll
    for (int dy = 0; dy < 7; dy++)
#pragma unroll
      for (int dx = 0; dx < 7; dx++)
        acc += W7s[dy * 7 + dx] * T[y + dy][x + dx];
#pragma unroll
    for (int dy = 0; dy < 5; dy++)
#pragma unroll
      for (int dx = 0; dx < 5; dx++)
        acc += W5s[dy * 5 + dx] * T[y + dy + 1][x + dx + 1];
#pragma unroll
    for (int dy = 0; dy < 3; dy++)
#pragma unroll
      for (int dx = 0; dx < 3; dx++)
        acc += W3s[dy * 3 + dx] * T[y + dy + 2][x + dx + 2];
    fo[(long)c * 16384 + (ty0 + y) * 128 + tx0 + x] = acc;
  }
}

// fo (512,16384) CHW -> h rows 1..16384
__global__ __launch_bounds__(256) void transpose_back(const float* __restrict__ fo, float* __restrict__ h) {
  __shared__ float tile[32][33];
  int p0 = blockIdx.x * 32;
  int c0 = blockIdx.y * 32;
  int tx = threadIdx.x & 31, ty = threadIdx.x >> 5;
  for (int i = 0; i < 32; i += 8)
    tile[ty + i][tx] = fo[(long)(c0 + ty + i) * 16384 + p0 + tx];
  __syncthreads();
  for (int i = 0; i < 32; i += 8)
    h[(long)(1 + p0 + ty + i) * CH + c0 + tx] = tile[tx][ty + i];
}

// final: LN(h row 0) then 2-class head
__global__ __launch_bounds__(256) void final_k(const float* __restrict__ h,
    const float* __restrict__ g, const float* __restrict__ b,
    const float* __restrict__ w, const float* __restrict__ fb, float* __restrict__ out)
{
  int t = threadIdx.x;
  float x0 = h[t], x1 = h[t + 256];
  float mu = blockSum(x0 + x1) * (1.f / 512.f);
  float d0 = x0 - mu, d1 = x1 - mu;
  float var = blockSum(d0 * d0 + d1 * d1) * (1.f / 512.f);
  float rs = rsqrtf(var + 1e-5f);
  float y0 = d0 * rs * g[t]       + b[t];
  float y1 = d1 * rs * g[t + 256] + b[t + 256];
  float s0 = blockSum(y0 * w[t]       + y1 * w[t + 256]);
  float s1 = blockSum(y0 * w[512 + t] + y1 * w[512 + t + 256]);
  if (t == 0) {
    out[0] = s0 + fb[0];
    out[1] = s1 + fb[1];
  }
}

// ---------------------------------------------------------------------------
struct AttnW {
  const float *lng, *lnb, *qkvw, *outw, *outb, *resw;
};

static void run_attn(const AttnW& Wt, const u16* qkvw_b, const u16* outw_b,
                     float* h, u16* hn_b, u16* qb, u16* kb, u16* vb, float* F,
                     float* ql, float* kl, u16* qlb, u16* klb,
                     float* w3v, float* Wm, u16* WmT_b,
                     float* a2, float* xz, float* t1, float* t2, float* zA, float* zB,
                     float* cs, float* inv,
                     float* pm, float* pl, float* poacc,
                     hipStream_t stream)
{
  const long s64 = (long)S * 64;
  ln_pad_b<<<S, 256, 0, stream>>>(h, Wt.lng, Wt.lnb, hn_b, PADR);
  mfma_gemm<u16, 2><<<dim3(12, 130, 1), 256, 0, stream>>>(
      hn_b, qkvw_b, nullptr, nullptr, S, 1536, 512, 512, 512, 0,
      0.125f, 0.f, qb, kb, vb, s64);
  landmark_b<<<2048, 64, 0, stream>>>(qb, ql, qlb);
  landmark_b<<<2048, 64, 0, stream>>>(kb, kl, klb);
  // a2 = softmax(ql @ kl^T) — f32 SIMT (feeds pinv)
  mm_kernel<true, 0><<<dim3(4, 4, 8), 256, 0, stream>>>(
      ql, kl, a2, nullptr, 256, 256, 64, 64, 64, 256, 16384, 16384, 65536, 1.f, 0.f, 0);
  rowsoftmax<<<2048, 256, 0, stream>>>(a2);
  colabs<<<2048, 256, 0, stream>>>(a2, cs);
  scaleinv<<<1, 256, 0, stream>>>(cs, inv);
  z0k<<<2048, 256, 0, stream>>>(a2, inv, zA);
  float* zc = zA; float* zo = zB;
  for (int it = 0; it < 6; it++) {
    pinv_gemm<3><<<dim3(8, 8, 8), 256, 0, stream>>>(a2, zc, xz, t1, 1.f, 7.f);
    pinv_gemm<4><<<dim3(8, 8, 8), 256, 0, stream>>>(xz, t1, t2, nullptr, 1.f, 15.f);
    pinv_gemm<4><<<dim3(8, 8, 8), 256, 0, stream>>>(xz, t2, t1, nullptr, 1.f, 13.f);
    pinv_gemm<0><<<dim3(8, 8, 8), 256, 0, stream>>>(zc, t1, zo, nullptr, 0.25f, 0.f);
    float* tmp = zc; zc = zo; zo = tmp;
  }
  attn_a3v_split<<<dim3(4, 8, 13), 256, 0, stream>>>(qlb, kb, vb, pm, pl, poacc, s64);
  a3v_merge<<<2048, 64, 0, stream>>>(pm, pl, poacc, w3v);
  mm_kernel<false, 0><<<dim3(1, 4, 8), 256, 0, stream>>>(
      zc, w3v, Wm, nullptr, 256, 64, 256, 256, 64, 64, 65536, 16384, 16384, 1.f, 0.f, 0);
  wm_transpose<<<dim3(64, 8, 1), 256, 0, stream>>>(Wm, WmT_b);
  attn_a1<<<dim3(260, 8, 1), 256, 0, stream>>>(qb, klb, WmT_b, F, s64);
  resconv2<<<dim3(130, 8, 1), 256, 0, stream>>>(vb, Wt.resw, F);
  // h += F[PADR:, :] @ outw^T + outb  (A read as f32 directly)
  mfma_gemm<float, 0><<<dim3(4, 129, 1), 256, 0, stream>>>(
      F + (long)PADR * CH, outw_b, h, Wt.outb, NT, 512, 512, 512, 512, 512,
      1.f, 1.f, nullptr, nullptr, nullptr, 0);
}

extern "C" void kernel_launch(void* const* d_in, const int* in_sizes, int n_in,
                              void* d_out, int out_size, void* d_ws, size_t ws_size,
                              hipStream_t stream)
{
  const float* X      = (const float*)d_in[0];
  const float* fc1w   = (const float*)d_in[1];
  const float* fc1b   = (const float*)d_in[2];
  const float* clstok = (const float*)d_in[3];
  AttnW w1{ (const float*)d_in[4], (const float*)d_in[5], (const float*)d_in[6],
            (const float*)d_in[7], (const float*)d_in[8], (const float*)d_in[9] };
  const float* w7 = (const float*)d_in[10]; const float* b7 = (const float*)d_in[11];
  const float* w5 = (const float*)d_in[12]; const float* b5 = (const float*)d_in[13];
  const float* w3 = (const float*)d_in[14]; const float* b3 = (const float*)d_in[15];
  AttnW w2{ (const float*)d_in[16], (const float*)d_in[17], (const float*)d_in[18],
            (const float*)d_in[19], (const float*)d_in[20], (const float*)d_in[21] };
  const float* lnfg = (const float*)d_in[22];
  const float* lnfb = (const float*)d_in[23];
  const float* fc2w = (const float*)d_in[24];
  const float* fc2b = (const float*)d_in[25];
  float* out = (float*)d_out;

  char* wsb = (char*)d_ws;
  size_t off = 0;
  auto alloc = [&](size_t nbytes) {
    void* p = wsb + off;
    off = (off + nbytes + 255) & ~(size_t)255;
    return p;
  };
  float* h    = (float*)alloc((size_t)NT * CH * 4);
  float* F    = (float*)alloc((size_t)S * CH * 4);      // attn out; ppeg CHW temp
  u16*  hn_b  = (u16*)alloc((size_t)S * CH * 2);
  u16*  qb    = (u16*)alloc((size_t)S * CH * 2);
  u16*  kb    = (u16*)alloc((size_t)S * CH * 2);
  u16*  vb    = (u16*)alloc((size_t)S * CH * 2);
  char* big   = (char*)alloc(33554432);                 // ppeg CHW f32
  u16*  fc1w_b = (u16*)alloc(524288 * 2);
  u16*  qkv1_b = (u16*)alloc(786432 * 2);
  u16*  qkv2_b = (u16*)alloc(786432 * 2);
  u16*  out1_b = (u16*)alloc(262144 * 2);
  u16*  out2_b = (u16*)alloc(262144 * 2);
  float* ql   = (float*)alloc(131072 * 4);
  float* kl   = (float*)alloc(131072 * 4);
  u16*  qlb   = (u16*)alloc(131072 * 2);
  u16*  klb   = (u16*)alloc(131072 * 2);
  float* w3v  = (float*)alloc(131072 * 4);
  float* Wm   = (float*)alloc(131072 * 4);
  u16*  WmT_b = (u16*)alloc(131072 * 2);
  float* a2   = (float*)alloc(524288 * 4);
  float* xz   = (float*)alloc(524288 * 4);
  float* t1   = (float*)alloc(524288 * 4);
  float* t2   = (float*)alloc(524288 * 4);
  float* zA   = (float*)alloc(524288 * 4);
  float* zB   = (float*)alloc(524288 * 4);
  float* cs   = (float*)alloc(2048 * 4);
  float* inv  = (float*)alloc(256);
  float* pm   = (float*)alloc((size_t)8 * 13 * 256 * 4);
  float* pl   = (float*)alloc((size_t)8 * 13 * 256 * 4);
  float* poacc = (float*)alloc((size_t)8 * 13 * 256 * 64 * 4);
  (void)in_sizes; (void)n_in; (void)out_size; (void)ws_size;

  // weight conversions (small; X and F consumed as f32 directly)
  cvt_f2b<<<512, 256, 0, stream>>>(fc1w, fc1w_b, 524288);
  cvt_f2b<<<768, 256, 0, stream>>>(w1.qkvw, qkv1_b, 786432);
  cvt_f2b<<<768, 256, 0, stream>>>(w2.qkvw, qkv2_b, 786432);
  cvt_f2b<<<256, 256, 0, stream>>>(w1.outw, out1_b, 262144);
  cvt_f2b<<<256, 256, 0, stream>>>(w2.outw, out2_b, 262144);

  cls_copy<<<1, 512, 0, stream>>>(clstok, h);
  mfma_gemm<float, 1><<<dim3(4, 128, 1), 256, 0, stream>>>(
      X, fc1w_b, h + CH, fc1b, 16384, 512, 1024, 1024, 1024, 512,
      1.f, 0.f, nullptr, nullptr, nullptr, 0);

  run_attn(w1, qkv1_b, out1_b, h, hn_b, qb, kb, vb, F, ql, kl, qlb, klb,
           w3v, Wm, WmT_b, a2, xz, t1, t2, zA, zB, cs, inv,
           pm, pl, poacc, stream);

  // PPEG: h -> CHW(big) -> conv -> CHW(F) -> h
  float* fppeg = (float*)big;
  transpose_feat<<<dim3(512, 16, 1), 256, 0, stream>>>(h, fppeg);
  ppeg_tile<<<dim3(16, 512, 1), 256, 0, stream>>>(fppeg, w7, b7, w5, b5, w3, b3, F);
  transpose_back<<<dim3(512, 16, 1), 256, 0, stream>>>(F, h);

  run_attn(w2, qkv2_b, out2_b, h, hn_b, qb, kb, vb, F, ql, kl, qlb, klb,
           w3v, Wm, WmT_b, a2, xz, t1, t2, zA, zB, cs, inv,
           pm, pl, poacc, stream);

  final_k<<<1, 256, 0, stream>>>(h, lnfg, lnfb, fc2w, fc2b, out);
}